// Round 8
// baseline (366.422 us; speedup 1.0000x reference)
//
#include <hip/hip_runtime.h>
#include <math.h>

// Problem constants (match reference setup_inputs()).
#define NNODES 10000
#define MPAD   10112           // 79 * 128 (MFMA M-tile padding)
#define NEDGES 80000           // directed edges before self loops
#define ETOT   (NEDGES + NNODES)

typedef __attribute__((ext_vector_type(4))) float f32x4;
typedef __attribute__((ext_vector_type(8))) short bf16x8;
typedef __attribute__((ext_vector_type(4))) unsigned short u16x4;
typedef __attribute__((ext_vector_type(4))) unsigned int u32x4;

__device__ inline unsigned short f2bf(float f) {
    unsigned int u = __float_as_uint(f);
    unsigned int r = (u + 0x7fffu + ((u >> 16) & 1u)) >> 16;
    return (unsigned short)r;
}
__device__ inline float bf2f(unsigned short h) {
    return __uint_as_float(((unsigned int)h) << 16);
}
__device__ inline float lrelu01(float v) { return (v > 0.f) ? v : 0.1f * v; }
__device__ inline float lrelu02(float v) { return (v > 0.f) ? v : 0.2f * v; }

// ---------------------------------------------------------------------------
// CSR build (group edges by destination). Rebuilt every launch (ws poisoned).
// ---------------------------------------------------------------------------
__global__ void count_deg(const int* __restrict__ ei, int* __restrict__ indeg,
                          int E, int n) {
    int i = blockIdx.x * blockDim.x + threadIdx.x;
    if (i >= E + n) return;
    int dst = (i < E) ? ei[E + i] : (i - E);
    atomicAdd(&indeg[dst], 1);
}

__global__ void scan_rowptr(const int* __restrict__ indeg, int* __restrict__ row_ptr,
                            int* __restrict__ cursor, int n) {
    __shared__ int sums[1024];
    int tid = threadIdx.x;
    int per = (n + 1023) / 1024;
    int start = tid * per;
    int end = start + per; if (end > n) end = n;
    int s = 0;
    for (int i = start; i < end; ++i) s += indeg[i];
    sums[tid] = s;
    __syncthreads();
    for (int off = 1; off < 1024; off <<= 1) {
        int v = (tid >= off) ? sums[tid - off] : 0;
        __syncthreads();
        sums[tid] += v;
        __syncthreads();
    }
    int excl = (tid == 0) ? 0 : sums[tid - 1];
    for (int i = start; i < end; ++i) {
        row_ptr[i] = excl;
        cursor[i]  = excl;
        excl += indeg[i];
    }
    if (tid == 1023) row_ptr[n] = sums[1023];
}

__global__ void scatter_edges(const int* __restrict__ ei, int* __restrict__ cursor,
                              int* __restrict__ col, int E, int n) {
    int i = blockIdx.x * blockDim.x + threadIdx.x;
    if (i >= E + n) return;
    int src, dst;
    if (i < E) { src = ei[i]; dst = ei[E + i]; }
    else       { src = i - E; dst = i - E; }
    int pos = atomicAdd(&cursor[dst], 1);
    col[pos] = src;
}

// ---------------------------------------------------------------------------
// fp32 -> bf16 elementwise convert (for x).
// ---------------------------------------------------------------------------
__global__ void convert_bf16(const float* __restrict__ in, unsigned short* __restrict__ out,
                             int n) {
    int i = blockIdx.x * blockDim.x + threadIdx.x;
    if (i < n) out[i] = f2bf(in[i]);
}

// Transpose-convert W[K][N] fp32 -> Wt[N][K] bf16. K,N multiples of 32.
__global__ void transpose_bf16(const float* __restrict__ W, unsigned short* __restrict__ Wt,
                               int K, int N) {
    __shared__ float t[32][33];
    int kb = blockIdx.y * 32, nb = blockIdx.x * 32;
    int tx = threadIdx.x, ty = threadIdx.y;   // 32 x 8
    #pragma unroll
    for (int i = 0; i < 32; i += 8)
        t[ty + i][tx] = W[(size_t)(kb + ty + i) * N + nb + tx];
    __syncthreads();
    #pragma unroll
    for (int i = 0; i < 32; i += 8)
        Wt[(size_t)(nb + ty + i) * K + kb + tx] = f2bf(t[tx][ty + i]);
}

// ---------------------------------------------------------------------------
// bf16 MFMA GEMM: C[MPAD][N] (bf16) = A[MPAD][K] (bf16) @ Bt[NB][K]^T (bf16),
// where NB = nbn*NT >= N (Bt rows padded; C columns >= N predicated off).
// Tile 128 x NT, 256 threads = 4 waves. SWIZ: 1-D grid, all N-tiles of one
// M-tile map to the same XCD (b%8) so the A-slice is L2-resident.
// ---------------------------------------------------------------------------
#define GBM 128
#define GBK 32
template <int NT, bool SWIZ>
__global__ __launch_bounds__(256) void gemm_mfma(const unsigned short* __restrict__ A,
                                                 const unsigned short* __restrict__ Bt,
                                                 unsigned short* __restrict__ C,
                                                 int N, int nbn, int K) {
    constexpr int NI = NT / 32;          // N-subtiles per wave
    __shared__ short As[GBM * GBK];
    __shared__ short Bs[NT * GBK];
    int bn, bm;
    if constexpr (SWIZ) {
        int b = blockIdx.x;
        int x = b & 7, t = b >> 3;
        int j = x + 8 * (t / nbn);       // M-tile index, fixed mod 8 per XCD
        if (j >= MPAD / GBM) return;
        bn = (t % nbn) * NT;
        bm = j * GBM;
    } else {
        bn = blockIdx.x * NT;
        bm = blockIdx.y * GBM;
    }
    int tid  = threadIdx.x;
    int wave = tid >> 6, lane = tid & 63;
    int wr = wave >> 1, wc = wave & 1;
    int lrow  = lane >> 2;
    int lkoff = (lane & 3) * 8;
    int row16 = lane & 15;
    int q8    = (lane >> 4) * 8;

    f32x4 acc[4][NI];
    #pragma unroll
    for (int mi = 0; mi < 4; ++mi)
        #pragma unroll
        for (int ni = 0; ni < NI; ++ni) acc[mi][ni] = (f32x4){0.f, 0.f, 0.f, 0.f};

    for (int k0 = 0; k0 < K; k0 += GBK) {
        // stage A: 8 chunks of 16 rows; wave handles chunks wave, wave+4
        #pragma unroll
        for (int i = 0; i < 2; ++i) {
            int c = i * 4 + wave;
            int row = c * 16 + lrow;
            const unsigned short* gp = A + (size_t)(bm + row) * K + k0 + lkoff;
            __builtin_amdgcn_global_load_lds(
                (const __attribute__((address_space(1))) void*)gp,
                (__attribute__((address_space(3))) void*)&As[c * 512], 16, 0, 0);
        }
        // stage Bt: NT/16 chunks of 16 rows
        #pragma unroll
        for (int i = 0; i < NT / 64; ++i) {
            int c = i * 4 + wave;
            int row = c * 16 + lrow;
            const unsigned short* gp = Bt + (size_t)(bn + row) * K + k0 + lkoff;
            __builtin_amdgcn_global_load_lds(
                (const __attribute__((address_space(1))) void*)gp,
                (__attribute__((address_space(3))) void*)&Bs[c * 512], 16, 0, 0);
        }
        __syncthreads();
        bf16x8 af[4], bfr[NI];
        #pragma unroll
        for (int mi = 0; mi < 4; ++mi)
            af[mi] = *(const bf16x8*)&As[(wr * 64 + mi * 16 + row16) * GBK + q8];
        #pragma unroll
        for (int ni = 0; ni < NI; ++ni)
            bfr[ni] = *(const bf16x8*)&Bs[(wc * (NT / 2) + ni * 16 + row16) * GBK + q8];
        #pragma unroll
        for (int mi = 0; mi < 4; ++mi)
            #pragma unroll
            for (int ni = 0; ni < NI; ++ni)
                acc[mi][ni] = __builtin_amdgcn_mfma_f32_16x16x32_bf16(
                    af[mi], bfr[ni], acc[mi][ni], 0, 0, 0);
        __syncthreads();
    }

    // epilogue: C/D layout col = lane&15, row = (lane>>4)*4 + r
    int rbase = bm + wr * 64 + (lane >> 4) * 4;
    #pragma unroll
    for (int mi = 0; mi < 4; ++mi)
        #pragma unroll
        for (int ni = 0; ni < NI; ++ni) {
            int cb = bn + wc * (NT / 2) + ni * 16;       // 16-aligned; N % 16 == 0
            if (cb >= N) continue;                        // padded columns dropped
            int cbase = cb + (lane & 15);
            #pragma unroll
            for (int r = 0; r < 4; ++r)
                C[(size_t)(rbase + mi * 16 + r) * N + cbase] = f2bf(acc[mi][ni][r]);
        }
}

// ---------------------------------------------------------------------------
// Tiny layer-4 GEMM: C[M][16] (bf16) = A[M][128] (bf16) @ W[128][16] (fp32).
// ---------------------------------------------------------------------------
__global__ __launch_bounds__(256) void gemm4(const unsigned short* __restrict__ A,
                                             const float* __restrict__ W,
                                             unsigned short* __restrict__ C, int M) {
    __shared__ float Ws[128 * 16];
    int tid = threadIdx.x;
    for (int i = tid; i < 2048; i += 256) Ws[i] = W[i];
    __syncthreads();
    int node = blockIdx.x * 16 + (tid >> 4);
    int n = tid & 15;
    if (node >= M) return;
    const unsigned short* ap = A + (size_t)node * 128;
    float acc = 0.f;
    #pragma unroll 8
    for (int k = 0; k < 128; ++k)
        acc += bf2f(ap[k]) * Ws[k * 16 + n];
    C[(size_t)node * 16 + n] = f2bf(acc);
}

// ---------------------------------------------------------------------------
// attn halves, wide rows (layer 1: H=10, C=256 and layer 4: H=1, C=16):
// one wave per (node,head).
// ---------------------------------------------------------------------------
__global__ __launch_bounds__(64) void attn_halves(const unsigned short* __restrict__ h,
                                                  const float* __restrict__ a_src,
                                                  const float* __restrict__ a_dst,
                                                  float* __restrict__ e_src,
                                                  float* __restrict__ e_dst,
                                                  int H, int C) {
    int wid = blockIdx.x;          // node*H + head
    int head = wid % H;
    int lane = threadIdx.x;
    const unsigned short* hp = h + (size_t)wid * C;
    float s1 = 0.f, s2 = 0.f;
    for (int c0 = lane * 4; c0 < C; c0 += 256) {
        u16x4 hv = *(const u16x4*)&hp[c0];
        f32x4 as = *(const f32x4*)&a_src[head * C + c0];
        f32x4 ad = *(const f32x4*)&a_dst[head * C + c0];
        #pragma unroll
        for (int j = 0; j < 4; ++j) {
            float v = bf2f(hv[j]);
            s1 += v * as[j];
            s2 += v * ad[j];
        }
    }
    #pragma unroll
    for (int off = 32; off; off >>= 1) {
        s1 += __shfl_down(s1, off);
        s2 += __shfl_down(s2, off);
    }
    if (lane == 0) { e_src[wid] = s1; e_dst[wid] = s2; }
}

// ---------------------------------------------------------------------------
// attn halves, small C (layers 2/3): one wave per NODE, all heads in-wave.
// ---------------------------------------------------------------------------
template <int H, int C>
__global__ __launch_bounds__(64) void attn_small(const unsigned short* __restrict__ h,
                                                 const float* __restrict__ a_src,
                                                 const float* __restrict__ a_dst,
                                                 float* __restrict__ e_src,
                                                 float* __restrict__ e_dst) {
    constexpr int LPH = 64 / H;
    constexpr int CPL = C / LPH;
    int node = blockIdx.x;
    int lane = threadIdx.x;
    int head = lane / LPH;
    int k = lane - head * LPH;
    const unsigned short* hp = h + (size_t)node * (H * C) + head * C + k * CPL;
    const float* as = a_src + head * C + k * CPL;
    const float* ad = a_dst + head * C + k * CPL;
    float s1 = 0.f, s2 = 0.f;
    #pragma unroll
    for (int c = 0; c < CPL; ++c) {
        float v = bf2f(hp[c]);
        s1 += v * as[c];
        s2 += v * ad[c];
    }
    #pragma unroll
    for (int off = LPH / 2; off; off >>= 1) {
        s1 += __shfl_down(s1, off);
        s2 += __shfl_down(s2, off);
    }
    if (k == 0) { e_src[node * H + head] = s1; e_dst[node * H + head] = s2; }
}

// ---------------------------------------------------------------------------
// Aggregation kernels. Softmax without max subtraction (m=0): mathematically
// identical; logits bounded. Edge walk manually unrolled by 2 with DUAL
// accumulator sets -> 2x memory-level parallelism (4 loads in flight).
// ---------------------------------------------------------------------------

// Layer-1 (H=10, C=256): one wave per (node, head-pair). Lane covers 8
// contiguous channels of one head; one dwordx4 per edge per lane.
__global__ __launch_bounds__(64) void agg_l1(const unsigned short* __restrict__ h,
                                             const float* __restrict__ e_src,
                                             const float* __restrict__ e_dst,
                                             const int* __restrict__ row_ptr,
                                             const int* __restrict__ col,
                                             const float* __restrict__ bias,
                                             unsigned short* __restrict__ out) {
    const int H = 10;
    int wid  = blockIdx.x;            // node*5 + hp
    int node = wid / 5;
    int hp   = wid - node * 5;
    int lane = threadIdx.x;
    int sub  = lane >> 5;             // 0/1 within head pair
    int head = hp * 2 + sub;
    int cpos = lane & 31;             // 8 channels each
    int rs = row_ptr[node], re = row_ptr[node + 1];
    float edv = e_dst[node * H + head];

    float dn = 0.f;
    float acc0[8], acc1[8];
    #pragma unroll
    for (int k = 0; k < 8; ++k) { acc0[k] = 0.f; acc1[k] = 0.f; }
    int i = rs;
    for (; i + 1 < re; i += 2) {
        int s0 = col[i], s1 = col[i + 1];
        float es0 = e_src[s0 * H + head];
        float es1 = e_src[s1 * H + head];
        u32x4 hv0 = *(const u32x4*)(h + (size_t)s0 * 2560 + head * 256 + cpos * 8);
        u32x4 hv1 = *(const u32x4*)(h + (size_t)s1 * 2560 + head * 256 + cpos * 8);
        float w0 = __expf(lrelu02(es0 + edv));
        float w1 = __expf(lrelu02(es1 + edv));
        dn += w0 + w1;
        #pragma unroll
        for (int d = 0; d < 4; ++d) {
            acc0[2 * d]     += w0 * bf2f((unsigned short)(hv0[d] & 0xffffu));
            acc0[2 * d + 1] += w0 * bf2f((unsigned short)(hv0[d] >> 16));
            acc1[2 * d]     += w1 * bf2f((unsigned short)(hv1[d] & 0xffffu));
            acc1[2 * d + 1] += w1 * bf2f((unsigned short)(hv1[d] >> 16));
        }
    }
    if (i < re) {
        int s = col[i];
        float w = __expf(lrelu02(e_src[s * H + head] + edv));
        dn += w;
        u32x4 hv = *(const u32x4*)(h + (size_t)s * 2560 + head * 256 + cpos * 8);
        #pragma unroll
        for (int d = 0; d < 4; ++d) {
            acc0[2 * d]     += w * bf2f((unsigned short)(hv[d] & 0xffffu));
            acc0[2 * d + 1] += w * bf2f((unsigned short)(hv[d] >> 16));
        }
    }
    float rdn = 1.f / (dn + 1e-16f);

    const float* bp = bias + head * 256 + cpos * 8;
    u32x4 o;
    #pragma unroll
    for (int d = 0; d < 4; ++d) {
        float v0 = lrelu01((acc0[2 * d] + acc1[2 * d]) * rdn + bp[2 * d]);
        float v1 = lrelu01((acc0[2 * d + 1] + acc1[2 * d + 1]) * rdn + bp[2 * d + 1]);
        o[d] = (unsigned int)f2bf(v0) | ((unsigned int)f2bf(v1) << 16);
    }
    *(u32x4*)(out + (size_t)node * 2560 + head * 256 + cpos * 8) = o;
}

// Layer-2 (H=8, C=56): one wave per node, 56 active lanes (8 heads x 7 slots).
__global__ __launch_bounds__(64) void agg_l2(const unsigned short* __restrict__ h,
                                             const float* __restrict__ e_src,
                                             const float* __restrict__ e_dst,
                                             const int* __restrict__ row_ptr,
                                             const int* __restrict__ col,
                                             const float* __restrict__ bias,
                                             unsigned short* __restrict__ out) {
    const int H = 8;
    int node = blockIdx.x;
    int lane = threadIdx.x;
    bool act = lane < 56;
    int head = act ? (lane / 7) : 0;
    int cpos = act ? (lane - head * 7) : 0;
    int rs = row_ptr[node], re = row_ptr[node + 1];
    float edv = e_dst[node * H + head];

    float dn = 0.f;
    float acc0[8], acc1[8];
    #pragma unroll
    for (int k = 0; k < 8; ++k) { acc0[k] = 0.f; acc1[k] = 0.f; }
    int i = rs;
    for (; i + 1 < re; i += 2) {
        int s0 = col[i], s1 = col[i + 1];
        float es0 = e_src[s0 * H + head];
        float es1 = e_src[s1 * H + head];
        u32x4 hv0 = *(const u32x4*)(h + (size_t)s0 * 448 + head * 56 + cpos * 8);
        u32x4 hv1 = *(const u32x4*)(h + (size_t)s1 * 448 + head * 56 + cpos * 8);
        float w0 = __expf(lrelu02(es0 + edv));
        float w1 = __expf(lrelu02(es1 + edv));
        dn += w0 + w1;
        #pragma unroll
        for (int d = 0; d < 4; ++d) {
            acc0[2 * d]     += w0 * bf2f((unsigned short)(hv0[d] & 0xffffu));
            acc0[2 * d + 1] += w0 * bf2f((unsigned short)(hv0[d] >> 16));
            acc1[2 * d]     += w1 * bf2f((unsigned short)(hv1[d] & 0xffffu));
            acc1[2 * d + 1] += w1 * bf2f((unsigned short)(hv1[d] >> 16));
        }
    }
    if (i < re) {
        int s = col[i];
        float w = __expf(lrelu02(e_src[s * H + head] + edv));
        dn += w;
        u32x4 hv = *(const u32x4*)(h + (size_t)s * 448 + head * 56 + cpos * 8);
        #pragma unroll
        for (int d = 0; d < 4; ++d) {
            acc0[2 * d]     += w * bf2f((unsigned short)(hv[d] & 0xffffu));
            acc0[2 * d + 1] += w * bf2f((unsigned short)(hv[d] >> 16));
        }
    }
    float rdn = 1.f / (dn + 1e-16f);

    if (act) {
        const float* bp = bias + head * 56 + cpos * 8;
        u32x4 o;
        #pragma unroll
        for (int d = 0; d < 4; ++d) {
            float v0 = lrelu01((acc0[2 * d] + acc1[2 * d]) * rdn + bp[2 * d]);
            float v1 = lrelu01((acc0[2 * d + 1] + acc1[2 * d + 1]) * rdn + bp[2 * d + 1]);
            o[d] = (unsigned int)f2bf(v0) | ((unsigned int)f2bf(v1) << 16);
        }
        *(u32x4*)(out + (size_t)node * 448 + head * 56 + cpos * 8) = o;
    }
}

// Layer-3 (H=4, C=32): one wave per node, 16 active lanes.
__global__ __launch_bounds__(64) void agg_l3(const unsigned short* __restrict__ h,
                                             const float* __restrict__ e_src,
                                             const float* __restrict__ e_dst,
                                             const int* __restrict__ row_ptr,
                                             const int* __restrict__ col,
                                             const float* __restrict__ bias,
                                             unsigned short* __restrict__ out) {
    const int H = 4;
    int node = blockIdx.x;
    int lane = threadIdx.x;
    bool act = lane < 16;
    int head = (lane >> 2) & 3;
    int cpos = lane & 3;
    int rs = row_ptr[node], re = row_ptr[node + 1];
    float edv = e_dst[node * H + head];

    float dn = 0.f;
    float acc0[8], acc1[8];
    #pragma unroll
    for (int k = 0; k < 8; ++k) { acc0[k] = 0.f; acc1[k] = 0.f; }
    int i = rs;
    for (; i + 1 < re; i += 2) {
        int s0 = col[i], s1 = col[i + 1];
        float es0 = e_src[s0 * H + head];
        float es1 = e_src[s1 * H + head];
        u32x4 hv0 = *(const u32x4*)(h + (size_t)s0 * 128 + head * 32 + cpos * 8);
        u32x4 hv1 = *(const u32x4*)(h + (size_t)s1 * 128 + head * 32 + cpos * 8);
        float w0 = __expf(lrelu02(es0 + edv));
        float w1 = __expf(lrelu02(es1 + edv));
        dn += w0 + w1;
        #pragma unroll
        for (int d = 0; d < 4; ++d) {
            acc0[2 * d]     += w0 * bf2f((unsigned short)(hv0[d] & 0xffffu));
            acc0[2 * d + 1] += w0 * bf2f((unsigned short)(hv0[d] >> 16));
            acc1[2 * d]     += w1 * bf2f((unsigned short)(hv1[d] & 0xffffu));
            acc1[2 * d + 1] += w1 * bf2f((unsigned short)(hv1[d] >> 16));
        }
    }
    if (i < re) {
        int s = col[i];
        float w = __expf(lrelu02(e_src[s * H + head] + edv));
        dn += w;
        u32x4 hv = *(const u32x4*)(h + (size_t)s * 128 + head * 32 + cpos * 8);
        #pragma unroll
        for (int d = 0; d < 4; ++d) {
            acc0[2 * d]     += w * bf2f((unsigned short)(hv[d] & 0xffffu));
            acc0[2 * d + 1] += w * bf2f((unsigned short)(hv[d] >> 16));
        }
    }
    float rdn = 1.f / (dn + 1e-16f);

    if (act) {
        const float* bp = bias + head * 32 + cpos * 8;
        u32x4 o;
        #pragma unroll
        for (int d = 0; d < 4; ++d) {
            float v0 = lrelu01((acc0[2 * d] + acc1[2 * d]) * rdn + bp[2 * d]);
            float v1 = lrelu01((acc0[2 * d + 1] + acc1[2 * d + 1]) * rdn + bp[2 * d + 1]);
            o[d] = (unsigned int)f2bf(v0) | ((unsigned int)f2bf(v1) << 16);
        }
        *(u32x4*)(out + (size_t)node * 128 + head * 32 + cpos * 8) = o;
    }
}

// Layer-4 fused: aggregate (H=1, C=16) + bias + LeakyReLU(0.1) + row softmax.
__global__ __launch_bounds__(64) void agg4_softmax(const unsigned int* __restrict__ h2,
                                                   const float* __restrict__ e_src,
                                                   const float* __restrict__ e_dst,
                                                   const int* __restrict__ row_ptr,
                                                   const int* __restrict__ col,
                                                   const float* __restrict__ bias,
                                                   float* __restrict__ out) {
    int node = blockIdx.x;
    int lane = threadIdx.x;
    int cpos = lane & 7;
    int rs = row_ptr[node], re = row_ptr[node + 1];
    float edv = e_dst[node];

    float dn = 0.f, a0 = 0.f, a1 = 0.f;
    for (int i = rs; i < re; ++i) {
        int s = col[i];
        float w = __expf(lrelu02(e_src[s] + edv));
        dn += w;
        unsigned int hv = h2[(size_t)s * 8 + cpos];
        a0 += w * bf2f((unsigned short)(hv & 0xffffu));
        a1 += w * bf2f((unsigned short)(hv >> 16));
    }
    float rdn = 1.f / (dn + 1e-16f);
    float v0 = lrelu01(a0 * rdn + bias[2 * cpos]);
    float v1 = lrelu01(a1 * rdn + bias[2 * cpos + 1]);

    // softmax over 16 values per aligned 8-lane group
    float m = fmaxf(v0, v1);
    #pragma unroll
    for (int off = 4; off; off >>= 1) m = fmaxf(m, __shfl_xor(m, off));
    float e0 = __expf(v0 - m), e1 = __expf(v1 - m);
    float s = e0 + e1;
    #pragma unroll
    for (int off = 4; off; off >>= 1) s += __shfl_xor(s, off);
    float r = 1.f / s;
    if (lane < 8) {
        out[node * 16 + 2 * cpos]     = e0 * r;
        out[node * 16 + 2 * cpos + 1] = e1 * r;
    }
}

// ---------------------------------------------------------------------------
extern "C" void kernel_launch(void* const* d_in, const int* in_sizes, int n_in,
                              void* d_out, int out_size, void* d_ws, size_t ws_size,
                              hipStream_t stream) {
    const float* x   = (const float*)d_in[0];
    const int*   ei  = (const int*)d_in[1];
    const float* W1  = (const float*)d_in[2];
    const float* as1 = (const float*)d_in[3];
    const float* ad1 = (const float*)d_in[4];
    const float* b1  = (const float*)d_in[5];
    const float* W2  = (const float*)d_in[6];
    const float* as2 = (const float*)d_in[7];
    const float* ad2 = (const float*)d_in[8];
    const float* b2  = (const float*)d_in[9];
    const float* W3  = (const float*)d_in[10];
    const float* as3 = (const float*)d_in[11];
    const float* ad3 = (const float*)d_in[12];
    const float* b3  = (const float*)d_in[13];
    const float* W4  = (const float*)d_in[14];
    const float* as4 = (const float*)d_in[15];
    const float* ad4 = (const float*)d_in[16];
    const float* b4  = (const float*)d_in[17];

    char* ws = (char*)d_ws;
    size_t off = 0;
    auto alloc = [&](size_t bytes) -> void* {
        void* p = ws + off;
        off = (off + bytes + 255) & ~(size_t)255;
        return p;
    };
    unsigned short* hbuf = (unsigned short*)alloc((size_t)MPAD * 2560 * sizeof(short)); // GEMM out / attn input
    unsigned short* abuf = (unsigned short*)alloc((size_t)MPAD * 2560 * sizeof(short)); // bf16 GEMM A input
    unsigned short* W1t  = (unsigned short*)alloc((size_t)2560 * 128 * sizeof(short));
    unsigned short* W2t  = (unsigned short*)alloc((size_t)512 * 2560 * sizeof(short));  // padded to 512 rows
    unsigned short* W3t  = (unsigned short*)alloc((size_t)128 * 448 * sizeof(short));
    float* e_src  = (float*)alloc((size_t)NNODES * 10 * sizeof(float));
    float* e_dst  = (float*)alloc((size_t)NNODES * 10 * sizeof(float));
    int* indeg    = (int*)alloc(NNODES * sizeof(int));
    int* row_ptr  = (int*)alloc((NNODES + 1) * sizeof(int));
    int* cursor   = (int*)alloc(NNODES * sizeof(int));
    int* col      = (int*)alloc(ETOT * sizeof(int));
    (void)ws_size;

    // ---- CSR build ----
    hipMemsetAsync(indeg, 0, NNODES * sizeof(int), stream);
    int eb = (ETOT + 255) / 256;
    count_deg<<<eb, 256, 0, stream>>>(ei, indeg, NEDGES, NNODES);
    scan_rowptr<<<1, 1024, 0, stream>>>(indeg, row_ptr, cursor, NNODES);
    scatter_edges<<<eb, 256, 0, stream>>>(ei, cursor, col, NEDGES, NNODES);

    // ---- weight transposes + x convert ----
    // Zero W2t pad rows (448-511) so padded-column MFMA inputs are benign.
    hipMemsetAsync(W2t + (size_t)448 * 2560, 0, (size_t)64 * 2560 * sizeof(short), stream);
    transpose_bf16<<<dim3(2560 / 32, 128 / 32), dim3(32, 8), 0, stream>>>(W1, W1t, 128, 2560);
    transpose_bf16<<<dim3(448 / 32, 2560 / 32), dim3(32, 8), 0, stream>>>(W2, W2t, 2560, 448);
    transpose_bf16<<<dim3(128 / 32, 448 / 32), dim3(32, 8), 0, stream>>>(W3, W3t, 448, 128);
    convert_bf16<<<(NNODES * 128 + 255) / 256, 256, 0, stream>>>(x, abuf, NNODES * 128);

    const int Mb = MPAD / GBM;   // 79

    // ---- Layer 1: 128 -> 10 heads x 256, concat ----
    gemm_mfma<128, false><<<dim3(2560 / 128, Mb), 256, 0, stream>>>(
        abuf, W1t, hbuf, 2560, 20, 128);
    attn_halves<<<NNODES * 10, 64, 0, stream>>>(hbuf, as1, ad1, e_src, e_dst, 10, 256);
    agg_l1<<<NNODES * 5, 64, 0, stream>>>(hbuf, e_src, e_dst, row_ptr, col, b1, abuf);

    // ---- Layer 2: 2560 -> 8 heads x 56 (XCD-swizzled, NT=128, N padded 512) ----
    gemm_mfma<128, true><<<dim3(8 * 4 * 10), 256, 0, stream>>>(
        abuf, W2t, hbuf, 448, 4, 2560);
    attn_small<8, 56><<<NNODES, 64, 0, stream>>>(hbuf, as2, ad2, e_src, e_dst);
    agg_l2<<<NNODES, 64, 0, stream>>>(hbuf, e_src, e_dst, row_ptr, col, b2, abuf);

    // ---- Layer 3: 448 -> 4 heads x 32, concat ----
    gemm_mfma<64, false><<<dim3(2, Mb), 256, 0, stream>>>(
        abuf, W3t, hbuf, 128, 2, 448);
    attn_small<4, 32><<<NNODES, 64, 0, stream>>>(hbuf, as3, ad3, e_src, e_dst);
    agg_l3<<<NNODES, 64, 0, stream>>>(hbuf, e_src, e_dst, row_ptr, col, b3, abuf);

    // ---- Layer 4: 128 -> 1 head x 16, mean(=identity), + softmax fused ----
    gemm4<<<(NNODES + 15) / 16, 256, 0, stream>>>(abuf, W4, hbuf, NNODES);
    attn_halves<<<NNODES, 64, 0, stream>>>(hbuf, as4, ad4, e_src, e_dst, 1, 16);
    agg4_softmax<<<NNODES, 64, 0, stream>>>(
        (const unsigned int*)hbuf, e_src, e_dst, row_ptr, col, b4, (float*)d_out);
}

// Round 9
// 347.555 us; speedup vs baseline: 1.0543x; 1.0543x over previous
//
#include <hip/hip_runtime.h>
#include <math.h>

// Problem constants (match reference setup_inputs()).
#define NNODES 10000
#define MPAD   10112           // 79 * 128 (MFMA M-tile padding)
#define NEDGES 80000           // directed edges before self loops
#define ETOT   (NEDGES + NNODES)

typedef __attribute__((ext_vector_type(4))) float f32x4;
typedef __attribute__((ext_vector_type(8))) short bf16x8;
typedef __attribute__((ext_vector_type(4))) unsigned short u16x4;
typedef __attribute__((ext_vector_type(4))) unsigned int u32x4;

__device__ inline unsigned short f2bf(float f) {
    unsigned int u = __float_as_uint(f);
    unsigned int r = (u + 0x7fffu + ((u >> 16) & 1u)) >> 16;
    return (unsigned short)r;
}
__device__ inline float bf2f(unsigned short h) {
    return __uint_as_float(((unsigned int)h) << 16);
}
__device__ inline float lrelu01(float v) { return (v > 0.f) ? v : 0.1f * v; }
__device__ inline float lrelu02(float v) { return (v > 0.f) ? v : 0.2f * v; }

// ---------------------------------------------------------------------------
// CSR build (group edges by destination). Rebuilt every launch (ws poisoned).
// ---------------------------------------------------------------------------
__global__ void count_deg(const int* __restrict__ ei, int* __restrict__ indeg,
                          int E, int n) {
    int i = blockIdx.x * blockDim.x + threadIdx.x;
    if (i >= E + n) return;
    int dst = (i < E) ? ei[E + i] : (i - E);
    atomicAdd(&indeg[dst], 1);
}

__global__ void scan_rowptr(const int* __restrict__ indeg, int* __restrict__ row_ptr,
                            int* __restrict__ cursor, int n) {
    __shared__ int sums[1024];
    int tid = threadIdx.x;
    int per = (n + 1023) / 1024;
    int start = tid * per;
    int end = start + per; if (end > n) end = n;
    int s = 0;
    for (int i = start; i < end; ++i) s += indeg[i];
    sums[tid] = s;
    __syncthreads();
    for (int off = 1; off < 1024; off <<= 1) {
        int v = (tid >= off) ? sums[tid - off] : 0;
        __syncthreads();
        sums[tid] += v;
        __syncthreads();
    }
    int excl = (tid == 0) ? 0 : sums[tid - 1];
    for (int i = start; i < end; ++i) {
        row_ptr[i] = excl;
        cursor[i]  = excl;
        excl += indeg[i];
    }
    if (tid == 1023) row_ptr[n] = sums[1023];
}

__global__ void scatter_edges(const int* __restrict__ ei, int* __restrict__ cursor,
                              int* __restrict__ col, int E, int n) {
    int i = blockIdx.x * blockDim.x + threadIdx.x;
    if (i >= E + n) return;
    int src, dst;
    if (i < E) { src = ei[i]; dst = ei[E + i]; }
    else       { src = i - E; dst = i - E; }
    int pos = atomicAdd(&cursor[dst], 1);
    col[pos] = src;
}

// ---------------------------------------------------------------------------
// fp32 -> bf16 elementwise convert (for x).
// ---------------------------------------------------------------------------
__global__ void convert_bf16(const float* __restrict__ in, unsigned short* __restrict__ out,
                             int n) {
    int i = blockIdx.x * blockDim.x + threadIdx.x;
    if (i < n) out[i] = f2bf(in[i]);
}

// All three weight transposes in ONE dispatch. W[K][N] fp32 -> Wt[N][K] bf16.
// Block -> (which weight, 32x32 tile). 1496 tiles total.
__global__ void transpose_all(const float* __restrict__ W1, const float* __restrict__ W2,
                              const float* __restrict__ W3,
                              unsigned short* __restrict__ W1t,
                              unsigned short* __restrict__ W2t,
                              unsigned short* __restrict__ W3t) {
    __shared__ float t[32][33];
    int b = blockIdx.x;
    const float* W; unsigned short* Wt; int K, N, nb, kb;
    if (b < 320)       { W = W1; Wt = W1t; K = 128;  N = 2560; int i = b;        nb = i % 80; kb = i / 80; }
    else if (b < 1440) { W = W2; Wt = W2t; K = 2560; N = 448;  int i = b - 320;  nb = i % 14; kb = i / 14; }
    else               { W = W3; Wt = W3t; K = 448;  N = 128;  int i = b - 1440; nb = i % 4;  kb = i / 4;  }
    int kb32 = kb * 32, nb32 = nb * 32;
    int tx = threadIdx.x, ty = threadIdx.y;   // 32 x 8
    #pragma unroll
    for (int i = 0; i < 32; i += 8)
        t[ty + i][tx] = W[(size_t)(kb32 + ty + i) * N + nb32 + tx];
    __syncthreads();
    #pragma unroll
    for (int i = 0; i < 32; i += 8)
        Wt[(size_t)(nb32 + ty + i) * K + kb32 + tx] = f2bf(t[tx][ty + i]);
}

// ---------------------------------------------------------------------------
// bf16 MFMA GEMM: C = A[MPAD][K] @ Bt[N][K]^T, bf16 in/out.
// Tile 128 x NT, 256 threads = 4 waves. SWIZ: 1-D grid.x, all N-tiles of one
// M-tile map to the same XCD (b%8) so the A-slice is L2-resident; blockIdx.y
// is the split-K slice (klen K-range each), writing bf16 partials at
// offset z*MPAD*N. Non-SWIZ: 2-D grid, full K.
// ---------------------------------------------------------------------------
#define GBM 128
#define GBK 32
template <int NT, bool SWIZ>
__global__ __launch_bounds__(256) void gemm_mfma(const unsigned short* __restrict__ A,
                                                 const unsigned short* __restrict__ Bt,
                                                 unsigned short* __restrict__ C,
                                                 int N, int nbn, int K, int klen) {
    constexpr int NI = NT / 32;          // N-subtiles per wave
    __shared__ short As[GBM * GBK];
    __shared__ short Bs[NT * GBK];
    int bn, bm, kbeg, kend;
    size_t zoff = 0;
    if constexpr (SWIZ) {
        int b = blockIdx.x;
        int x = b & 7, t = b >> 3;
        int j = x + 8 * (t / nbn);       // M-tile index, fixed mod 8 per XCD
        if (j >= MPAD / GBM) return;
        bn = (t % nbn) * NT;
        bm = j * GBM;
        kbeg = blockIdx.y * klen;
        kend = kbeg + klen;
        zoff = (size_t)blockIdx.y * MPAD * N;
    } else {
        bn = blockIdx.x * NT;
        bm = blockIdx.y * GBM;
        kbeg = 0; kend = K;
    }
    int tid  = threadIdx.x;
    int wave = tid >> 6, lane = tid & 63;
    int wr = wave >> 1, wc = wave & 1;
    int lrow  = lane >> 2;
    int lkoff = (lane & 3) * 8;
    int row16 = lane & 15;
    int q8    = (lane >> 4) * 8;

    f32x4 acc[4][NI];
    #pragma unroll
    for (int mi = 0; mi < 4; ++mi)
        #pragma unroll
        for (int ni = 0; ni < NI; ++ni) acc[mi][ni] = (f32x4){0.f, 0.f, 0.f, 0.f};

    for (int k0 = kbeg; k0 < kend; k0 += GBK) {
        // stage A: 8 chunks of 16 rows; wave handles chunks wave, wave+4
        #pragma unroll
        for (int i = 0; i < 2; ++i) {
            int c = i * 4 + wave;
            int row = c * 16 + lrow;
            const unsigned short* gp = A + (size_t)(bm + row) * K + k0 + lkoff;
            __builtin_amdgcn_global_load_lds(
                (const __attribute__((address_space(1))) void*)gp,
                (__attribute__((address_space(3))) void*)&As[c * 512], 16, 0, 0);
        }
        // stage Bt: NT/16 chunks of 16 rows
        #pragma unroll
        for (int i = 0; i < NT / 64; ++i) {
            int c = i * 4 + wave;
            int row = c * 16 + lrow;
            const unsigned short* gp = Bt + (size_t)(bn + row) * K + k0 + lkoff;
            __builtin_amdgcn_global_load_lds(
                (const __attribute__((address_space(1))) void*)gp,
                (__attribute__((address_space(3))) void*)&Bs[c * 512], 16, 0, 0);
        }
        __syncthreads();
        bf16x8 af[4], bfr[NI];
        #pragma unroll
        for (int mi = 0; mi < 4; ++mi)
            af[mi] = *(const bf16x8*)&As[(wr * 64 + mi * 16 + row16) * GBK + q8];
        #pragma unroll
        for (int ni = 0; ni < NI; ++ni)
            bfr[ni] = *(const bf16x8*)&Bs[(wc * (NT / 2) + ni * 16 + row16) * GBK + q8];
        #pragma unroll
        for (int mi = 0; mi < 4; ++mi)
            #pragma unroll
            for (int ni = 0; ni < NI; ++ni)
                acc[mi][ni] = __builtin_amdgcn_mfma_f32_16x16x32_bf16(
                    af[mi], bfr[ni], acc[mi][ni], 0, 0, 0);
        __syncthreads();
    }

    // epilogue: C/D layout col = lane&15, row = (lane>>4)*4 + r
    int rbase = bm + wr * 64 + (lane >> 4) * 4;
    int cbase = bn + wc * (NT / 2) + (lane & 15);
    #pragma unroll
    for (int mi = 0; mi < 4; ++mi)
        #pragma unroll
        for (int ni = 0; ni < NI; ++ni)
            #pragma unroll
            for (int r = 0; r < 4; ++r)
                C[zoff + (size_t)(rbase + mi * 16 + r) * N + cbase + ni * 16] =
                    f2bf(acc[mi][ni][r]);
}

// Sum two bf16x2-packed split-K partials -> packed bf16x2.
__global__ void reduce2p(const unsigned int* __restrict__ P, unsigned int* __restrict__ out,
                         int n2) {
    int i = blockIdx.x * blockDim.x + threadIdx.x;
    if (i >= n2) return;
    unsigned int a = P[i];
    unsigned int b = P[(size_t)MPAD * 448 / 2 + i];
    float lo = bf2f((unsigned short)(a & 0xffffu)) + bf2f((unsigned short)(b & 0xffffu));
    float hi = bf2f((unsigned short)(a >> 16))     + bf2f((unsigned short)(b >> 16));
    out[i] = (unsigned int)f2bf(lo) | ((unsigned int)f2bf(hi) << 16);
}

// ---------------------------------------------------------------------------
// Layer-4 GEMM fused with attention halves: C[M][16] = A[M][128] @ W[128][16],
// plus e_src[node] = dot(C_row, as4), e_dst = dot(C_row, ad4) via 16-lane
// shfl_xor reduction (16 threads per node, 16-aligned groups).
// ---------------------------------------------------------------------------
__global__ __launch_bounds__(256) void gemm4_attn(const unsigned short* __restrict__ A,
                                                  const float* __restrict__ W,
                                                  const float* __restrict__ as4,
                                                  const float* __restrict__ ad4,
                                                  unsigned short* __restrict__ C,
                                                  float* __restrict__ e_src,
                                                  float* __restrict__ e_dst, int M) {
    __shared__ float Ws[128 * 16];
    int tid = threadIdx.x;
    for (int i = tid; i < 2048; i += 256) Ws[i] = W[i];
    __syncthreads();
    int node = blockIdx.x * 16 + (tid >> 4);
    int n = tid & 15;
    if (node >= M) return;
    const unsigned short* ap = A + (size_t)node * 128;
    float acc = 0.f;
    #pragma unroll 8
    for (int k = 0; k < 128; ++k)
        acc += bf2f(ap[k]) * Ws[k * 16 + n];
    C[(size_t)node * 16 + n] = f2bf(acc);
    float vs = acc * as4[n];
    float vd = acc * ad4[n];
    #pragma unroll
    for (int off = 1; off < 16; off <<= 1) {
        vs += __shfl_xor(vs, off);
        vd += __shfl_xor(vd, off);
    }
    if (n == 0) { e_src[node] = vs; e_dst[node] = vd; }
}

// ---------------------------------------------------------------------------
// attn halves, wide rows (layer 1: H=10, C=256): one wave per (node,head).
// ---------------------------------------------------------------------------
__global__ __launch_bounds__(64) void attn_halves(const unsigned short* __restrict__ h,
                                                  const float* __restrict__ a_src,
                                                  const float* __restrict__ a_dst,
                                                  float* __restrict__ e_src,
                                                  float* __restrict__ e_dst,
                                                  int H, int C) {
    int wid = blockIdx.x;          // node*H + head
    int head = wid % H;
    int lane = threadIdx.x;
    const unsigned short* hp = h + (size_t)wid * C;
    float s1 = 0.f, s2 = 0.f;
    for (int c0 = lane * 4; c0 < C; c0 += 256) {
        u16x4 hv = *(const u16x4*)&hp[c0];
        f32x4 as = *(const f32x4*)&a_src[head * C + c0];
        f32x4 ad = *(const f32x4*)&a_dst[head * C + c0];
        #pragma unroll
        for (int j = 0; j < 4; ++j) {
            float v = bf2f(hv[j]);
            s1 += v * as[j];
            s2 += v * ad[j];
        }
    }
    #pragma unroll
    for (int off = 32; off; off >>= 1) {
        s1 += __shfl_down(s1, off);
        s2 += __shfl_down(s2, off);
    }
    if (lane == 0) { e_src[wid] = s1; e_dst[wid] = s2; }
}

// ---------------------------------------------------------------------------
// attn halves, small C (layers 2/3): one wave per NODE, all heads in-wave.
// ---------------------------------------------------------------------------
template <int H, int C>
__global__ __launch_bounds__(64) void attn_small(const unsigned short* __restrict__ h,
                                                 const float* __restrict__ a_src,
                                                 const float* __restrict__ a_dst,
                                                 float* __restrict__ e_src,
                                                 float* __restrict__ e_dst) {
    constexpr int LPH = 64 / H;
    constexpr int CPL = C / LPH;
    int node = blockIdx.x;
    int lane = threadIdx.x;
    int head = lane / LPH;
    int k = lane - head * LPH;
    const unsigned short* hp = h + (size_t)node * (H * C) + head * C + k * CPL;
    const float* as = a_src + head * C + k * CPL;
    const float* ad = a_dst + head * C + k * CPL;
    float s1 = 0.f, s2 = 0.f;
    #pragma unroll
    for (int c = 0; c < CPL; ++c) {
        float v = bf2f(hp[c]);
        s1 += v * as[c];
        s2 += v * ad[c];
    }
    #pragma unroll
    for (int off = LPH / 2; off; off >>= 1) {
        s1 += __shfl_down(s1, off);
        s2 += __shfl_down(s2, off);
    }
    if (k == 0) { e_src[node * H + head] = s1; e_dst[node * H + head] = s2; }
}

// ---------------------------------------------------------------------------
// Aggregation kernels. Softmax without max subtraction (m=0): mathematically
// identical; logits bounded. Edge walk unrolled by 2 with dual accumulators.
// ---------------------------------------------------------------------------

// Layer-1 (H=10, C=256): one wave per (node, head-pair).
__global__ __launch_bounds__(64) void agg_l1(const unsigned short* __restrict__ h,
                                             const float* __restrict__ e_src,
                                             const float* __restrict__ e_dst,
                                             const int* __restrict__ row_ptr,
                                             const int* __restrict__ col,
                                             const float* __restrict__ bias,
                                             unsigned short* __restrict__ out) {
    const int H = 10;
    int wid  = blockIdx.x;            // node*5 + hp
    int node = wid / 5;
    int hp   = wid - node * 5;
    int lane = threadIdx.x;
    int sub  = lane >> 5;             // 0/1 within head pair
    int head = hp * 2 + sub;
    int cpos = lane & 31;             // 8 channels each
    int rs = row_ptr[node], re = row_ptr[node + 1];
    float edv = e_dst[node * H + head];

    float dn = 0.f;
    float acc0[8], acc1[8];
    #pragma unroll
    for (int k = 0; k < 8; ++k) { acc0[k] = 0.f; acc1[k] = 0.f; }
    int i = rs;
    for (; i + 1 < re; i += 2) {
        int s0 = col[i], s1 = col[i + 1];
        float es0 = e_src[s0 * H + head];
        float es1 = e_src[s1 * H + head];
        u32x4 hv0 = *(const u32x4*)(h + (size_t)s0 * 2560 + head * 256 + cpos * 8);
        u32x4 hv1 = *(const u32x4*)(h + (size_t)s1 * 2560 + head * 256 + cpos * 8);
        float w0 = __expf(lrelu02(es0 + edv));
        float w1 = __expf(lrelu02(es1 + edv));
        dn += w0 + w1;
        #pragma unroll
        for (int d = 0; d < 4; ++d) {
            acc0[2 * d]     += w0 * bf2f((unsigned short)(hv0[d] & 0xffffu));
            acc0[2 * d + 1] += w0 * bf2f((unsigned short)(hv0[d] >> 16));
            acc1[2 * d]     += w1 * bf2f((unsigned short)(hv1[d] & 0xffffu));
            acc1[2 * d + 1] += w1 * bf2f((unsigned short)(hv1[d] >> 16));
        }
    }
    if (i < re) {
        int s = col[i];
        float w = __expf(lrelu02(e_src[s * H + head] + edv));
        dn += w;
        u32x4 hv = *(const u32x4*)(h + (size_t)s * 2560 + head * 256 + cpos * 8);
        #pragma unroll
        for (int d = 0; d < 4; ++d) {
            acc0[2 * d]     += w * bf2f((unsigned short)(hv[d] & 0xffffu));
            acc0[2 * d + 1] += w * bf2f((unsigned short)(hv[d] >> 16));
        }
    }
    float rdn = 1.f / (dn + 1e-16f);

    const float* bp = bias + head * 256 + cpos * 8;
    u32x4 o;
    #pragma unroll
    for (int d = 0; d < 4; ++d) {
        float v0 = lrelu01((acc0[2 * d] + acc1[2 * d]) * rdn + bp[2 * d]);
        float v1 = lrelu01((acc0[2 * d + 1] + acc1[2 * d + 1]) * rdn + bp[2 * d + 1]);
        o[d] = (unsigned int)f2bf(v0) | ((unsigned int)f2bf(v1) << 16);
    }
    *(u32x4*)(out + (size_t)node * 2560 + head * 256 + cpos * 8) = o;
}

// Layer-2 (H=8, C=56): one wave per node, 56 active lanes (8 heads x 7 slots).
__global__ __launch_bounds__(64) void agg_l2(const unsigned short* __restrict__ h,
                                             const float* __restrict__ e_src,
                                             const float* __restrict__ e_dst,
                                             const int* __restrict__ row_ptr,
                                             const int* __restrict__ col,
                                             const float* __restrict__ bias,
                                             unsigned short* __restrict__ out) {
    const int H = 8;
    int node = blockIdx.x;
    int lane = threadIdx.x;
    bool act = lane < 56;
    int head = act ? (lane / 7) : 0;
    int cpos = act ? (lane - head * 7) : 0;
    int rs = row_ptr[node], re = row_ptr[node + 1];
    float edv = e_dst[node * H + head];

    float dn = 0.f;
    float acc0[8], acc1[8];
    #pragma unroll
    for (int k = 0; k < 8; ++k) { acc0[k] = 0.f; acc1[k] = 0.f; }
    int i = rs;
    for (; i + 1 < re; i += 2) {
        int s0 = col[i], s1 = col[i + 1];
        float es0 = e_src[s0 * H + head];
        float es1 = e_src[s1 * H + head];
        u32x4 hv0 = *(const u32x4*)(h + (size_t)s0 * 448 + head * 56 + cpos * 8);
        u32x4 hv1 = *(const u32x4*)(h + (size_t)s1 * 448 + head * 56 + cpos * 8);
        float w0 = __expf(lrelu02(es0 + edv));
        float w1 = __expf(lrelu02(es1 + edv));
        dn += w0 + w1;
        #pragma unroll
        for (int d = 0; d < 4; ++d) {
            acc0[2 * d]     += w0 * bf2f((unsigned short)(hv0[d] & 0xffffu));
            acc0[2 * d + 1] += w0 * bf2f((unsigned short)(hv0[d] >> 16));
            acc1[2 * d]     += w1 * bf2f((unsigned short)(hv1[d] & 0xffffu));
            acc1[2 * d + 1] += w1 * bf2f((unsigned short)(hv1[d] >> 16));
        }
    }
    if (i < re) {
        int s = col[i];
        float w = __expf(lrelu02(e_src[s * H + head] + edv));
        dn += w;
        u32x4 hv = *(const u32x4*)(h + (size_t)s * 448 + head * 56 + cpos * 8);
        #pragma unroll
        for (int d = 0; d < 4; ++d) {
            acc0[2 * d]     += w * bf2f((unsigned short)(hv[d] & 0xffffu));
            acc0[2 * d + 1] += w * bf2f((unsigned short)(hv[d] >> 16));
        }
    }
    float rdn = 1.f / (dn + 1e-16f);

    if (act) {
        const float* bp = bias + head * 56 + cpos * 8;
        u32x4 o;
        #pragma unroll
        for (int d = 0; d < 4; ++d) {
            float v0 = lrelu01((acc0[2 * d] + acc1[2 * d]) * rdn + bp[2 * d]);
            float v1 = lrelu01((acc0[2 * d + 1] + acc1[2 * d + 1]) * rdn + bp[2 * d + 1]);
            o[d] = (unsigned int)f2bf(v0) | ((unsigned int)f2bf(v1) << 16);
        }
        *(u32x4*)(out + (size_t)node * 448 + head * 56 + cpos * 8) = o;
    }
}

// Layer-3 (H=4, C=32): one wave per node, 16 active lanes.
__global__ __launch_bounds__(64) void agg_l3(const unsigned short* __restrict__ h,
                                             const float* __restrict__ e_src,
                                             const float* __restrict__ e_dst,
                                             const int* __restrict__ row_ptr,
                                             const int* __restrict__ col,
                                             const float* __restrict__ bias,
                                             unsigned short* __restrict__ out) {
    const int H = 4;
    int node = blockIdx.x;
    int lane = threadIdx.x;
    bool act = lane < 16;
    int head = (lane >> 2) & 3;
    int cpos = lane & 3;
    int rs = row_ptr[node], re = row_ptr[node + 1];
    float edv = e_dst[node * H + head];

    float dn = 0.f;
    float acc0[8], acc1[8];
    #pragma unroll
    for (int k = 0; k < 8; ++k) { acc0[k] = 0.f; acc1[k] = 0.f; }
    int i = rs;
    for (; i + 1 < re; i += 2) {
        int s0 = col[i], s1 = col[i + 1];
        float es0 = e_src[s0 * H + head];
        float es1 = e_src[s1 * H + head];
        u32x4 hv0 = *(const u32x4*)(h + (size_t)s0 * 128 + head * 32 + cpos * 8);
        u32x4 hv1 = *(const u32x4*)(h + (size_t)s1 * 128 + head * 32 + cpos * 8);
        float w0 = __expf(lrelu02(es0 + edv));
        float w1 = __expf(lrelu02(es1 + edv));
        dn += w0 + w1;
        #pragma unroll
        for (int d = 0; d < 4; ++d) {
            acc0[2 * d]     += w0 * bf2f((unsigned short)(hv0[d] & 0xffffu));
            acc0[2 * d + 1] += w0 * bf2f((unsigned short)(hv0[d] >> 16));
            acc1[2 * d]     += w1 * bf2f((unsigned short)(hv1[d] & 0xffffu));
            acc1[2 * d + 1] += w1 * bf2f((unsigned short)(hv1[d] >> 16));
        }
    }
    if (i < re) {
        int s = col[i];
        float w = __expf(lrelu02(e_src[s * H + head] + edv));
        dn += w;
        u32x4 hv = *(const u32x4*)(h + (size_t)s * 128 + head * 32 + cpos * 8);
        #pragma unroll
        for (int d = 0; d < 4; ++d) {
            acc0[2 * d]     += w * bf2f((unsigned short)(hv[d] & 0xffffu));
            acc0[2 * d + 1] += w * bf2f((unsigned short)(hv[d] >> 16));
        }
    }
    float rdn = 1.f / (dn + 1e-16f);

    if (act) {
        const float* bp = bias + head * 32 + cpos * 8;
        u32x4 o;
        #pragma unroll
        for (int d = 0; d < 4; ++d) {
            float v0 = lrelu01((acc0[2 * d] + acc1[2 * d]) * rdn + bp[2 * d]);
            float v1 = lrelu01((acc0[2 * d + 1] + acc1[2 * d + 1]) * rdn + bp[2 * d + 1]);
            o[d] = (unsigned int)f2bf(v0) | ((unsigned int)f2bf(v1) << 16);
        }
        *(u32x4*)(out + (size_t)node * 128 + head * 32 + cpos * 8) = o;
    }
}

// Layer-4 fused: aggregate (H=1, C=16) + bias + LeakyReLU(0.1) + row softmax.
__global__ __launch_bounds__(64) void agg4_softmax(const unsigned int* __restrict__ h2,
                                                   const float* __restrict__ e_src,
                                                   const float* __restrict__ e_dst,
                                                   const int* __restrict__ row_ptr,
                                                   const int* __restrict__ col,
                                                   const float* __restrict__ bias,
                                                   float* __restrict__ out) {
    int node = blockIdx.x;
    int lane = threadIdx.x;
    int cpos = lane & 7;
    int rs = row_ptr[node], re = row_ptr[node + 1];
    float edv = e_dst[node];

    float dn = 0.f, a0 = 0.f, a1 = 0.f;
    for (int i = rs; i < re; ++i) {
        int s = col[i];
        float w = __expf(lrelu02(e_src[s] + edv));
        dn += w;
        unsigned int hv = h2[(size_t)s * 8 + cpos];
        a0 += w * bf2f((unsigned short)(hv & 0xffffu));
        a1 += w * bf2f((unsigned short)(hv >> 16));
    }
    float rdn = 1.f / (dn + 1e-16f);
    float v0 = lrelu01(a0 * rdn + bias[2 * cpos]);
    float v1 = lrelu01(a1 * rdn + bias[2 * cpos + 1]);

    // softmax over 16 values per aligned 8-lane group
    float m = fmaxf(v0, v1);
    #pragma unroll
    for (int off = 4; off; off >>= 1) m = fmaxf(m, __shfl_xor(m, off));
    float e0 = __expf(v0 - m), e1 = __expf(v1 - m);
    float s = e0 + e1;
    #pragma unroll
    for (int off = 4; off; off >>= 1) s += __shfl_xor(s, off);
    float r = 1.f / s;
    if (lane < 8) {
        out[node * 16 + 2 * cpos]     = e0 * r;
        out[node * 16 + 2 * cpos + 1] = e1 * r;
    }
}

// ---------------------------------------------------------------------------
extern "C" void kernel_launch(void* const* d_in, const int* in_sizes, int n_in,
                              void* d_out, int out_size, void* d_ws, size_t ws_size,
                              hipStream_t stream) {
    const float* x   = (const float*)d_in[0];
    const int*   ei  = (const int*)d_in[1];
    const float* W1  = (const float*)d_in[2];
    const float* as1 = (const float*)d_in[3];
    const float* ad1 = (const float*)d_in[4];
    const float* b1  = (const float*)d_in[5];
    const float* W2  = (const float*)d_in[6];
    const float* as2 = (const float*)d_in[7];
    const float* ad2 = (const float*)d_in[8];
    const float* b2  = (const float*)d_in[9];
    const float* W3  = (const float*)d_in[10];
    const float* as3 = (const float*)d_in[11];
    const float* ad3 = (const float*)d_in[12];
    const float* b3  = (const float*)d_in[13];
    const float* W4  = (const float*)d_in[14];
    const float* as4 = (const float*)d_in[15];
    const float* ad4 = (const float*)d_in[16];
    const float* b4  = (const float*)d_in[17];

    char* ws = (char*)d_ws;
    size_t off = 0;
    auto alloc = [&](size_t bytes) -> void* {
        void* p = ws + off;
        off = (off + bytes + 255) & ~(size_t)255;
        return p;
    };
    unsigned short* hbuf = (unsigned short*)alloc((size_t)MPAD * 2560 * sizeof(short)); // GEMM out / attn input
    unsigned short* abuf = (unsigned short*)alloc((size_t)MPAD * 2560 * sizeof(short)); // bf16 GEMM A input
    unsigned short* pbuf = (unsigned short*)alloc((size_t)2 * MPAD * 448 * sizeof(short)); // split-K bf16 partials
    unsigned short* W1t  = (unsigned short*)alloc((size_t)2560 * 128 * sizeof(short));
    unsigned short* W2t  = (unsigned short*)alloc((size_t)448 * 2560 * sizeof(short));
    unsigned short* W3t  = (unsigned short*)alloc((size_t)128 * 448 * sizeof(short));
    float* e_src  = (float*)alloc((size_t)NNODES * 10 * sizeof(float));
    float* e_dst  = (float*)alloc((size_t)NNODES * 10 * sizeof(float));
    int* indeg    = (int*)alloc(NNODES * sizeof(int));
    int* row_ptr  = (int*)alloc((NNODES + 1) * sizeof(int));
    int* cursor   = (int*)alloc(NNODES * sizeof(int));
    int* col      = (int*)alloc(ETOT * sizeof(int));
    (void)ws_size;

    // ---- CSR build ----
    hipMemsetAsync(indeg, 0, NNODES * sizeof(int), stream);
    int eb = (ETOT + 255) / 256;
    count_deg<<<eb, 256, 0, stream>>>(ei, indeg, NEDGES, NNODES);
    scan_rowptr<<<1, 1024, 0, stream>>>(indeg, row_ptr, cursor, NNODES);
    scatter_edges<<<eb, 256, 0, stream>>>(ei, cursor, col, NEDGES, NNODES);

    // ---- weight transposes (single dispatch) + x convert ----
    transpose_all<<<1496, dim3(32, 8), 0, stream>>>(W1, W2, W3, W1t, W2t, W3t);
    convert_bf16<<<(NNODES * 128 + 255) / 256, 256, 0, stream>>>(x, abuf, NNODES * 128);

    const int Mb = MPAD / GBM;   // 79

    // ---- Layer 1: 128 -> 10 heads x 256, concat ----
    gemm_mfma<128, false><<<dim3(2560 / 128, Mb), 256, 0, stream>>>(
        abuf, W1t, hbuf, 2560, 1, 128, 128);
    attn_halves<<<NNODES * 10, 64, 0, stream>>>(hbuf, as1, ad1, e_src, e_dst, 10, 256);
    agg_l1<<<NNODES * 5, 64, 0, stream>>>(hbuf, e_src, e_dst, row_ptr, col, b1, abuf);

    // ---- Layer 2: 2560 -> 8 heads x 56 (XCD-swizzled, split-K=2, bf16 partials) ----
    gemm_mfma<64, true><<<dim3(8 * 7 * 10, 2), 256, 0, stream>>>(
        abuf, W2t, pbuf, 448, 7, 2560, 1280);
    {
        int n2 = NNODES * 448 / 2;
        reduce2p<<<(n2 + 255) / 256, 256, 0, stream>>>(
            (const unsigned int*)pbuf, (unsigned int*)hbuf, n2);
    }
    attn_small<8, 56><<<NNODES, 64, 0, stream>>>(hbuf, as2, ad2, e_src, e_dst);
    agg_l2<<<NNODES, 64, 0, stream>>>(hbuf, e_src, e_dst, row_ptr, col, b2, abuf);

    // ---- Layer 3: 448 -> 4 heads x 32, concat ----
    gemm_mfma<64, false><<<dim3(2, Mb), 256, 0, stream>>>(
        abuf, W3t, hbuf, 128, 1, 448, 448);
    attn_small<4, 32><<<NNODES, 64, 0, stream>>>(hbuf, as3, ad3, e_src, e_dst);
    agg_l3<<<NNODES, 64, 0, stream>>>(hbuf, e_src, e_dst, row_ptr, col, b3, abuf);

    // ---- Layer 4: 128 -> 1 head x 16 (attn fused into GEMM) + softmax ----
    gemm4_attn<<<(NNODES + 15) / 16, 256, 0, stream>>>(
        abuf, W4, as4, ad4, hbuf, e_src, e_dst, NNODES);
    agg4_softmax<<<NNODES, 64, 0, stream>>>(
        (const unsigned int*)hbuf, e_src, e_dst, row_ptr, col, b4, (float*)d_out);
}

// Round 10
// 301.412 us; speedup vs baseline: 1.2157x; 1.1531x over previous
//
#include <hip/hip_runtime.h>
#include <math.h>

// Problem constants (match reference setup_inputs()).
#define NNODES 10000
#define MPAD   10112           // 79 * 128 (MFMA M-tile padding)
#define NEDGES 80000           // directed edges before self loops
#define ETOT   (NEDGES + NNODES)

typedef __attribute__((ext_vector_type(4))) float f32x4;
typedef __attribute__((ext_vector_type(8))) short bf16x8;
typedef __attribute__((ext_vector_type(4))) unsigned int u32x4;

__device__ inline unsigned short f2bf(float f) {
    unsigned int u = __float_as_uint(f);
    unsigned int r = (u + 0x7fffu + ((u >> 16) & 1u)) >> 16;
    return (unsigned short)r;
}
__device__ inline float bf2f(unsigned short h) {
    return __uint_as_float(((unsigned int)h) << 16);
}
__device__ inline float lrelu01(float v) { return (v > 0.f) ? v : 0.1f * v; }
__device__ inline float lrelu02(float v) { return (v > 0.f) ? v : 0.2f * v; }

// ---------------------------------------------------------------------------
// CSR build (group edges by destination). Rebuilt every launch (ws poisoned).
// ---------------------------------------------------------------------------
__global__ void count_deg(const int* __restrict__ ei, int* __restrict__ indeg,
                          int E, int n) {
    int i = blockIdx.x * blockDim.x + threadIdx.x;
    if (i >= E + n) return;
    int dst = (i < E) ? ei[E + i] : (i - E);
    atomicAdd(&indeg[dst], 1);
}

__global__ void scan_rowptr(const int* __restrict__ indeg, int* __restrict__ row_ptr,
                            int* __restrict__ cursor, int n) {
    __shared__ int sums[1024];
    int tid = threadIdx.x;
    int per = (n + 1023) / 1024;
    int start = tid * per;
    int end = start + per; if (end > n) end = n;
    int s = 0;
    for (int i = start; i < end; ++i) s += indeg[i];
    sums[tid] = s;
    __syncthreads();
    for (int off = 1; off < 1024; off <<= 1) {
        int v = (tid >= off) ? sums[tid - off] : 0;
        __syncthreads();
        sums[tid] += v;
        __syncthreads();
    }
    int excl = (tid == 0) ? 0 : sums[tid - 1];
    for (int i = start; i < end; ++i) {
        row_ptr[i] = excl;
        cursor[i]  = excl;
        excl += indeg[i];
    }
    if (tid == 1023) row_ptr[n] = sums[1023];
}

__global__ void scatter_edges(const int* __restrict__ ei, int* __restrict__ cursor,
                              int* __restrict__ col, int E, int n) {
    int i = blockIdx.x * blockDim.x + threadIdx.x;
    if (i >= E + n) return;
    int src, dst;
    if (i < E) { src = ei[i]; dst = ei[E + i]; }
    else       { src = i - E; dst = i - E; }
    int pos = atomicAdd(&cursor[dst], 1);
    col[pos] = src;
}

// ---------------------------------------------------------------------------
// fp32 -> bf16 elementwise convert (for x).
// ---------------------------------------------------------------------------
__global__ void convert_bf16(const float* __restrict__ in, unsigned short* __restrict__ out,
                             int n) {
    int i = blockIdx.x * blockDim.x + threadIdx.x;
    if (i < n) out[i] = f2bf(in[i]);
}

// All three weight transposes in ONE dispatch. W[K][N] fp32 -> Wt[N][K] bf16.
__global__ void transpose_all(const float* __restrict__ W1, const float* __restrict__ W2,
                              const float* __restrict__ W3,
                              unsigned short* __restrict__ W1t,
                              unsigned short* __restrict__ W2t,
                              unsigned short* __restrict__ W3t) {
    __shared__ float t[32][33];
    int b = blockIdx.x;
    const float* W; unsigned short* Wt; int K, N, nb, kb;
    if (b < 320)       { W = W1; Wt = W1t; K = 128;  N = 2560; int i = b;        nb = i % 80; kb = i / 80; }
    else if (b < 1440) { W = W2; Wt = W2t; K = 2560; N = 448;  int i = b - 320;  nb = i % 14; kb = i / 14; }
    else               { W = W3; Wt = W3t; K = 448;  N = 128;  int i = b - 1440; nb = i % 4;  kb = i / 4;  }
    int kb32 = kb * 32, nb32 = nb * 32;
    int tx = threadIdx.x, ty = threadIdx.y;   // 32 x 8
    #pragma unroll
    for (int i = 0; i < 32; i += 8)
        t[ty + i][tx] = W[(size_t)(kb32 + ty + i) * N + nb32 + tx];
    __syncthreads();
    #pragma unroll
    for (int i = 0; i < 32; i += 8)
        Wt[(size_t)(nb32 + ty + i) * K + kb32 + tx] = f2bf(t[tx][ty + i]);
}

// ---------------------------------------------------------------------------
// wsrc[h,k] = sum_c W1[k, h*256+c] * as1[h,c]; same for wdst with ad1.
// 1280 threads, each streams one 1 KB W1 row-slice (float4).
// ---------------------------------------------------------------------------
__global__ void make_wsd(const float* __restrict__ W1, const float* __restrict__ as1,
                         const float* __restrict__ ad1,
                         float* __restrict__ wsrc, float* __restrict__ wdst) {
    int idx = blockIdx.x * blockDim.x + threadIdx.x;
    if (idx >= 1280) return;
    int h = idx >> 7, k = idx & 127;
    const float* wrow = W1 + (size_t)k * 2560 + h * 256;
    const float* as = as1 + h * 256;
    const float* ad = ad1 + h * 256;
    float s = 0.f, d = 0.f;
    for (int c = 0; c < 256; c += 4) {
        f32x4 w = *(const f32x4*)&wrow[c];
        f32x4 a = *(const f32x4*)&as[c];
        f32x4 b = *(const f32x4*)&ad[c];
        #pragma unroll
        for (int j = 0; j < 4; ++j) { s += w[j] * a[j]; d += w[j] * b[j]; }
    }
    wsrc[h * 128 + k] = s;
    wdst[h * 128 + k] = d;
}

// ---------------------------------------------------------------------------
// e_src[n,h] = x[n]·wsrc[h], e_dst[n,h] = x[n]·wdst[h].  4 nodes per block
// (4 waves); wsrc/wdst staged in LDS.
// ---------------------------------------------------------------------------
__global__ __launch_bounds__(256) void e1_dots(const unsigned short* __restrict__ xb,
                                               const float* __restrict__ wsrc,
                                               const float* __restrict__ wdst,
                                               float* __restrict__ e_src,
                                               float* __restrict__ e_dst, int M) {
    __shared__ float ws[1280], wd[1280];
    int tid = threadIdx.x;
    for (int i = tid; i < 1280; i += 256) { ws[i] = wsrc[i]; wd[i] = wdst[i]; }
    __syncthreads();
    int node = blockIdx.x * 4 + (tid >> 6);
    int lane = tid & 63;
    if (node >= M) return;
    unsigned int xv = ((const unsigned int*)xb)[node * 64 + lane];
    float v0 = bf2f((unsigned short)(xv & 0xffffu));
    float v1 = bf2f((unsigned short)(xv >> 16));
    #pragma unroll
    for (int h = 0; h < 10; ++h) {
        float ps = v0 * ws[h * 128 + 2 * lane] + v1 * ws[h * 128 + 2 * lane + 1];
        float pd = v0 * wd[h * 128 + 2 * lane] + v1 * wd[h * 128 + 2 * lane + 1];
        #pragma unroll
        for (int off = 32; off; off >>= 1) {
            ps += __shfl_down(ps, off);
            pd += __shfl_down(pd, off);
        }
        if (lane == 0) { e_src[node * 10 + h] = ps; e_dst[node * 10 + h] = pd; }
    }
}

// ---------------------------------------------------------------------------
// Layer-1 x-aggregation: xagg[d,h,:] = sum_s alpha[d,s,h] * x[s,:].
// One wave per dst node, ALL 10 heads: per edge 1 x-dword/lane + lanes 0-9
// compute the 10 unnormalized weights, shfl-broadcast. Softmax w/o max
// subtraction (m=0, mathematically identical; logits bounded).
// ---------------------------------------------------------------------------
__global__ __launch_bounds__(64) void agg_x(const unsigned short* __restrict__ xb,
                                            const float* __restrict__ e_src,
                                            const float* __restrict__ e_dst,
                                            const int* __restrict__ row_ptr,
                                            const int* __restrict__ col,
                                            unsigned short* __restrict__ xagg) {
    int node = blockIdx.x;
    int lane = threadIdx.x;
    int rs = row_ptr[node], re = row_ptr[node + 1];
    float edv = (lane < 10) ? e_dst[node * 10 + lane] : 0.f;

    float dn = 0.f;
    float a0[10], a1[10];
    #pragma unroll
    for (int h = 0; h < 10; ++h) { a0[h] = 0.f; a1[h] = 0.f; }
    for (int i = rs; i < re; ++i) {
        int s = col[i];
        float w = 0.f;
        if (lane < 10) w = __expf(lrelu02(e_src[s * 10 + lane] + edv));
        dn += w;
        unsigned int xv = ((const unsigned int*)xb)[s * 64 + lane];
        float v0 = bf2f((unsigned short)(xv & 0xffffu));
        float v1 = bf2f((unsigned short)(xv >> 16));
        #pragma unroll
        for (int h = 0; h < 10; ++h) {
            float wh = __shfl(w, h);
            a0[h] += wh * v0;
            a1[h] += wh * v1;
        }
    }
    #pragma unroll
    for (int h = 0; h < 10; ++h) {
        float rdn = 1.f / (__shfl(dn, h) + 1e-16f);
        unsigned int o = (unsigned int)f2bf(a0[h] * rdn) |
                         ((unsigned int)f2bf(a1[h] * rdn) << 16);
        ((unsigned int*)xagg)[((size_t)node * 10 + h) * 64 + lane] = o;
    }
}

// ---------------------------------------------------------------------------
// Layer-1 batched per-head GEMM: x2[n, h*256+c] = lrelu01(xagg[n,h,:]·W1t[h*256+c,:]
// + b1[h*256+c]).  Grid (20, 79): blockIdx.x = h*2 + ntile. Tile 128x128.
// ---------------------------------------------------------------------------
#define GBM 128
#define GBK 32
__global__ __launch_bounds__(256) void gemm_l1(const unsigned short* __restrict__ A,
                                               const unsigned short* __restrict__ Bt,
                                               const float* __restrict__ bias,
                                               unsigned short* __restrict__ C) {
    constexpr int NT = 128, NI = 4, K = 128;
    __shared__ short As[GBM * GBK];
    __shared__ short Bs[NT * GBK];
    int h  = blockIdx.x >> 1;
    int nt = blockIdx.x & 1;
    int bn = h * 256 + nt * 128;
    int bm = blockIdx.y * GBM;
    int tid  = threadIdx.x;
    int wave = tid >> 6, lane = tid & 63;
    int wr = wave >> 1, wc = wave & 1;
    int lrow  = lane >> 2;
    int lkoff = (lane & 3) * 8;
    int row16 = lane & 15;
    int q8    = (lane >> 4) * 8;

    f32x4 acc[4][NI];
    #pragma unroll
    for (int mi = 0; mi < 4; ++mi)
        #pragma unroll
        for (int ni = 0; ni < NI; ++ni) acc[mi][ni] = (f32x4){0.f, 0.f, 0.f, 0.f};

    for (int k0 = 0; k0 < K; k0 += GBK) {
        #pragma unroll
        for (int i = 0; i < 2; ++i) {
            int c = i * 4 + wave;
            int row = c * 16 + lrow;
            const unsigned short* gp = A + ((size_t)(bm + row) * 10 + h) * K + k0 + lkoff;
            __builtin_amdgcn_global_load_lds(
                (const __attribute__((address_space(1))) void*)gp,
                (__attribute__((address_space(3))) void*)&As[c * 512], 16, 0, 0);
        }
        #pragma unroll
        for (int i = 0; i < 2; ++i) {
            int c = i * 4 + wave;
            int row = c * 16 + lrow;
            const unsigned short* gp = Bt + (size_t)(bn + row) * K + k0 + lkoff;
            __builtin_amdgcn_global_load_lds(
                (const __attribute__((address_space(1))) void*)gp,
                (__attribute__((address_space(3))) void*)&Bs[c * 512], 16, 0, 0);
        }
        __syncthreads();
        bf16x8 af[4], bfr[NI];
        #pragma unroll
        for (int mi = 0; mi < 4; ++mi)
            af[mi] = *(const bf16x8*)&As[(wr * 64 + mi * 16 + row16) * GBK + q8];
        #pragma unroll
        for (int ni = 0; ni < NI; ++ni)
            bfr[ni] = *(const bf16x8*)&Bs[(wc * 64 + ni * 16 + row16) * GBK + q8];
        #pragma unroll
        for (int mi = 0; mi < 4; ++mi)
            #pragma unroll
            for (int ni = 0; ni < NI; ++ni)
                acc[mi][ni] = __builtin_amdgcn_mfma_f32_16x16x32_bf16(
                    af[mi], bfr[ni], acc[mi][ni], 0, 0, 0);
        __syncthreads();
    }

    int rbase = bm + wr * 64 + (lane >> 4) * 4;
    #pragma unroll
    for (int mi = 0; mi < 4; ++mi)
        #pragma unroll
        for (int ni = 0; ni < NI; ++ni) {
            int cc = bn + wc * 64 + ni * 16 + (lane & 15);
            float b = bias[cc];
            #pragma unroll
            for (int r = 0; r < 4; ++r) {
                float v = lrelu01(acc[mi][ni][r] + b);
                C[(size_t)(rbase + mi * 16 + r) * 2560 + cc] = f2bf(v);
            }
        }
}

// ---------------------------------------------------------------------------
// Generic bf16 MFMA GEMM (layers 2/3): C = A[MPAD][K] @ Bt[N][K]^T.
// SWIZ: 1-D grid.x (XCD-local M-tiles) + split-K via blockIdx.y (bf16 partials
// at z*MPAD*N). Non-SWIZ: 2-D grid, full K.
// ---------------------------------------------------------------------------
template <int NT, bool SWIZ>
__global__ __launch_bounds__(256) void gemm_mfma(const unsigned short* __restrict__ A,
                                                 const unsigned short* __restrict__ Bt,
                                                 unsigned short* __restrict__ C,
                                                 int N, int nbn, int K, int klen) {
    constexpr int NI = NT / 32;
    __shared__ short As[GBM * GBK];
    __shared__ short Bs[NT * GBK];
    int bn, bm, kbeg, kend;
    size_t zoff = 0;
    if constexpr (SWIZ) {
        int b = blockIdx.x;
        int x = b & 7, t = b >> 3;
        int j = x + 8 * (t / nbn);
        if (j >= MPAD / GBM) return;
        bn = (t % nbn) * NT;
        bm = j * GBM;
        kbeg = blockIdx.y * klen;
        kend = kbeg + klen;
        zoff = (size_t)blockIdx.y * MPAD * N;
    } else {
        bn = blockIdx.x * NT;
        bm = blockIdx.y * GBM;
        kbeg = 0; kend = K;
    }
    int tid  = threadIdx.x;
    int wave = tid >> 6, lane = tid & 63;
    int wr = wave >> 1, wc = wave & 1;
    int lrow  = lane >> 2;
    int lkoff = (lane & 3) * 8;
    int row16 = lane & 15;
    int q8    = (lane >> 4) * 8;

    f32x4 acc[4][NI];
    #pragma unroll
    for (int mi = 0; mi < 4; ++mi)
        #pragma unroll
        for (int ni = 0; ni < NI; ++ni) acc[mi][ni] = (f32x4){0.f, 0.f, 0.f, 0.f};

    for (int k0 = kbeg; k0 < kend; k0 += GBK) {
        #pragma unroll
        for (int i = 0; i < 2; ++i) {
            int c = i * 4 + wave;
            int row = c * 16 + lrow;
            const unsigned short* gp = A + (size_t)(bm + row) * K + k0 + lkoff;
            __builtin_amdgcn_global_load_lds(
                (const __attribute__((address_space(1))) void*)gp,
                (__attribute__((address_space(3))) void*)&As[c * 512], 16, 0, 0);
        }
        #pragma unroll
        for (int i = 0; i < NT / 64; ++i) {
            int c = i * 4 + wave;
            int row = c * 16 + lrow;
            const unsigned short* gp = Bt + (size_t)(bn + row) * K + k0 + lkoff;
            __builtin_amdgcn_global_load_lds(
                (const __attribute__((address_space(1))) void*)gp,
                (__attribute__((address_space(3))) void*)&Bs[c * 512], 16, 0, 0);
        }
        __syncthreads();
        bf16x8 af[4], bfr[NI];
        #pragma unroll
        for (int mi = 0; mi < 4; ++mi)
            af[mi] = *(const bf16x8*)&As[(wr * 64 + mi * 16 + row16) * GBK + q8];
        #pragma unroll
        for (int ni = 0; ni < NI; ++ni)
            bfr[ni] = *(const bf16x8*)&Bs[(wc * (NT / 2) + ni * 16 + row16) * GBK + q8];
        #pragma unroll
        for (int mi = 0; mi < 4; ++mi)
            #pragma unroll
            for (int ni = 0; ni < NI; ++ni)
                acc[mi][ni] = __builtin_amdgcn_mfma_f32_16x16x32_bf16(
                    af[mi], bfr[ni], acc[mi][ni], 0, 0, 0);
        __syncthreads();
    }

    int rbase = bm + wr * 64 + (lane >> 4) * 4;
    int cbase = bn + wc * (NT / 2) + (lane & 15);
    #pragma unroll
    for (int mi = 0; mi < 4; ++mi)
        #pragma unroll
        for (int ni = 0; ni < NI; ++ni)
            #pragma unroll
            for (int r = 0; r < 4; ++r)
                C[zoff + (size_t)(rbase + mi * 16 + r) * N + cbase + ni * 16] =
                    f2bf(acc[mi][ni][r]);
}

// Sum two bf16x2-packed split-K partials -> packed bf16x2.
__global__ void reduce2p(const unsigned int* __restrict__ P, unsigned int* __restrict__ out,
                         int n2) {
    int i = blockIdx.x * blockDim.x + threadIdx.x;
    if (i >= n2) return;
    unsigned int a = P[i];
    unsigned int b = P[(size_t)MPAD * 448 / 2 + i];
    float lo = bf2f((unsigned short)(a & 0xffffu)) + bf2f((unsigned short)(b & 0xffffu));
    float hi = bf2f((unsigned short)(a >> 16))     + bf2f((unsigned short)(b >> 16));
    out[i] = (unsigned int)f2bf(lo) | ((unsigned int)f2bf(hi) << 16);
}

// ---------------------------------------------------------------------------
// Layer-4 GEMM fused with attention halves.
// ---------------------------------------------------------------------------
__global__ __launch_bounds__(256) void gemm4_attn(const unsigned short* __restrict__ A,
                                                  const float* __restrict__ W,
                                                  const float* __restrict__ as4,
                                                  const float* __restrict__ ad4,
                                                  unsigned short* __restrict__ C,
                                                  float* __restrict__ e_src,
                                                  float* __restrict__ e_dst, int M) {
    __shared__ float Ws[128 * 16];
    int tid = threadIdx.x;
    for (int i = tid; i < 2048; i += 256) Ws[i] = W[i];
    __syncthreads();
    int node = blockIdx.x * 16 + (tid >> 4);
    int n = tid & 15;
    if (node >= M) return;
    const unsigned short* ap = A + (size_t)node * 128;
    float acc = 0.f;
    #pragma unroll 8
    for (int k = 0; k < 128; ++k)
        acc += bf2f(ap[k]) * Ws[k * 16 + n];
    C[(size_t)node * 16 + n] = f2bf(acc);
    float vs = acc * as4[n];
    float vd = acc * ad4[n];
    #pragma unroll
    for (int off = 1; off < 16; off <<= 1) {
        vs += __shfl_xor(vs, off);
        vd += __shfl_xor(vd, off);
    }
    if (n == 0) { e_src[node] = vs; e_dst[node] = vd; }
}

// ---------------------------------------------------------------------------
// attn halves, small C (layers 2/3): one wave per NODE, all heads in-wave.
// ---------------------------------------------------------------------------
template <int H, int C>
__global__ __launch_bounds__(64) void attn_small(const unsigned short* __restrict__ h,
                                                 const float* __restrict__ a_src,
                                                 const float* __restrict__ a_dst,
                                                 float* __restrict__ e_src,
                                                 float* __restrict__ e_dst) {
    constexpr int LPH = 64 / H;
    constexpr int CPL = C / LPH;
    int node = blockIdx.x;
    int lane = threadIdx.x;
    int head = lane / LPH;
    int k = lane - head * LPH;
    const unsigned short* hp = h + (size_t)node * (H * C) + head * C + k * CPL;
    const float* as = a_src + head * C + k * CPL;
    const float* ad = a_dst + head * C + k * CPL;
    float s1 = 0.f, s2 = 0.f;
    #pragma unroll
    for (int c = 0; c < CPL; ++c) {
        float v = bf2f(hp[c]);
        s1 += v * as[c];
        s2 += v * ad[c];
    }
    #pragma unroll
    for (int off = LPH / 2; off; off >>= 1) {
        s1 += __shfl_down(s1, off);
        s2 += __shfl_down(s2, off);
    }
    if (k == 0) { e_src[node * H + head] = s1; e_dst[node * H + head] = s2; }
}

// ---------------------------------------------------------------------------
// Layer-2 (H=8, C=56) aggregation: one wave per node, 56 active lanes.
// ---------------------------------------------------------------------------
__global__ __launch_bounds__(64) void agg_l2(const unsigned short* __restrict__ h,
                                             const float* __restrict__ e_src,
                                             const float* __restrict__ e_dst,
                                             const int* __restrict__ row_ptr,
                                             const int* __restrict__ col,
                                             const float* __restrict__ bias,
                                             unsigned short* __restrict__ out) {
    const int H = 8;
    int node = blockIdx.x;
    int lane = threadIdx.x;
    bool act = lane < 56;
    int head = act ? (lane / 7) : 0;
    int cpos = act ? (lane - head * 7) : 0;
    int rs = row_ptr[node], re = row_ptr[node + 1];
    float edv = e_dst[node * H + head];

    float dn = 0.f;
    float acc0[8], acc1[8];
    #pragma unroll
    for (int k = 0; k < 8; ++k) { acc0[k] = 0.f; acc1[k] = 0.f; }
    int i = rs;
    for (; i + 1 < re; i += 2) {
        int s0 = col[i], s1 = col[i + 1];
        float es0 = e_src[s0 * H + head];
        float es1 = e_src[s1 * H + head];
        u32x4 hv0 = *(const u32x4*)(h + (size_t)s0 * 448 + head * 56 + cpos * 8);
        u32x4 hv1 = *(const u32x4*)(h + (size_t)s1 * 448 + head * 56 + cpos * 8);
        float w0 = __expf(lrelu02(es0 + edv));
        float w1 = __expf(lrelu02(es1 + edv));
        dn += w0 + w1;
        #pragma unroll
        for (int d = 0; d < 4; ++d) {
            acc0[2 * d]     += w0 * bf2f((unsigned short)(hv0[d] & 0xffffu));
            acc0[2 * d + 1] += w0 * bf2f((unsigned short)(hv0[d] >> 16));
            acc1[2 * d]     += w1 * bf2f((unsigned short)(hv1[d] & 0xffffu));
            acc1[2 * d + 1] += w1 * bf2f((unsigned short)(hv1[d] >> 16));
        }
    }
    if (i < re) {
        int s = col[i];
        float w = __expf(lrelu02(e_src[s * H + head] + edv));
        dn += w;
        u32x4 hv = *(const u32x4*)(h + (size_t)s * 448 + head * 56 + cpos * 8);
        #pragma unroll
        for (int d = 0; d < 4; ++d) {
            acc0[2 * d]     += w * bf2f((unsigned short)(hv[d] & 0xffffu));
            acc0[2 * d + 1] += w * bf2f((unsigned short)(hv[d] >> 16));
        }
    }
    float rdn = 1.f / (dn + 1e-16f);

    if (act) {
        const float* bp = bias + head * 56 + cpos * 8;
        u32x4 o;
        #pragma unroll
        for (int d = 0; d < 4; ++d) {
            float v0 = lrelu01((acc0[2 * d] + acc1[2 * d]) * rdn + bp[2 * d]);
            float v1 = lrelu01((acc0[2 * d + 1] + acc1[2 * d + 1]) * rdn + bp[2 * d + 1]);
            o[d] = (unsigned int)f2bf(v0) | ((unsigned int)f2bf(v1) << 16);
        }
        *(u32x4*)(out + (size_t)node * 448 + head * 56 + cpos * 8) = o;
    }
}

// Layer-3 (H=4, C=32): one wave per node, 16 active lanes.
__global__ __launch_bounds__(64) void agg_l3(const unsigned short* __restrict__ h,
                                             const float* __restrict__ e_src,
                                             const float* __restrict__ e_dst,
                                             const int* __restrict__ row_ptr,
                                             const int* __restrict__ col,
                                             const float* __restrict__ bias,
                                             unsigned short* __restrict__ out) {
    const int H = 4;
    int node = blockIdx.x;
    int lane = threadIdx.x;
    bool act = lane < 16;
    int head = (lane >> 2) & 3;
    int cpos = lane & 3;
    int rs = row_ptr[node], re = row_ptr[node + 1];
    float edv = e_dst[node * H + head];

    float dn = 0.f;
    float acc0[8], acc1[8];
    #pragma unroll
    for (int k = 0; k < 8; ++k) { acc0[k] = 0.f; acc1[k] = 0.f; }
    int i = rs;
    for (; i + 1 < re; i += 2) {
        int s0 = col[i], s1 = col[i + 1];
        float es0 = e_src[s0 * H + head];
        float es1 = e_src[s1 * H + head];
        u32x4 hv0 = *(const u32x4*)(h + (size_t)s0 * 128 + head * 32 + cpos * 8);
        u32x4 hv1 = *(const u32x4*)(h + (size_t)s1 * 128 + head * 32 + cpos * 8);
        float w0 = __expf(lrelu02(es0 + edv));
        float w1 = __expf(lrelu02(es1 + edv));
        dn += w0 + w1;
        #pragma unroll
        for (int d = 0; d < 4; ++d) {
            acc0[2 * d]     += w0 * bf2f((unsigned short)(hv0[d] & 0xffffu));
            acc0[2 * d + 1] += w0 * bf2f((unsigned short)(hv0[d] >> 16));
            acc1[2 * d]     += w1 * bf2f((unsigned short)(hv1[d] & 0xffffu));
            acc1[2 * d + 1] += w1 * bf2f((unsigned short)(hv1[d] >> 16));
        }
    }
    if (i < re) {
        int s = col[i];
        float w = __expf(lrelu02(e_src[s * H + head] + edv));
        dn += w;
        u32x4 hv = *(const u32x4*)(h + (size_t)s * 128 + head * 32 + cpos * 8);
        #pragma unroll
        for (int d = 0; d < 4; ++d) {
            acc0[2 * d]     += w * bf2f((unsigned short)(hv[d] & 0xffffu));
            acc0[2 * d + 1] += w * bf2f((unsigned short)(hv[d] >> 16));
        }
    }
    float rdn = 1.f / (dn + 1e-16f);

    if (act) {
        const float* bp = bias + head * 32 + cpos * 8;
        u32x4 o;
        #pragma unroll
        for (int d = 0; d < 4; ++d) {
            float v0 = lrelu01((acc0[2 * d] + acc1[2 * d]) * rdn + bp[2 * d]);
            float v1 = lrelu01((acc0[2 * d + 1] + acc1[2 * d + 1]) * rdn + bp[2 * d + 1]);
            o[d] = (unsigned int)f2bf(v0) | ((unsigned int)f2bf(v1) << 16);
        }
        *(u32x4*)(out + (size_t)node * 128 + head * 32 + cpos * 8) = o;
    }
}

// Layer-4 fused: aggregate (H=1, C=16) + bias + LeakyReLU(0.1) + row softmax.
__global__ __launch_bounds__(64) void agg4_softmax(const unsigned int* __restrict__ h2,
                                                   const float* __restrict__ e_src,
                                                   const float* __restrict__ e_dst,
                                                   const int* __restrict__ row_ptr,
                                                   const int* __restrict__ col,
                                                   const float* __restrict__ bias,
                                                   float* __restrict__ out) {
    int node = blockIdx.x;
    int lane = threadIdx.x;
    int cpos = lane & 7;
    int rs = row_ptr[node], re = row_ptr[node + 1];
    float edv = e_dst[node];

    float dn = 0.f, a0 = 0.f, a1 = 0.f;
    for (int i = rs; i < re; ++i) {
        int s = col[i];
        float w = __expf(lrelu02(e_src[s] + edv));
        dn += w;
        unsigned int hv = h2[(size_t)s * 8 + cpos];
        a0 += w * bf2f((unsigned short)(hv & 0xffffu));
        a1 += w * bf2f((unsigned short)(hv >> 16));
    }
    float rdn = 1.f / (dn + 1e-16f);
    float v0 = lrelu01(a0 * rdn + bias[2 * cpos]);
    float v1 = lrelu01(a1 * rdn + bias[2 * cpos + 1]);

    float m = fmaxf(v0, v1);
    #pragma unroll
    for (int off = 4; off; off >>= 1) m = fmaxf(m, __shfl_xor(m, off));
    float e0 = __expf(v0 - m), e1 = __expf(v1 - m);
    float s = e0 + e1;
    #pragma unroll
    for (int off = 4; off; off >>= 1) s += __shfl_xor(s, off);
    float r = 1.f / s;
    if (lane < 8) {
        out[node * 16 + 2 * cpos]     = e0 * r;
        out[node * 16 + 2 * cpos + 1] = e1 * r;
    }
}

// ---------------------------------------------------------------------------
extern "C" void kernel_launch(void* const* d_in, const int* in_sizes, int n_in,
                              void* d_out, int out_size, void* d_ws, size_t ws_size,
                              hipStream_t stream) {
    const float* x   = (const float*)d_in[0];
    const int*   ei  = (const int*)d_in[1];
    const float* W1  = (const float*)d_in[2];
    const float* as1 = (const float*)d_in[3];
    const float* ad1 = (const float*)d_in[4];
    const float* b1  = (const float*)d_in[5];
    const float* W2  = (const float*)d_in[6];
    const float* as2 = (const float*)d_in[7];
    const float* ad2 = (const float*)d_in[8];
    const float* b2  = (const float*)d_in[9];
    const float* W3  = (const float*)d_in[10];
    const float* as3 = (const float*)d_in[11];
    const float* ad3 = (const float*)d_in[12];
    const float* b3  = (const float*)d_in[13];
    const float* W4  = (const float*)d_in[14];
    const float* as4 = (const float*)d_in[15];
    const float* ad4 = (const float*)d_in[16];
    const float* b4  = (const float*)d_in[17];

    char* ws = (char*)d_ws;
    size_t off = 0;
    auto alloc = [&](size_t bytes) -> void* {
        void* p = ws + off;
        off = (off + bytes + 255) & ~(size_t)255;
        return p;
    };
    unsigned short* hbuf = (unsigned short*)alloc((size_t)MPAD * 2560 * sizeof(short)); // GEMM out / attn input
    unsigned short* abuf = (unsigned short*)alloc((size_t)MPAD * 2560 * sizeof(short)); // xb, then x2/x3/x4
    unsigned short* pbuf = (unsigned short*)alloc((size_t)2 * MPAD * 448 * sizeof(short)); // split-K partials
    unsigned short* xagg = (unsigned short*)alloc((size_t)MPAD * 10 * 128 * sizeof(short));
    unsigned short* W1t  = (unsigned short*)alloc((size_t)2560 * 128 * sizeof(short));
    unsigned short* W2t  = (unsigned short*)alloc((size_t)448 * 2560 * sizeof(short));
    unsigned short* W3t  = (unsigned short*)alloc((size_t)128 * 448 * sizeof(short));
    float* wsrc   = (float*)alloc((size_t)10 * 128 * sizeof(float));
    float* wdst   = (float*)alloc((size_t)10 * 128 * sizeof(float));
    float* e_src  = (float*)alloc((size_t)NNODES * 10 * sizeof(float));
    float* e_dst  = (float*)alloc((size_t)NNODES * 10 * sizeof(float));
    int* indeg    = (int*)alloc(NNODES * sizeof(int));
    int* row_ptr  = (int*)alloc((NNODES + 1) * sizeof(int));
    int* cursor   = (int*)alloc(NNODES * sizeof(int));
    int* col      = (int*)alloc(ETOT * sizeof(int));
    (void)ws_size;

    // ---- CSR build ----
    hipMemsetAsync(indeg, 0, NNODES * sizeof(int), stream);
    int eb = (ETOT + 255) / 256;
    count_deg<<<eb, 256, 0, stream>>>(ei, indeg, NEDGES, NNODES);
    scan_rowptr<<<1, 1024, 0, stream>>>(indeg, row_ptr, cursor, NNODES);
    scatter_edges<<<eb, 256, 0, stream>>>(ei, cursor, col, NEDGES, NNODES);

    // ---- weight prep + x convert ----
    transpose_all<<<1496, dim3(32, 8), 0, stream>>>(W1, W2, W3, W1t, W2t, W3t);
    make_wsd<<<20, 64, 0, stream>>>(W1, as1, ad1, wsrc, wdst);
    convert_bf16<<<(NNODES * 128 + 255) / 256, 256, 0, stream>>>(x, abuf, NNODES * 128);

    const int Mb = MPAD / GBM;   // 79

    // ---- Layer 1 (linearity-restructured): e1 -> agg_x -> batched GEMM ----
    e1_dots<<<(NNODES + 3) / 4, 256, 0, stream>>>(abuf, wsrc, wdst, e_src, e_dst, NNODES);
    agg_x<<<NNODES, 64, 0, stream>>>(abuf, e_src, e_dst, row_ptr, col, xagg);
    gemm_l1<<<dim3(20, Mb), 256, 0, stream>>>(xagg, W1t, b1, abuf);   // abuf = x2

    // ---- Layer 2: 2560 -> 8 heads x 56 (XCD-swizzled, split-K=2) ----
    gemm_mfma<64, true><<<dim3(8 * 7 * 10, 2), 256, 0, stream>>>(
        abuf, W2t, pbuf, 448, 7, 2560, 1280);
    {
        int n2 = NNODES * 448 / 2;
        reduce2p<<<(n2 + 255) / 256, 256, 0, stream>>>(
            (const unsigned int*)pbuf, (unsigned int*)hbuf, n2);
    }
    attn_small<8, 56><<<NNODES, 64, 0, stream>>>(hbuf, as2, ad2, e_src, e_dst);
    agg_l2<<<NNODES, 64, 0, stream>>>(hbuf, e_src, e_dst, row_ptr, col, b2, abuf);

    // ---- Layer 3: 448 -> 4 heads x 32 ----
    gemm_mfma<64, false><<<dim3(2, Mb), 256, 0, stream>>>(
        abuf, W3t, hbuf, 128, 1, 448, 448);
    attn_small<4, 32><<<NNODES, 64, 0, stream>>>(hbuf, as3, ad3, e_src, e_dst);
    agg_l3<<<NNODES, 64, 0, stream>>>(hbuf, e_src, e_dst, row_ptr, col, b3, abuf);

    // ---- Layer 4: 128 -> 1 head x 16 (attn fused into GEMM) + softmax ----
    gemm4_attn<<<(NNODES + 15) / 16, 256, 0, stream>>>(
        abuf, W4, as4, ad4, hbuf, e_src, e_dst, NNODES);
    agg4_softmax<<<NNODES, 64, 0, stream>>>(
        (const unsigned int*)hbuf, e_src, e_dst, row_ptr, col, b4, (float*)d_out);
}

// Round 11
// 299.756 us; speedup vs baseline: 1.2224x; 1.0055x over previous
//
#include <hip/hip_runtime.h>
#include <math.h>

// Problem constants (match reference setup_inputs()).
#define NNODES 10000
#define MPAD   10112           // 79 * 128 (MFMA M-tile padding)
#define NEDGES 80000           // directed edges before self loops
#define ETOT   (NEDGES + NNODES)

typedef __attribute__((ext_vector_type(4))) float f32x4;
typedef __attribute__((ext_vector_type(8))) short bf16x8;
typedef __attribute__((ext_vector_type(4))) unsigned int u32x4;

__device__ inline unsigned short f2bf(float f) {
    unsigned int u = __float_as_uint(f);
    unsigned int r = (u + 0x7fffu + ((u >> 16) & 1u)) >> 16;
    return (unsigned short)r;
}
__device__ inline float bf2f(unsigned short h) {
    return __uint_as_float(((unsigned int)h) << 16);
}
__device__ inline float lrelu01(float v) { return (v > 0.f) ? v : 0.1f * v; }
__device__ inline float lrelu02(float v) { return (v > 0.f) ? v : 0.2f * v; }

// ---------------------------------------------------------------------------
// CSR build (group edges by destination). Rebuilt every launch (ws poisoned).
// ---------------------------------------------------------------------------
__global__ void count_deg(const int* __restrict__ ei, int* __restrict__ indeg,
                          int E, int n) {
    int i = blockIdx.x * blockDim.x + threadIdx.x;
    if (i >= E + n) return;
    int dst = (i < E) ? ei[E + i] : (i - E);
    atomicAdd(&indeg[dst], 1);
}

__global__ void scan_rowptr(const int* __restrict__ indeg, int* __restrict__ row_ptr,
                            int* __restrict__ cursor, int n) {
    __shared__ int sums[1024];
    int tid = threadIdx.x;
    int per = (n + 1023) / 1024;
    int start = tid * per;
    int end = start + per; if (end > n) end = n;
    int s = 0;
    for (int i = start; i < end; ++i) s += indeg[i];
    sums[tid] = s;
    __syncthreads();
    for (int off = 1; off < 1024; off <<= 1) {
        int v = (tid >= off) ? sums[tid - off] : 0;
        __syncthreads();
        sums[tid] += v;
        __syncthreads();
    }
    int excl = (tid == 0) ? 0 : sums[tid - 1];
    for (int i = start; i < end; ++i) {
        row_ptr[i] = excl;
        cursor[i]  = excl;
        excl += indeg[i];
    }
    if (tid == 1023) row_ptr[n] = sums[1023];
}

__global__ void scatter_edges(const int* __restrict__ ei, int* __restrict__ cursor,
                              int* __restrict__ col, int E, int n) {
    int i = blockIdx.x * blockDim.x + threadIdx.x;
    if (i >= E + n) return;
    int src, dst;
    if (i < E) { src = ei[i]; dst = ei[E + i]; }
    else       { src = i - E; dst = i - E; }
    int pos = atomicAdd(&cursor[dst], 1);
    col[pos] = src;
}

// ---------------------------------------------------------------------------
// fp32 -> bf16 elementwise convert (for x).
// ---------------------------------------------------------------------------
__global__ void convert_bf16(const float* __restrict__ in, unsigned short* __restrict__ out,
                             int n) {
    int i = blockIdx.x * blockDim.x + threadIdx.x;
    if (i < n) out[i] = f2bf(in[i]);
}

// All three weight transposes in ONE dispatch. W[K][N] fp32 -> Wt[N][K] bf16.
__global__ void transpose_all(const float* __restrict__ W1, const float* __restrict__ W2,
                              const float* __restrict__ W3,
                              unsigned short* __restrict__ W1t,
                              unsigned short* __restrict__ W2t,
                              unsigned short* __restrict__ W3t) {
    __shared__ float t[32][33];
    int b = blockIdx.x;
    const float* W; unsigned short* Wt; int K, N, nb, kb;
    if (b < 320)       { W = W1; Wt = W1t; K = 128;  N = 2560; int i = b;        nb = i % 80; kb = i / 80; }
    else if (b < 1440) { W = W2; Wt = W2t; K = 2560; N = 448;  int i = b - 320;  nb = i % 14; kb = i / 14; }
    else               { W = W3; Wt = W3t; K = 448;  N = 128;  int i = b - 1440; nb = i % 4;  kb = i / 4;  }
    int kb32 = kb * 32, nb32 = nb * 32;
    int tx = threadIdx.x, ty = threadIdx.y;   // 32 x 8
    #pragma unroll
    for (int i = 0; i < 32; i += 8)
        t[ty + i][tx] = W[(size_t)(kb32 + ty + i) * N + nb32 + tx];
    __syncthreads();
    #pragma unroll
    for (int i = 0; i < 32; i += 8)
        Wt[(size_t)(nb32 + ty + i) * K + kb32 + tx] = f2bf(t[tx][ty + i]);
}

// ---------------------------------------------------------------------------
// wsrc[h,k] = sum_c W1[k, h*256+c] * as1[h,c]; same for wdst with ad1.
// ---------------------------------------------------------------------------
__global__ void make_wsd(const float* __restrict__ W1, const float* __restrict__ as1,
                         const float* __restrict__ ad1,
                         float* __restrict__ wsrc, float* __restrict__ wdst) {
    int idx = blockIdx.x * blockDim.x + threadIdx.x;
    if (idx >= 1280) return;
    int h = idx >> 7, k = idx & 127;
    const float* wrow = W1 + (size_t)k * 2560 + h * 256;
    const float* as = as1 + h * 256;
    const float* ad = ad1 + h * 256;
    float s = 0.f, d = 0.f;
    for (int c = 0; c < 256; c += 4) {
        f32x4 w = *(const f32x4*)&wrow[c];
        f32x4 a = *(const f32x4*)&as[c];
        f32x4 b = *(const f32x4*)&ad[c];
        #pragma unroll
        for (int j = 0; j < 4; ++j) { s += w[j] * a[j]; d += w[j] * b[j]; }
    }
    wsrc[h * 128 + k] = s;
    wdst[h * 128 + k] = d;
}

// ---------------------------------------------------------------------------
// e_src[n,h] = x[n]·wsrc[h], e_dst[n,h] = x[n]·wdst[h].
// ---------------------------------------------------------------------------
__global__ __launch_bounds__(256) void e1_dots(const unsigned short* __restrict__ xb,
                                               const float* __restrict__ wsrc,
                                               const float* __restrict__ wdst,
                                               float* __restrict__ e_src,
                                               float* __restrict__ e_dst, int M) {
    __shared__ float ws[1280], wd[1280];
    int tid = threadIdx.x;
    for (int i = tid; i < 1280; i += 256) { ws[i] = wsrc[i]; wd[i] = wdst[i]; }
    __syncthreads();
    int node = blockIdx.x * 4 + (tid >> 6);
    int lane = tid & 63;
    if (node >= M) return;
    unsigned int xv = ((const unsigned int*)xb)[node * 64 + lane];
    float v0 = bf2f((unsigned short)(xv & 0xffffu));
    float v1 = bf2f((unsigned short)(xv >> 16));
    #pragma unroll
    for (int h = 0; h < 10; ++h) {
        float ps = v0 * ws[h * 128 + 2 * lane] + v1 * ws[h * 128 + 2 * lane + 1];
        float pd = v0 * wd[h * 128 + 2 * lane] + v1 * wd[h * 128 + 2 * lane + 1];
        #pragma unroll
        for (int off = 32; off; off >>= 1) {
            ps += __shfl_down(ps, off);
            pd += __shfl_down(pd, off);
        }
        if (lane == 0) { e_src[node * 10 + h] = ps; e_dst[node * 10 + h] = pd; }
    }
}

// ---------------------------------------------------------------------------
// Layer-1 x-aggregation: xagg[d,h,:] = sum_s alpha[d,s,h] * x[s,:].
// One wave per dst node, all 10 heads; softmax w/o max subtraction.
// ---------------------------------------------------------------------------
__global__ __launch_bounds__(64) void agg_x(const unsigned short* __restrict__ xb,
                                            const float* __restrict__ e_src,
                                            const float* __restrict__ e_dst,
                                            const int* __restrict__ row_ptr,
                                            const int* __restrict__ col,
                                            unsigned short* __restrict__ xagg) {
    int node = blockIdx.x;
    int lane = threadIdx.x;
    int rs = row_ptr[node], re = row_ptr[node + 1];
    float edv = (lane < 10) ? e_dst[node * 10 + lane] : 0.f;

    float dn = 0.f;
    float a0[10], a1[10];
    #pragma unroll
    for (int h = 0; h < 10; ++h) { a0[h] = 0.f; a1[h] = 0.f; }
    for (int i = rs; i < re; ++i) {
        int s = col[i];
        float w = 0.f;
        if (lane < 10) w = __expf(lrelu02(e_src[s * 10 + lane] + edv));
        dn += w;
        unsigned int xv = ((const unsigned int*)xb)[s * 64 + lane];
        float v0 = bf2f((unsigned short)(xv & 0xffffu));
        float v1 = bf2f((unsigned short)(xv >> 16));
        #pragma unroll
        for (int h = 0; h < 10; ++h) {
            float wh = __shfl(w, h);
            a0[h] += wh * v0;
            a1[h] += wh * v1;
        }
    }
    #pragma unroll
    for (int h = 0; h < 10; ++h) {
        float rdn = 1.f / (__shfl(dn, h) + 1e-16f);
        unsigned int o = (unsigned int)f2bf(a0[h] * rdn) |
                         ((unsigned int)f2bf(a1[h] * rdn) << 16);
        ((unsigned int*)xagg)[((size_t)node * 10 + h) * 64 + lane] = o;
    }
}

// ---------------------------------------------------------------------------
// LDS bank-conflict XOR swizzle (global_load_lds dest is lane-fixed, so we
// permute WHICH 16B k-chunk each staging lane fetches and un-permute at read:
// chunk(p,row) holds global chunk p ^ ((row>>1)&3) -> fragment reads spread
// rows over 8 bank-groups (2-way aliasing = free) instead of 2 (8-way).
// ---------------------------------------------------------------------------

// Layer-1 batched per-head GEMM: x2[n,h*256+c] = lrelu01(xagg[n,h,:]·W1t + b1).
#define GBM 128
#define GBK 32
__global__ __launch_bounds__(256) void gemm_l1(const unsigned short* __restrict__ A,
                                               const unsigned short* __restrict__ Bt,
                                               const float* __restrict__ bias,
                                               unsigned short* __restrict__ C) {
    constexpr int NT = 128, NI = 4, K = 128;
    __shared__ short As[GBM * GBK];
    __shared__ short Bs[NT * GBK];
    int h  = blockIdx.x >> 1;
    int nt = blockIdx.x & 1;
    int bn = h * 256 + nt * 128;
    int bm = blockIdx.y * GBM;
    int tid  = threadIdx.x;
    int wave = tid >> 6, lane = tid & 63;
    int wr = wave >> 1, wc = wave & 1;
    int lrow  = lane >> 2;
    int lk    = (((lane & 3) ^ ((lrow >> 1) & 3))) * 8;   // swizzled staging chunk
    int row16 = lane & 15;
    int qs    = (((lane >> 4) ^ ((row16 >> 1) & 3))) * 8; // swizzled read chunk

    f32x4 acc[4][NI];
    #pragma unroll
    for (int mi = 0; mi < 4; ++mi)
        #pragma unroll
        for (int ni = 0; ni < NI; ++ni) acc[mi][ni] = (f32x4){0.f, 0.f, 0.f, 0.f};

    for (int k0 = 0; k0 < K; k0 += GBK) {
        #pragma unroll
        for (int i = 0; i < 2; ++i) {
            int c = i * 4 + wave;
            int row = c * 16 + lrow;
            const unsigned short* gp = A + ((size_t)(bm + row) * 10 + h) * K + k0 + lk;
            __builtin_amdgcn_global_load_lds(
                (const __attribute__((address_space(1))) void*)gp,
                (__attribute__((address_space(3))) void*)&As[c * 512], 16, 0, 0);
        }
        #pragma unroll
        for (int i = 0; i < 2; ++i) {
            int c = i * 4 + wave;
            int row = c * 16 + lrow;
            const unsigned short* gp = Bt + (size_t)(bn + row) * K + k0 + lk;
            __builtin_amdgcn_global_load_lds(
                (const __attribute__((address_space(1))) void*)gp,
                (__attribute__((address_space(3))) void*)&Bs[c * 512], 16, 0, 0);
        }
        __syncthreads();
        bf16x8 af[4], bfr[NI];
        #pragma unroll
        for (int mi = 0; mi < 4; ++mi)
            af[mi] = *(const bf16x8*)&As[(wr * 64 + mi * 16 + row16) * GBK + qs];
        #pragma unroll
        for (int ni = 0; ni < NI; ++ni)
            bfr[ni] = *(const bf16x8*)&Bs[(wc * 64 + ni * 16 + row16) * GBK + qs];
        #pragma unroll
        for (int mi = 0; mi < 4; ++mi)
            #pragma unroll
            for (int ni = 0; ni < NI; ++ni)
                acc[mi][ni] = __builtin_amdgcn_mfma_f32_16x16x32_bf16(
                    af[mi], bfr[ni], acc[mi][ni], 0, 0, 0);
        __syncthreads();
    }

    int rbase = bm + wr * 64 + (lane >> 4) * 4;
    #pragma unroll
    for (int mi = 0; mi < 4; ++mi)
        #pragma unroll
        for (int ni = 0; ni < NI; ++ni) {
            int cc = bn + wc * 64 + ni * 16 + (lane & 15);
            float b = bias[cc];
            #pragma unroll
            for (int r = 0; r < 4; ++r) {
                float v = lrelu01(acc[mi][ni][r] + b);
                C[(size_t)(rbase + mi * 16 + r) * 2560 + cc] = f2bf(v);
            }
        }
}

// ---------------------------------------------------------------------------
// Generic bf16 MFMA GEMM (layers 2/3): C = A[MPAD][K] @ Bt[N][K]^T.
// SWIZ grid: 1-D grid.x (XCD-local M-tiles), blockIdx.y = split-K slice
// (bf16 partials at z*MPAD*N). LDS XOR swizzle as above.
// ---------------------------------------------------------------------------
template <int NT, bool SWIZ>
__global__ __launch_bounds__(256) void gemm_mfma(const unsigned short* __restrict__ A,
                                                 const unsigned short* __restrict__ Bt,
                                                 unsigned short* __restrict__ C,
                                                 int N, int nbn, int K, int klen) {
    constexpr int NI = NT / 32;
    __shared__ short As[GBM * GBK];
    __shared__ short Bs[NT * GBK];
    int bn, bm, kbeg, kend;
    size_t zoff = 0;
    if constexpr (SWIZ) {
        int b = blockIdx.x;
        int x = b & 7, t = b >> 3;
        int j = x + 8 * (t / nbn);
        if (j >= MPAD / GBM) return;
        bn = (t % nbn) * NT;
        bm = j * GBM;
        kbeg = blockIdx.y * klen;
        kend = kbeg + klen;
        zoff = (size_t)blockIdx.y * MPAD * N;
    } else {
        bn = blockIdx.x * NT;
        bm = blockIdx.y * GBM;
        kbeg = 0; kend = K;
    }
    int tid  = threadIdx.x;
    int wave = tid >> 6, lane = tid & 63;
    int wr = wave >> 1, wc = wave & 1;
    int lrow  = lane >> 2;
    int lk    = (((lane & 3) ^ ((lrow >> 1) & 3))) * 8;
    int row16 = lane & 15;
    int qs    = (((lane >> 4) ^ ((row16 >> 1) & 3))) * 8;

    f32x4 acc[4][NI];
    #pragma unroll
    for (int mi = 0; mi < 4; ++mi)
        #pragma unroll
        for (int ni = 0; ni < NI; ++ni) acc[mi][ni] = (f32x4){0.f, 0.f, 0.f, 0.f};

    for (int k0 = kbeg; k0 < kend; k0 += GBK) {
        #pragma unroll
        for (int i = 0; i < 2; ++i) {
            int c = i * 4 + wave;
            int row = c * 16 + lrow;
            const unsigned short* gp = A + (size_t)(bm + row) * K + k0 + lk;
            __builtin_amdgcn_global_load_lds(
                (const __attribute__((address_space(1))) void*)gp,
                (__attribute__((address_space(3))) void*)&As[c * 512], 16, 0, 0);
        }
        #pragma unroll
        for (int i = 0; i < NT / 64; ++i) {
            int c = i * 4 + wave;
            int row = c * 16 + lrow;
            const unsigned short* gp = Bt + (size_t)(bn + row) * K + k0 + lk;
            __builtin_amdgcn_global_load_lds(
                (const __attribute__((address_space(1))) void*)gp,
                (__attribute__((address_space(3))) void*)&Bs[c * 512], 16, 0, 0);
        }
        __syncthreads();
        bf16x8 af[4], bfr[NI];
        #pragma unroll
        for (int mi = 0; mi < 4; ++mi)
            af[mi] = *(const bf16x8*)&As[(wr * 64 + mi * 16 + row16) * GBK + qs];
        #pragma unroll
        for (int ni = 0; ni < NI; ++ni)
            bfr[ni] = *(const bf16x8*)&Bs[(wc * (NT / 2) + ni * 16 + row16) * GBK + qs];
        #pragma unroll
        for (int mi = 0; mi < 4; ++mi)
            #pragma unroll
            for (int ni = 0; ni < NI; ++ni)
                acc[mi][ni] = __builtin_amdgcn_mfma_f32_16x16x32_bf16(
                    af[mi], bfr[ni], acc[mi][ni], 0, 0, 0);
        __syncthreads();
    }

    int rbase = bm + wr * 64 + (lane >> 4) * 4;
    int cbase = bn + wc * (NT / 2) + (lane & 15);
    #pragma unroll
    for (int mi = 0; mi < 4; ++mi)
        #pragma unroll
        for (int ni = 0; ni < NI; ++ni)
            #pragma unroll
            for (int r = 0; r < 4; ++r)
                C[zoff + (size_t)(rbase + mi * 16 + r) * N + cbase + ni * 16] =
                    f2bf(acc[mi][ni][r]);
}

// Sum S bf16x2-packed split-K partial slices -> packed bf16x2.
template <int S>
__global__ void reduce_k(const unsigned int* __restrict__ P, unsigned int* __restrict__ out,
                         size_t stride, int n2) {
    int i = blockIdx.x * blockDim.x + threadIdx.x;
    if (i >= n2) return;
    float lo = 0.f, hi = 0.f;
    #pragma unroll
    for (int s = 0; s < S; ++s) {
        unsigned int v = P[s * stride + i];
        lo += bf2f((unsigned short)(v & 0xffffu));
        hi += bf2f((unsigned short)(v >> 16));
    }
    out[i] = (unsigned int)f2bf(lo) | ((unsigned int)f2bf(hi) << 16);
}

// ---------------------------------------------------------------------------
// Layer-4 GEMM fused with attention halves.
// ---------------------------------------------------------------------------
__global__ __launch_bounds__(256) void gemm4_attn(const unsigned short* __restrict__ A,
                                                  const float* __restrict__ W,
                                                  const float* __restrict__ as4,
                                                  const float* __restrict__ ad4,
                                                  unsigned short* __restrict__ C,
                                                  float* __restrict__ e_src,
                                                  float* __restrict__ e_dst, int M) {
    __shared__ float Ws[128 * 16];
    int tid = threadIdx.x;
    for (int i = tid; i < 2048; i += 256) Ws[i] = W[i];
    __syncthreads();
    int node = blockIdx.x * 16 + (tid >> 4);
    int n = tid & 15;
    if (node >= M) return;
    const unsigned short* ap = A + (size_t)node * 128;
    float acc = 0.f;
    #pragma unroll 8
    for (int k = 0; k < 128; ++k)
        acc += bf2f(ap[k]) * Ws[k * 16 + n];
    C[(size_t)node * 16 + n] = f2bf(acc);
    float vs = acc * as4[n];
    float vd = acc * ad4[n];
    #pragma unroll
    for (int off = 1; off < 16; off <<= 1) {
        vs += __shfl_xor(vs, off);
        vd += __shfl_xor(vd, off);
    }
    if (n == 0) { e_src[node] = vs; e_dst[node] = vd; }
}

// ---------------------------------------------------------------------------
// attn halves, small C (layers 2/3): one wave per NODE, all heads in-wave.
// ---------------------------------------------------------------------------
template <int H, int C>
__global__ __launch_bounds__(64) void attn_small(const unsigned short* __restrict__ h,
                                                 const float* __restrict__ a_src,
                                                 const float* __restrict__ a_dst,
                                                 float* __restrict__ e_src,
                                                 float* __restrict__ e_dst) {
    constexpr int LPH = 64 / H;
    constexpr int CPL = C / LPH;
    int node = blockIdx.x;
    int lane = threadIdx.x;
    int head = lane / LPH;
    int k = lane - head * LPH;
    const unsigned short* hp = h + (size_t)node * (H * C) + head * C + k * CPL;
    const float* as = a_src + head * C + k * CPL;
    const float* ad = a_dst + head * C + k * CPL;
    float s1 = 0.f, s2 = 0.f;
    #pragma unroll
    for (int c = 0; c < CPL; ++c) {
        float v = bf2f(hp[c]);
        s1 += v * as[c];
        s2 += v * ad[c];
    }
    #pragma unroll
    for (int off = LPH / 2; off; off >>= 1) {
        s1 += __shfl_down(s1, off);
        s2 += __shfl_down(s2, off);
    }
    if (k == 0) { e_src[node * H + head] = s1; e_dst[node * H + head] = s2; }
}

// ---------------------------------------------------------------------------
// Layer-2 (H=8, C=56) aggregation: one wave per node, 56 active lanes.
// ---------------------------------------------------------------------------
__global__ __launch_bounds__(64) void agg_l2(const unsigned short* __restrict__ h,
                                             const float* __restrict__ e_src,
                                             const float* __restrict__ e_dst,
                                             const int* __restrict__ row_ptr,
                                             const int* __restrict__ col,
                                             const float* __restrict__ bias,
                                             unsigned short* __restrict__ out) {
    const int H = 8;
    int node = blockIdx.x;
    int lane = threadIdx.x;
    bool act = lane < 56;
    int head = act ? (lane / 7) : 0;
    int cpos = act ? (lane - head * 7) : 0;
    int rs = row_ptr[node], re = row_ptr[node + 1];
    float edv = e_dst[node * H + head];

    float dn = 0.f;
    float acc0[8], acc1[8];
    #pragma unroll
    for (int k = 0; k < 8; ++k) { acc0[k] = 0.f; acc1[k] = 0.f; }
    int i = rs;
    for (; i + 1 < re; i += 2) {
        int s0 = col[i], s1 = col[i + 1];
        float es0 = e_src[s0 * H + head];
        float es1 = e_src[s1 * H + head];
        u32x4 hv0 = *(const u32x4*)(h + (size_t)s0 * 448 + head * 56 + cpos * 8);
        u32x4 hv1 = *(const u32x4*)(h + (size_t)s1 * 448 + head * 56 + cpos * 8);
        float w0 = __expf(lrelu02(es0 + edv));
        float w1 = __expf(lrelu02(es1 + edv));
        dn += w0 + w1;
        #pragma unroll
        for (int d = 0; d < 4; ++d) {
            acc0[2 * d]     += w0 * bf2f((unsigned short)(hv0[d] & 0xffffu));
            acc0[2 * d + 1] += w0 * bf2f((unsigned short)(hv0[d] >> 16));
            acc1[2 * d]     += w1 * bf2f((unsigned short)(hv1[d] & 0xffffu));
            acc1[2 * d + 1] += w1 * bf2f((unsigned short)(hv1[d] >> 16));
        }
    }
    if (i < re) {
        int s = col[i];
        float w = __expf(lrelu02(e_src[s * H + head] + edv));
        dn += w;
        u32x4 hv = *(const u32x4*)(h + (size_t)s * 448 + head * 56 + cpos * 8);
        #pragma unroll
        for (int d = 0; d < 4; ++d) {
            acc0[2 * d]     += w * bf2f((unsigned short)(hv[d] & 0xffffu));
            acc0[2 * d + 1] += w * bf2f((unsigned short)(hv[d] >> 16));
        }
    }
    float rdn = 1.f / (dn + 1e-16f);

    if (act) {
        const float* bp = bias + head * 56 + cpos * 8;
        u32x4 o;
        #pragma unroll
        for (int d = 0; d < 4; ++d) {
            float v0 = lrelu01((acc0[2 * d] + acc1[2 * d]) * rdn + bp[2 * d]);
            float v1 = lrelu01((acc0[2 * d + 1] + acc1[2 * d + 1]) * rdn + bp[2 * d + 1]);
            o[d] = (unsigned int)f2bf(v0) | ((unsigned int)f2bf(v1) << 16);
        }
        *(u32x4*)(out + (size_t)node * 448 + head * 56 + cpos * 8) = o;
    }
}

// Layer-3 (H=4, C=32): one wave per node, 16 active lanes.
__global__ __launch_bounds__(64) void agg_l3(const unsigned short* __restrict__ h,
                                             const float* __restrict__ e_src,
                                             const float* __restrict__ e_dst,
                                             const int* __restrict__ row_ptr,
                                             const int* __restrict__ col,
                                             const float* __restrict__ bias,
                                             unsigned short* __restrict__ out) {
    const int H = 4;
    int node = blockIdx.x;
    int lane = threadIdx.x;
    bool act = lane < 16;
    int head = (lane >> 2) & 3;
    int cpos = lane & 3;
    int rs = row_ptr[node], re = row_ptr[node + 1];
    float edv = e_dst[node * H + head];

    float dn = 0.f;
    float acc0[8], acc1[8];
    #pragma unroll
    for (int k = 0; k < 8; ++k) { acc0[k] = 0.f; acc1[k] = 0.f; }
    int i = rs;
    for (; i + 1 < re; i += 2) {
        int s0 = col[i], s1 = col[i + 1];
        float es0 = e_src[s0 * H + head];
        float es1 = e_src[s1 * H + head];
        u32x4 hv0 = *(const u32x4*)(h + (size_t)s0 * 128 + head * 32 + cpos * 8);
        u32x4 hv1 = *(const u32x4*)(h + (size_t)s1 * 128 + head * 32 + cpos * 8);
        float w0 = __expf(lrelu02(es0 + edv));
        float w1 = __expf(lrelu02(es1 + edv));
        dn += w0 + w1;
        #pragma unroll
        for (int d = 0; d < 4; ++d) {
            acc0[2 * d]     += w0 * bf2f((unsigned short)(hv0[d] & 0xffffu));
            acc0[2 * d + 1] += w0 * bf2f((unsigned short)(hv0[d] >> 16));
            acc1[2 * d]     += w1 * bf2f((unsigned short)(hv1[d] & 0xffffu));
            acc1[2 * d + 1] += w1 * bf2f((unsigned short)(hv1[d] >> 16));
        }
    }
    if (i < re) {
        int s = col[i];
        float w = __expf(lrelu02(e_src[s * H + head] + edv));
        dn += w;
        u32x4 hv = *(const u32x4*)(h + (size_t)s * 128 + head * 32 + cpos * 8);
        #pragma unroll
        for (int d = 0; d < 4; ++d) {
            acc0[2 * d]     += w * bf2f((unsigned short)(hv[d] & 0xffffu));
            acc0[2 * d + 1] += w * bf2f((unsigned short)(hv[d] >> 16));
        }
    }
    float rdn = 1.f / (dn + 1e-16f);

    if (act) {
        const float* bp = bias + head * 32 + cpos * 8;
        u32x4 o;
        #pragma unroll
        for (int d = 0; d < 4; ++d) {
            float v0 = lrelu01((acc0[2 * d] + acc1[2 * d]) * rdn + bp[2 * d]);
            float v1 = lrelu01((acc0[2 * d + 1] + acc1[2 * d + 1]) * rdn + bp[2 * d + 1]);
            o[d] = (unsigned int)f2bf(v0) | ((unsigned int)f2bf(v1) << 16);
        }
        *(u32x4*)(out + (size_t)node * 128 + head * 32 + cpos * 8) = o;
    }
}

// Layer-4 fused: aggregate (H=1, C=16) + bias + LeakyReLU(0.1) + row softmax.
__global__ __launch_bounds__(64) void agg4_softmax(const unsigned int* __restrict__ h2,
                                                   const float* __restrict__ e_src,
                                                   const float* __restrict__ e_dst,
                                                   const int* __restrict__ row_ptr,
                                                   const int* __restrict__ col,
                                                   const float* __restrict__ bias,
                                                   float* __restrict__ out) {
    int node = blockIdx.x;
    int lane = threadIdx.x;
    int cpos = lane & 7;
    int rs = row_ptr[node], re = row_ptr[node + 1];
    float edv = e_dst[node];

    float dn = 0.f, a0 = 0.f, a1 = 0.f;
    for (int i = rs; i < re; ++i) {
        int s = col[i];
        float w = __expf(lrelu02(e_src[s] + edv));
        dn += w;
        unsigned int hv = h2[(size_t)s * 8 + cpos];
        a0 += w * bf2f((unsigned short)(hv & 0xffffu));
        a1 += w * bf2f((unsigned short)(hv >> 16));
    }
    float rdn = 1.f / (dn + 1e-16f);
    float v0 = lrelu01(a0 * rdn + bias[2 * cpos]);
    float v1 = lrelu01(a1 * rdn + bias[2 * cpos + 1]);

    float m = fmaxf(v0, v1);
    #pragma unroll
    for (int off = 4; off; off >>= 1) m = fmaxf(m, __shfl_xor(m, off));
    float e0 = __expf(v0 - m), e1 = __expf(v1 - m);
    float s = e0 + e1;
    #pragma unroll
    for (int off = 4; off; off >>= 1) s += __shfl_xor(s, off);
    float r = 1.f / s;
    if (lane < 8) {
        out[node * 16 + 2 * cpos]     = e0 * r;
        out[node * 16 + 2 * cpos + 1] = e1 * r;
    }
}

// ---------------------------------------------------------------------------
extern "C" void kernel_launch(void* const* d_in, const int* in_sizes, int n_in,
                              void* d_out, int out_size, void* d_ws, size_t ws_size,
                              hipStream_t stream) {
    const float* x   = (const float*)d_in[0];
    const int*   ei  = (const int*)d_in[1];
    const float* W1  = (const float*)d_in[2];
    const float* as1 = (const float*)d_in[3];
    const float* ad1 = (const float*)d_in[4];
    const float* b1  = (const float*)d_in[5];
    const float* W2  = (const float*)d_in[6];
    const float* as2 = (const float*)d_in[7];
    const float* ad2 = (const float*)d_in[8];
    const float* b2  = (const float*)d_in[9];
    const float* W3  = (const float*)d_in[10];
    const float* as3 = (const float*)d_in[11];
    const float* ad3 = (const float*)d_in[12];
    const float* b3  = (const float*)d_in[13];
    const float* W4  = (const float*)d_in[14];
    const float* as4 = (const float*)d_in[15];
    const float* ad4 = (const float*)d_in[16];
    const float* b4  = (const float*)d_in[17];

    char* ws = (char*)d_ws;
    size_t off = 0;
    auto alloc = [&](size_t bytes) -> void* {
        void* p = ws + off;
        off = (off + bytes + 255) & ~(size_t)255;
        return p;
    };
    unsigned short* hbuf = (unsigned short*)alloc((size_t)MPAD * 2560 * sizeof(short));
    unsigned short* abuf = (unsigned short*)alloc((size_t)MPAD * 2560 * sizeof(short));
    unsigned short* pbuf = (unsigned short*)alloc((size_t)4 * MPAD * 448 * sizeof(short));
    unsigned short* xagg = (unsigned short*)alloc((size_t)MPAD * 10 * 128 * sizeof(short));
    unsigned short* W1t  = (unsigned short*)alloc((size_t)2560 * 128 * sizeof(short));
    unsigned short* W2t  = (unsigned short*)alloc((size_t)448 * 2560 * sizeof(short));
    unsigned short* W3t  = (unsigned short*)alloc((size_t)128 * 448 * sizeof(short));
    float* wsrc   = (float*)alloc((size_t)10 * 128 * sizeof(float));
    float* wdst   = (float*)alloc((size_t)10 * 128 * sizeof(float));
    float* e_src  = (float*)alloc((size_t)NNODES * 10 * sizeof(float));
    float* e_dst  = (float*)alloc((size_t)NNODES * 10 * sizeof(float));
    int* indeg    = (int*)alloc(NNODES * sizeof(int));
    int* row_ptr  = (int*)alloc((NNODES + 1) * sizeof(int));
    int* cursor   = (int*)alloc(NNODES * sizeof(int));
    int* col      = (int*)alloc(ETOT * sizeof(int));
    (void)ws_size;

    // ---- CSR build ----
    hipMemsetAsync(indeg, 0, NNODES * sizeof(int), stream);
    int eb = (ETOT + 255) / 256;
    count_deg<<<eb, 256, 0, stream>>>(ei, indeg, NEDGES, NNODES);
    scan_rowptr<<<1, 1024, 0, stream>>>(indeg, row_ptr, cursor, NNODES);
    scatter_edges<<<eb, 256, 0, stream>>>(ei, cursor, col, NEDGES, NNODES);

    // ---- weight prep + x convert ----
    transpose_all<<<1496, dim3(32, 8), 0, stream>>>(W1, W2, W3, W1t, W2t, W3t);
    make_wsd<<<20, 64, 0, stream>>>(W1, as1, ad1, wsrc, wdst);
    convert_bf16<<<(NNODES * 128 + 255) / 256, 256, 0, stream>>>(x, abuf, NNODES * 128);

    const int Mb = MPAD / GBM;   // 79

    // ---- Layer 1 (linearity-restructured): e1 -> agg_x -> batched GEMM ----
    e1_dots<<<(NNODES + 3) / 4, 256, 0, stream>>>(abuf, wsrc, wdst, e_src, e_dst, NNODES);
    agg_x<<<NNODES, 64, 0, stream>>>(abuf, e_src, e_dst, row_ptr, col, xagg);
    gemm_l1<<<dim3(20, Mb), 256, 0, stream>>>(xagg, W1t, b1, abuf);   // abuf = x2

    // ---- Layer 2: 2560 -> 8 heads x 56 (XCD-swizzled, split-K=4) ----
    gemm_mfma<64, true><<<dim3(8 * 7 * 10, 4), 256, 0, stream>>>(
        abuf, W2t, pbuf, 448, 7, 2560, 640);
    {
        int n2 = NNODES * 448 / 2;
        reduce_k<4><<<(n2 + 255) / 256, 256, 0, stream>>>(
            (const unsigned int*)pbuf, (unsigned int*)hbuf, (size_t)MPAD * 448 / 2, n2);
    }
    attn_small<8, 56><<<NNODES, 64, 0, stream>>>(hbuf, as2, ad2, e_src, e_dst);
    agg_l2<<<NNODES, 64, 0, stream>>>(hbuf, e_src, e_dst, row_ptr, col, b2, abuf);

    // ---- Layer 3: 448 -> 4 heads x 32 (XCD-swizzled, split-K=2) ----
    gemm_mfma<64, true><<<dim3(8 * 2 * 10, 2), 256, 0, stream>>>(
        abuf, W3t, pbuf, 128, 2, 448, 224);
    {
        int n2 = NNODES * 128 / 2;
        reduce_k<2><<<(n2 + 255) / 256, 256, 0, stream>>>(
            (const unsigned int*)pbuf, (unsigned int*)hbuf, (size_t)MPAD * 128 / 2, n2);
    }
    attn_small<4, 32><<<NNODES, 64, 0, stream>>>(hbuf, as3, ad3, e_src, e_dst);
    agg_l3<<<NNODES, 64, 0, stream>>>(hbuf, e_src, e_dst, row_ptr, col, b3, abuf);

    // ---- Layer 4: 128 -> 1 head x 16 (attn fused into GEMM) + softmax ----
    gemm4_attn<<<(NNODES + 15) / 16, 256, 0, stream>>>(
        abuf, W4, as4, ad4, hbuf, e_src, e_dst, NNODES);
    agg4_softmax<<<NNODES, 64, 0, stream>>>(
        (const unsigned int*)hbuf, e_src, e_dst, row_ptr, col, b4, (float*)d_out);
}

// Round 12
// 281.452 us; speedup vs baseline: 1.3019x; 1.0650x over previous
//
#include <hip/hip_runtime.h>
#include <math.h>

// Problem constants (match reference setup_inputs()).
#define NNODES 10000
#define MPAD   10112           // 79 * 128 (MFMA M-tile padding)
#define NEDGES 80000           // directed edges before self loops
#define ETOT   (NEDGES + NNODES)

typedef __attribute__((ext_vector_type(4))) float f32x4;
typedef __attribute__((ext_vector_type(8))) short bf16x8;
typedef __attribute__((ext_vector_type(4))) unsigned int u32x4;

__device__ inline unsigned short f2bf(float f) {
    unsigned int u = __float_as_uint(f);
    unsigned int r = (u + 0x7fffu + ((u >> 16) & 1u)) >> 16;
    return (unsigned short)r;
}
__device__ inline float bf2f(unsigned short h) {
    return __uint_as_float(((unsigned int)h) << 16);
}
__device__ inline float lrelu01(float v) { return (v > 0.f) ? v : 0.1f * v; }
__device__ inline float lrelu02(float v) { return (v > 0.f) ? v : 0.2f * v; }

// ---------------------------------------------------------------------------
// Mega prep kernel: count_deg | x->bf16 convert | make_wsd | 3 transposes.
// Block ranges: [0,352) count, [352,5352) convert, [5352,5357) wsd,
// [5357,6853) transpose tiles.
// ---------------------------------------------------------------------------
__global__ __launch_bounds__(256) void prep_all(const int* __restrict__ ei,
                                                int* __restrict__ indeg,
                                                const float* __restrict__ x,
                                                unsigned short* __restrict__ xb,
                                                const float* __restrict__ W1,
                                                const float* __restrict__ as1,
                                                const float* __restrict__ ad1,
                                                float* __restrict__ wsrc,
                                                float* __restrict__ wdst,
                                                const float* __restrict__ W2,
                                                const float* __restrict__ W3,
                                                unsigned short* __restrict__ W1t,
                                                unsigned short* __restrict__ W2t,
                                                unsigned short* __restrict__ W3t) {
    __shared__ float t[32][33];
    int b = blockIdx.x, tid = threadIdx.x;
    if (b < 352) {                       // count_deg
        int i = b * 256 + tid;
        if (i < ETOT) {
            int dst = (i < NEDGES) ? ei[NEDGES + i] : (i - NEDGES);
            atomicAdd(&indeg[dst], 1);
        }
        return;
    }
    b -= 352;
    if (b < 5000) {                      // convert x -> bf16
        int i = b * 256 + tid;
        if (i < NNODES * 128) xb[i] = f2bf(x[i]);
        return;
    }
    b -= 5000;
    if (b < 5) {                         // make_wsd: wsrc/wdst [10][128]
        int idx = b * 256 + tid;
        if (idx < 1280) {
            int h = idx >> 7, k = idx & 127;
            const float* wrow = W1 + (size_t)k * 2560 + h * 256;
            const float* as = as1 + h * 256;
            const float* ad = ad1 + h * 256;
            float s = 0.f, d = 0.f;
            for (int c = 0; c < 256; c += 4) {
                f32x4 w = *(const f32x4*)&wrow[c];
                f32x4 a = *(const f32x4*)&as[c];
                f32x4 bb = *(const f32x4*)&ad[c];
                #pragma unroll
                for (int j = 0; j < 4; ++j) { s += w[j] * a[j]; d += w[j] * bb[j]; }
            }
            wsrc[h * 128 + k] = s;
            wdst[h * 128 + k] = d;
        }
        return;
    }
    b -= 5;                              // transposes (1496 32x32 tiles)
    const float* W; unsigned short* Wt; int K, N, nb, kb;
    if (b < 320)       { W = W1; Wt = W1t; K = 128;  N = 2560; nb = b % 80; kb = b / 80; }
    else if (b < 1440) { W = W2; Wt = W2t; K = 2560; N = 448;  int i = b - 320;  nb = i % 14; kb = i / 14; }
    else               { W = W3; Wt = W3t; K = 448;  N = 128;  int i = b - 1440; nb = i % 4;  kb = i / 4;  }
    int kb32 = kb * 32, nb32 = nb * 32;
    int tx = tid & 31, ty = tid >> 5;    // 32 x 8
    #pragma unroll
    for (int i = 0; i < 32; i += 8)
        t[ty + i][tx] = W[(size_t)(kb32 + ty + i) * N + nb32 + tx];
    __syncthreads();
    #pragma unroll
    for (int i = 0; i < 32; i += 8)
        Wt[(size_t)(nb32 + ty + i) * K + kb32 + tx] = f2bf(t[tx][ty + i]);
}

// ---------------------------------------------------------------------------
// Single-block exclusive scan over indeg -> row_ptr (and cursor copy).
// ---------------------------------------------------------------------------
__global__ void scan_rowptr(const int* __restrict__ indeg, int* __restrict__ row_ptr,
                            int* __restrict__ cursor, int n) {
    __shared__ int sums[1024];
    int tid = threadIdx.x;
    int per = (n + 1023) / 1024;
    int start = tid * per;
    int end = start + per; if (end > n) end = n;
    int s = 0;
    for (int i = start; i < end; ++i) s += indeg[i];
    sums[tid] = s;
    __syncthreads();
    for (int off = 1; off < 1024; off <<= 1) {
        int v = (tid >= off) ? sums[tid - off] : 0;
        __syncthreads();
        sums[tid] += v;
        __syncthreads();
    }
    int excl = (tid == 0) ? 0 : sums[tid - 1];
    for (int i = start; i < end; ++i) {
        row_ptr[i] = excl;
        cursor[i]  = excl;
        excl += indeg[i];
    }
    if (tid == 1023) row_ptr[n] = sums[1023];
}

// ---------------------------------------------------------------------------
// scatter_edges | e1_dots merged. Blocks [0,352) scatter, [352,2852) e1.
// e1: e_src[n,h]=x[n]·wsrc[h], e_dst likewise; 4 nodes/block.
// ---------------------------------------------------------------------------
__global__ __launch_bounds__(256) void scatter_e1(const int* __restrict__ ei,
                                                  int* __restrict__ cursor,
                                                  int* __restrict__ col,
                                                  const unsigned short* __restrict__ xb,
                                                  const float* __restrict__ wsrc,
                                                  const float* __restrict__ wdst,
                                                  float* __restrict__ e_src,
                                                  float* __restrict__ e_dst) {
    __shared__ float ws[1280], wd[1280];
    int b = blockIdx.x, tid = threadIdx.x;
    if (b < 352) {
        int i = b * 256 + tid;
        if (i < ETOT) {
            int src, dst;
            if (i < NEDGES) { src = ei[i]; dst = ei[NEDGES + i]; }
            else            { src = i - NEDGES; dst = i - NEDGES; }
            int pos = atomicAdd(&cursor[dst], 1);
            col[pos] = src;
        }
        return;
    }
    b -= 352;
    for (int i = tid; i < 1280; i += 256) { ws[i] = wsrc[i]; wd[i] = wdst[i]; }
    __syncthreads();
    int node = b * 4 + (tid >> 6);
    int lane = tid & 63;
    if (node >= NNODES) return;
    unsigned int xv = ((const unsigned int*)xb)[node * 64 + lane];
    float v0 = bf2f((unsigned short)(xv & 0xffffu));
    float v1 = bf2f((unsigned short)(xv >> 16));
    #pragma unroll
    for (int h = 0; h < 10; ++h) {
        float ps = v0 * ws[h * 128 + 2 * lane] + v1 * ws[h * 128 + 2 * lane + 1];
        float pd = v0 * wd[h * 128 + 2 * lane] + v1 * wd[h * 128 + 2 * lane + 1];
        #pragma unroll
        for (int off = 32; off; off >>= 1) {
            ps += __shfl_down(ps, off);
            pd += __shfl_down(pd, off);
        }
        if (lane == 0) { e_src[node * 10 + h] = ps; e_dst[node * 10 + h] = pd; }
    }
}

// ---------------------------------------------------------------------------
// Layer-1 x-aggregation: xagg[d,h,:] = sum_s alpha[d,s,h] * x[s,:].
// One wave per dst node, all 10 heads; softmax w/o max subtraction.
// ---------------------------------------------------------------------------
__global__ __launch_bounds__(64) void agg_x(const unsigned short* __restrict__ xb,
                                            const float* __restrict__ e_src,
                                            const float* __restrict__ e_dst,
                                            const int* __restrict__ row_ptr,
                                            const int* __restrict__ col,
                                            unsigned short* __restrict__ xagg) {
    int node = blockIdx.x;
    int lane = threadIdx.x;
    int rs = row_ptr[node], re = row_ptr[node + 1];
    float edv = (lane < 10) ? e_dst[node * 10 + lane] : 0.f;

    float dn = 0.f;
    float a0[10], a1[10];
    #pragma unroll
    for (int h = 0; h < 10; ++h) { a0[h] = 0.f; a1[h] = 0.f; }
    for (int i = rs; i < re; ++i) {
        int s = col[i];
        float w = 0.f;
        if (lane < 10) w = __expf(lrelu02(e_src[s * 10 + lane] + edv));
        dn += w;
        unsigned int xv = ((const unsigned int*)xb)[s * 64 + lane];
        float v0 = bf2f((unsigned short)(xv & 0xffffu));
        float v1 = bf2f((unsigned short)(xv >> 16));
        #pragma unroll
        for (int h = 0; h < 10; ++h) {
            float wh = __shfl(w, h);
            a0[h] += wh * v0;
            a1[h] += wh * v1;
        }
    }
    #pragma unroll
    for (int h = 0; h < 10; ++h) {
        float rdn = 1.f / (__shfl(dn, h) + 1e-16f);
        unsigned int o = (unsigned int)f2bf(a0[h] * rdn) |
                         ((unsigned int)f2bf(a1[h] * rdn) << 16);
        ((unsigned int*)xagg)[((size_t)node * 10 + h) * 64 + lane] = o;
    }
}

// ---------------------------------------------------------------------------
// GBK=64 LDS XOR-8 swizzle: rows are 128 B (full 32-bank period). LDS chunk
// position p of row R holds global 16B-chunk p^(R&7); staging lane ℓ fetches
// chunk (ℓ&7)^(ℓ>>3) of its row (global side is a gather, still 128B
// coalesced); fragment reads use pos q^(row16&7) -> 2-way aliasing = free.
// ---------------------------------------------------------------------------

// Layer-1 batched per-head GEMM (K=128, GBK=64): x2 = lrelu01(xagg@W1t + b1).
#define GBM 128
__global__ __launch_bounds__(256) void gemm_l1(const unsigned short* __restrict__ A,
                                               const unsigned short* __restrict__ Bt,
                                               const float* __restrict__ bias,
                                               unsigned short* __restrict__ C) {
    constexpr int NT = 128, NI = 4, K = 128;
    __shared__ short As[GBM * 64];
    __shared__ short Bs[NT * 64];
    int h  = blockIdx.x >> 1;
    int nt = blockIdx.x & 1;
    int bn = h * 256 + nt * 128;
    int bm = blockIdx.y * GBM;
    int tid  = threadIdx.x;
    int wave = tid >> 6, lane = tid & 63;
    int wr = wave >> 1, wc = wave & 1;
    int lr8    = lane >> 3;
    int gchunk = (lane & 7) ^ lr8;       // swizzled source chunk
    int row16  = lane & 15;
    int quad   = lane >> 4;

    f32x4 acc[4][NI];
    #pragma unroll
    for (int mi = 0; mi < 4; ++mi)
        #pragma unroll
        for (int ni = 0; ni < NI; ++ni) acc[mi][ni] = (f32x4){0.f, 0.f, 0.f, 0.f};

    for (int k0 = 0; k0 < K; k0 += 64) {
        #pragma unroll
        for (int r = 0; r < 4; ++r) {    // A: 16 wave-chunks of 8 rows
            int cs = r * 4 + wave;
            int row = cs * 8 + lr8;
            const unsigned short* gp = A + ((size_t)(bm + row) * 10 + h) * K + k0 + gchunk * 8;
            __builtin_amdgcn_global_load_lds(
                (const __attribute__((address_space(1))) void*)gp,
                (__attribute__((address_space(3))) void*)&As[cs * 512], 16, 0, 0);
        }
        #pragma unroll
        for (int r = 0; r < 4; ++r) {    // B: 16 wave-chunks
            int cs = r * 4 + wave;
            int row = cs * 8 + lr8;
            const unsigned short* gp = Bt + (size_t)(bn + row) * K + k0 + gchunk * 8;
            __builtin_amdgcn_global_load_lds(
                (const __attribute__((address_space(1))) void*)gp,
                (__attribute__((address_space(3))) void*)&Bs[cs * 512], 16, 0, 0);
        }
        __syncthreads();
        #pragma unroll
        for (int kh = 0; kh < 2; ++kh) {
            int q = kh * 4 + quad;
            int pos = (q ^ (row16 & 7)) * 8;
            bf16x8 af[4], bfr[NI];
            #pragma unroll
            for (int mi = 0; mi < 4; ++mi)
                af[mi] = *(const bf16x8*)&As[(wr * 64 + mi * 16 + row16) * 64 + pos];
            #pragma unroll
            for (int ni = 0; ni < NI; ++ni)
                bfr[ni] = *(const bf16x8*)&Bs[(wc * 64 + ni * 16 + row16) * 64 + pos];
            #pragma unroll
            for (int mi = 0; mi < 4; ++mi)
                #pragma unroll
                for (int ni = 0; ni < NI; ++ni)
                    acc[mi][ni] = __builtin_amdgcn_mfma_f32_16x16x32_bf16(
                        af[mi], bfr[ni], acc[mi][ni], 0, 0, 0);
        }
        __syncthreads();
    }

    int rbase = bm + wr * 64 + (lane >> 4) * 4;
    #pragma unroll
    for (int mi = 0; mi < 4; ++mi)
        #pragma unroll
        for (int ni = 0; ni < NI; ++ni) {
            int cc = bn + wc * 64 + ni * 16 + (lane & 15);
            float b = bias[cc];
            #pragma unroll
            for (int r = 0; r < 4; ++r) {
                float v = lrelu01(acc[mi][ni][r] + b);
                C[(size_t)(rbase + mi * 16 + r) * 2560 + cc] = f2bf(v);
            }
        }
}

// ---------------------------------------------------------------------------
// Layer-2 GEMM, GBK=64, XCD-swizzled grid.x + split-K grid.y (bf16 partials).
// klen must be a multiple of 64.
// ---------------------------------------------------------------------------
template <int NT>
__global__ __launch_bounds__(256) void gemm_k64(const unsigned short* __restrict__ A,
                                                const unsigned short* __restrict__ Bt,
                                                unsigned short* __restrict__ C,
                                                int N, int nbn, int K, int klen) {
    constexpr int NI = NT / 32;
    __shared__ short As[GBM * 64];
    __shared__ short Bs[NT * 64];
    int b = blockIdx.x;
    int x = b & 7, t = b >> 3;
    int j = x + 8 * (t / nbn);
    if (j >= MPAD / GBM) return;
    int bn = (t % nbn) * NT;
    int bm = j * GBM;
    int kbeg = blockIdx.y * klen;
    int kend = kbeg + klen;
    size_t zoff = (size_t)blockIdx.y * MPAD * N;
    int tid  = threadIdx.x;
    int wave = tid >> 6, lane = tid & 63;
    int wr = wave >> 1, wc = wave & 1;
    int lr8    = lane >> 3;
    int gchunk = (lane & 7) ^ lr8;
    int row16  = lane & 15;
    int quad   = lane >> 4;

    f32x4 acc[4][NI];
    #pragma unroll
    for (int mi = 0; mi < 4; ++mi)
        #pragma unroll
        for (int ni = 0; ni < NI; ++ni) acc[mi][ni] = (f32x4){0.f, 0.f, 0.f, 0.f};

    for (int k0 = kbeg; k0 < kend; k0 += 64) {
        #pragma unroll
        for (int r = 0; r < 4; ++r) {
            int cs = r * 4 + wave;
            int row = cs * 8 + lr8;
            const unsigned short* gp = A + (size_t)(bm + row) * K + k0 + gchunk * 8;
            __builtin_amdgcn_global_load_lds(
                (const __attribute__((address_space(1))) void*)gp,
                (__attribute__((address_space(3))) void*)&As[cs * 512], 16, 0, 0);
        }
        #pragma unroll
        for (int r = 0; r < NT / 32; ++r) {
            int cs = r * 4 + wave;
            int row = cs * 8 + lr8;
            const unsigned short* gp = Bt + (size_t)(bn + row) * K + k0 + gchunk * 8;
            __builtin_amdgcn_global_load_lds(
                (const __attribute__((address_space(1))) void*)gp,
                (__attribute__((address_space(3))) void*)&Bs[cs * 512], 16, 0, 0);
        }
        __syncthreads();
        #pragma unroll
        for (int kh = 0; kh < 2; ++kh) {
            int q = kh * 4 + quad;
            int pos = (q ^ (row16 & 7)) * 8;
            bf16x8 af[4], bfr[NI];
            #pragma unroll
            for (int mi = 0; mi < 4; ++mi)
                af[mi] = *(const bf16x8*)&As[(wr * 64 + mi * 16 + row16) * 64 + pos];
            #pragma unroll
            for (int ni = 0; ni < NI; ++ni)
                bfr[ni] = *(const bf16x8*)&Bs[(wc * (NT / 2) + ni * 16 + row16) * 64 + pos];
            #pragma unroll
            for (int mi = 0; mi < 4; ++mi)
                #pragma unroll
                for (int ni = 0; ni < NI; ++ni)
                    acc[mi][ni] = __builtin_amdgcn_mfma_f32_16x16x32_bf16(
                        af[mi], bfr[ni], acc[mi][ni], 0, 0, 0);
        }
        __syncthreads();
    }

    int rbase = bm + wr * 64 + (lane >> 4) * 4;
    int cbase = bn + wc * (NT / 2) + (lane & 15);
    #pragma unroll
    for (int mi = 0; mi < 4; ++mi)
        #pragma unroll
        for (int ni = 0; ni < NI; ++ni)
            #pragma unroll
            for (int r = 0; r < 4; ++r)
                C[zoff + (size_t)(rbase + mi * 16 + r) * N + cbase + ni * 16] =
                    f2bf(acc[mi][ni][r]);
}

// ---------------------------------------------------------------------------
// Layer-3 GEMM: GBK=32 variant (klen=224 not 64-divisible). XCD swizzle +
// split-K, XOR-4 swizzle for 64 B rows.
// ---------------------------------------------------------------------------
#define GBK 32
template <int NT>
__global__ __launch_bounds__(256) void gemm_k32(const unsigned short* __restrict__ A,
                                                const unsigned short* __restrict__ Bt,
                                                unsigned short* __restrict__ C,
                                                int N, int nbn, int K, int klen) {
    constexpr int NI = NT / 32;
    __shared__ short As[GBM * GBK];
    __shared__ short Bs[NT * GBK];
    int b = blockIdx.x;
    int x = b & 7, t = b >> 3;
    int j = x + 8 * (t / nbn);
    if (j >= MPAD / GBM) return;
    int bn = (t % nbn) * NT;
    int bm = j * GBM;
    int kbeg = blockIdx.y * klen;
    int kend = kbeg + klen;
    size_t zoff = (size_t)blockIdx.y * MPAD * N;
    int tid  = threadIdx.x;
    int wave = tid >> 6, lane = tid & 63;
    int wr = wave >> 1, wc = wave & 1;
    int lrow  = lane >> 2;
    int lk    = (((lane & 3) ^ ((lrow >> 1) & 3))) * 8;
    int row16 = lane & 15;
    int qs    = (((lane >> 4) ^ ((row16 >> 1) & 3))) * 8;

    f32x4 acc[4][NI];
    #pragma unroll
    for (int mi = 0; mi < 4; ++mi)
        #pragma unroll
        for (int ni = 0; ni < NI; ++ni) acc[mi][ni] = (f32x4){0.f, 0.f, 0.f, 0.f};

    for (int k0 = kbeg; k0 < kend; k0 += GBK) {
        #pragma unroll
        for (int i = 0; i < 2; ++i) {
            int c = i * 4 + wave;
            int row = c * 16 + lrow;
            const unsigned short* gp = A + (size_t)(bm + row) * K + k0 + lk;
            __builtin_amdgcn_global_load_lds(
                (const __attribute__((address_space(1))) void*)gp,
                (__attribute__((address_space(3))) void*)&As[c * 512], 16, 0, 0);
        }
        #pragma unroll
        for (int i = 0; i < NT / 64; ++i) {
            int c = i * 4 + wave;
            int row = c * 16 + lrow;
            const unsigned short* gp = Bt + (size_t)(bn + row) * K + k0 + lk;
            __builtin_amdgcn_global_load_lds(
                (const __attribute__((address_space(1))) void*)gp,
                (__attribute__((address_space(3))) void*)&Bs[c * 512], 16, 0, 0);
        }
        __syncthreads();
        bf16x8 af[4], bfr[NI];
        #pragma unroll
        for (int mi = 0; mi < 4; ++mi)
            af[mi] = *(const bf16x8*)&As[(wr * 64 + mi * 16 + row16) * GBK + qs];
        #pragma unroll
        for (int ni = 0; ni < NI; ++ni)
            bfr[ni] = *(const bf16x8*)&Bs[(wc * (NT / 2) + ni * 16 + row16) * GBK + qs];
        #pragma unroll
        for (int mi = 0; mi < 4; ++mi)
            #pragma unroll
            for (int ni = 0; ni < NI; ++ni)
                acc[mi][ni] = __builtin_amdgcn_mfma_f32_16x16x32_bf16(
                    af[mi], bfr[ni], acc[mi][ni], 0, 0, 0);
        __syncthreads();
    }

    int rbase = bm + wr * 64 + (lane >> 4) * 4;
    int cbase = bn + wc * (NT / 2) + (lane & 15);
    #pragma unroll
    for (int mi = 0; mi < 4; ++mi)
        #pragma unroll
        for (int ni = 0; ni < NI; ++ni)
            #pragma unroll
            for (int r = 0; r < 4; ++r)
                C[zoff + (size_t)(rbase + mi * 16 + r) * N + cbase + ni * 16] =
                    f2bf(acc[mi][ni][r]);
}

// ---------------------------------------------------------------------------
// Fused split-K reduce + attention halves, layer 2 (4 slices, N=448, H=8).
// One wave per node: lane<56 covers 4 dwords (8 ch), head = lane/7.
// ---------------------------------------------------------------------------
__global__ __launch_bounds__(256) void reduce_attn_l2(const unsigned int* __restrict__ P,
                                                      unsigned int* __restrict__ h2out,
                                                      const float* __restrict__ as2,
                                                      const float* __restrict__ ad2,
                                                      float* __restrict__ e_src,
                                                      float* __restrict__ e_dst, int M) {
    const size_t stride = (size_t)MPAD * 224;
    int wave = threadIdx.x >> 6, lane = threadIdx.x & 63;
    int node = blockIdx.x * 4 + wave;
    if (node >= M) return;
    bool act = lane < 56;
    int head = lane / 7;
    int m = lane - head * 7;
    size_t base = (size_t)node * 224 + lane * 4;
    float lo[4], hi[4];
    #pragma unroll
    for (int d = 0; d < 4; ++d) {
        float l = 0.f, hh = 0.f;
        #pragma unroll
        for (int s = 0; s < 4; ++s) {
            unsigned int v = P[s * stride + base + d];
            l  += bf2f((unsigned short)(v & 0xffffu));
            hh += bf2f((unsigned short)(v >> 16));
        }
        lo[d] = l; hi[d] = hh;
    }
    if (act) {
        #pragma unroll
        for (int d = 0; d < 4; ++d)
            h2out[base + d] = (unsigned int)f2bf(lo[d]) |
                              ((unsigned int)f2bf(hi[d]) << 16);
    }
    float ps = 0.f, pd = 0.f;
    if (act) {
        const float* as = as2 + head * 56 + m * 8;
        const float* ad = ad2 + head * 56 + m * 8;
        #pragma unroll
        for (int d = 0; d < 4; ++d) {
            ps += lo[d] * as[2 * d] + hi[d] * as[2 * d + 1];
            pd += lo[d] * ad[2 * d] + hi[d] * ad[2 * d + 1];
        }
    }
    int lead = (lane / 7) * 7;
    float ts = 0.f, td = 0.f;
    #pragma unroll
    for (int jj = 0; jj < 7; ++jj) {
        int src = lead + jj; if (src > 63) src = 63;
        ts += __shfl(ps, src);
        td += __shfl(pd, src);
    }
    if (act && m == 0) {
        e_src[node * 8 + head] = ts;
        e_dst[node * 8 + head] = td;
    }
}

// Fused reduce+attn, layer 3 (2 slices, N=128, H=4). One wave per node.
__global__ __launch_bounds__(256) void reduce_attn_l3(const unsigned int* __restrict__ P,
                                                      unsigned int* __restrict__ h2out,
                                                      const float* __restrict__ as3,
                                                      const float* __restrict__ ad3,
                                                      float* __restrict__ e_src,
                                                      float* __restrict__ e_dst, int M) {
    const size_t stride = (size_t)MPAD * 64;
    int wave = threadIdx.x >> 6, lane = threadIdx.x & 63;
    int node = blockIdx.x * 4 + wave;
    if (node >= M) return;
    int head = lane >> 4;
    int cl = (lane & 15) * 2;
    size_t idx = (size_t)node * 64 + lane;
    unsigned int v0 = P[idx], v1 = P[stride + idx];
    float lo = bf2f((unsigned short)(v0 & 0xffffu)) + bf2f((unsigned short)(v1 & 0xffffu));
    float hi = bf2f((unsigned short)(v0 >> 16)) + bf2f((unsigned short)(v1 >> 16));
    h2out[idx] = (unsigned int)f2bf(lo) | ((unsigned int)f2bf(hi) << 16);
    float ps = lo * as3[head * 32 + cl] + hi * as3[head * 32 + cl + 1];
    float pd = lo * ad3[head * 32 + cl] + hi * ad3[head * 32 + cl + 1];
    #pragma unroll
    for (int off = 8; off; off >>= 1) {
        ps += __shfl_xor(ps, off);
        pd += __shfl_xor(pd, off);
    }
    if ((lane & 15) == 0) {
        e_src[node * 4 + head] = ps;
        e_dst[node * 4 + head] = pd;
    }
}

// ---------------------------------------------------------------------------
// Layer-4 GEMM fused with attention halves.
// ---------------------------------------------------------------------------
__global__ __launch_bounds__(256) void gemm4_attn(const unsigned short* __restrict__ A,
                                                  const float* __restrict__ W,
                                                  const float* __restrict__ as4,
                                                  const float* __restrict__ ad4,
                                                  unsigned short* __restrict__ C,
                                                  float* __restrict__ e_src,
                                                  float* __restrict__ e_dst, int M) {
    __shared__ float Ws[128 * 16];
    int tid = threadIdx.x;
    for (int i = tid; i < 2048; i += 256) Ws[i] = W[i];
    __syncthreads();
    int node = blockIdx.x * 16 + (tid >> 4);
    int n = tid & 15;
    if (node >= M) return;
    const unsigned short* ap = A + (size_t)node * 128;
    float acc = 0.f;
    #pragma unroll 8
    for (int k = 0; k < 128; ++k)
        acc += bf2f(ap[k]) * Ws[k * 16 + n];
    C[(size_t)node * 16 + n] = f2bf(acc);
    float vs = acc * as4[n];
    float vd = acc * ad4[n];
    #pragma unroll
    for (int off = 1; off < 16; off <<= 1) {
        vs += __shfl_xor(vs, off);
        vd += __shfl_xor(vd, off);
    }
    if (n == 0) { e_src[node] = vs; e_dst[node] = vd; }
}

// ---------------------------------------------------------------------------
// Layer-2 (H=8, C=56) aggregation: one wave per node, 56 active lanes.
// ---------------------------------------------------------------------------
__global__ __launch_bounds__(64) void agg_l2(const unsigned short* __restrict__ h,
                                             const float* __restrict__ e_src,
                                             const float* __restrict__ e_dst,
                                             const int* __restrict__ row_ptr,
                                             const int* __restrict__ col,
                                             const float* __restrict__ bias,
                                             unsigned short* __restrict__ out) {
    const int H = 8;
    int node = blockIdx.x;
    int lane = threadIdx.x;
    bool act = lane < 56;
    int head = act ? (lane / 7) : 0;
    int cpos = act ? (lane - head * 7) : 0;
    int rs = row_ptr[node], re = row_ptr[node + 1];
    float edv = e_dst[node * H + head];

    float dn = 0.f;
    float acc0[8], acc1[8];
    #pragma unroll
    for (int k = 0; k < 8; ++k) { acc0[k] = 0.f; acc1[k] = 0.f; }
    int i = rs;
    for (; i + 1 < re; i += 2) {
        int s0 = col[i], s1 = col[i + 1];
        float es0 = e_src[s0 * H + head];
        float es1 = e_src[s1 * H + head];
        u32x4 hv0 = *(const u32x4*)(h + (size_t)s0 * 448 + head * 56 + cpos * 8);
        u32x4 hv1 = *(const u32x4*)(h + (size_t)s1 * 448 + head * 56 + cpos * 8);
        float w0 = __expf(lrelu02(es0 + edv));
        float w1 = __expf(lrelu02(es1 + edv));
        dn += w0 + w1;
        #pragma unroll
        for (int d = 0; d < 4; ++d) {
            acc0[2 * d]     += w0 * bf2f((unsigned short)(hv0[d] & 0xffffu));
            acc0[2 * d + 1] += w0 * bf2f((unsigned short)(hv0[d] >> 16));
            acc1[2 * d]     += w1 * bf2f((unsigned short)(hv1[d] & 0xffffu));
            acc1[2 * d + 1] += w1 * bf2f((unsigned short)(hv1[d] >> 16));
        }
    }
    if (i < re) {
        int s = col[i];
        float w = __expf(lrelu02(e_src[s * H + head] + edv));
        dn += w;
        u32x4 hv = *(const u32x4*)(h + (size_t)s * 448 + head * 56 + cpos * 8);
        #pragma unroll
        for (int d = 0; d < 4; ++d) {
            acc0[2 * d]     += w * bf2f((unsigned short)(hv[d] & 0xffffu));
            acc0[2 * d + 1] += w * bf2f((unsigned short)(hv[d] >> 16));
        }
    }
    float rdn = 1.f / (dn + 1e-16f);

    if (act) {
        const float* bp = bias + head * 56 + cpos * 8;
        u32x4 o;
        #pragma unroll
        for (int d = 0; d < 4; ++d) {
            float v0 = lrelu01((acc0[2 * d] + acc1[2 * d]) * rdn + bp[2 * d]);
            float v1 = lrelu01((acc0[2 * d + 1] + acc1[2 * d + 1]) * rdn + bp[2 * d + 1]);
            o[d] = (unsigned int)f2bf(v0) | ((unsigned int)f2bf(v1) << 16);
        }
        *(u32x4*)(out + (size_t)node * 448 + head * 56 + cpos * 8) = o;
    }
}

// Layer-3 (H=4, C=32): one wave per node, 16 active lanes.
__global__ __launch_bounds__(64) void agg_l3(const unsigned short* __restrict__ h,
                                             const float* __restrict__ e_src,
                                             const float* __restrict__ e_dst,
                                             const int* __restrict__ row_ptr,
                                             const int* __restrict__ col,
                                             const float* __restrict__ bias,
                                             unsigned short* __restrict__ out) {
    const int H = 4;
    int node = blockIdx.x;
    int lane = threadIdx.x;
    bool act = lane < 16;
    int head = (lane >> 2) & 3;
    int cpos = lane & 3;
    int rs = row_ptr[node], re = row_ptr[node + 1];
    float edv = e_dst[node * H + head];

    float dn = 0.f;
    float acc0[8], acc1[8];
    #pragma unroll
    for (int k = 0; k < 8; ++k) { acc0[k] = 0.f; acc1[k] = 0.f; }
    int i = rs;
    for (; i + 1 < re; i += 2) {
        int s0 = col[i], s1 = col[i + 1];
        float es0 = e_src[s0 * H + head];
        float es1 = e_src[s1 * H + head];
        u32x4 hv0 = *(const u32x4*)(h + (size_t)s0 * 128 + head * 32 + cpos * 8);
        u32x4 hv1 = *(const u32x4*)(h + (size_t)s1 * 128 + head * 32 + cpos * 8);
        float w0 = __expf(lrelu02(es0 + edv));
        float w1 = __expf(lrelu02(es1 + edv));
        dn += w0 + w1;
        #pragma unroll
        for (int d = 0; d < 4; ++d) {
            acc0[2 * d]     += w0 * bf2f((unsigned short)(hv0[d] & 0xffffu));
            acc0[2 * d + 1] += w0 * bf2f((unsigned short)(hv0[d] >> 16));
            acc1[2 * d]     += w1 * bf2f((unsigned short)(hv1[d] & 0xffffu));
            acc1[2 * d + 1] += w1 * bf2f((unsigned short)(hv1[d] >> 16));
        }
    }
    if (i < re) {
        int s = col[i];
        float w = __expf(lrelu02(e_src[s * H + head] + edv));
        dn += w;
        u32x4 hv = *(const u32x4*)(h + (size_t)s * 128 + head * 32 + cpos * 8);
        #pragma unroll
        for (int d = 0; d < 4; ++d) {
            acc0[2 * d]     += w * bf2f((unsigned short)(hv[d] & 0xffffu));
            acc0[2 * d + 1] += w * bf2f((unsigned short)(hv[d] >> 16));
        }
    }
    float rdn = 1.f / (dn + 1e-16f);

    if (act) {
        const float* bp = bias + head * 32 + cpos * 8;
        u32x4 o;
        #pragma unroll
        for (int d = 0; d < 4; ++d) {
            float v0 = lrelu01((acc0[2 * d] + acc1[2 * d]) * rdn + bp[2 * d]);
            float v1 = lrelu01((acc0[2 * d + 1] + acc1[2 * d + 1]) * rdn + bp[2 * d + 1]);
            o[d] = (unsigned int)f2bf(v0) | ((unsigned int)f2bf(v1) << 16);
        }
        *(u32x4*)(out + (size_t)node * 128 + head * 32 + cpos * 8) = o;
    }
}

// Layer-4 fused: aggregate (H=1, C=16) + bias + LeakyReLU(0.1) + row softmax.
__global__ __launch_bounds__(64) void agg4_softmax(const unsigned int* __restrict__ h2,
                                                   const float* __restrict__ e_src,
                                                   const float* __restrict__ e_dst,
                                                   const int* __restrict__ row_ptr,
                                                   const int* __restrict__ col,
                                                   const float* __restrict__ bias,
                                                   float* __restrict__ out) {
    int node = blockIdx.x;
    int lane = threadIdx.x;
    int cpos = lane & 7;
    int rs = row_ptr[node], re = row_ptr[node + 1];
    float edv = e_dst[node];

    float dn = 0.f, a0 = 0.f, a1 = 0.f;
    for (int i = rs; i < re; ++i) {
        int s = col[i];
        float w = __expf(lrelu02(e_src[s] + edv));
        dn += w;
        unsigned int hv = h2[(size_t)s * 8 + cpos];
        a0 += w * bf2f((unsigned short)(hv & 0xffffu));
        a1 += w * bf2f((unsigned short)(hv >> 16));
    }
    float rdn = 1.f / (dn + 1e-16f);
    float v0 = lrelu01(a0 * rdn + bias[2 * cpos]);
    float v1 = lrelu01(a1 * rdn + bias[2 * cpos + 1]);

    float m = fmaxf(v0, v1);
    #pragma unroll
    for (int off = 4; off; off >>= 1) m = fmaxf(m, __shfl_xor(m, off));
    float e0 = __expf(v0 - m), e1 = __expf(v1 - m);
    float s = e0 + e1;
    #pragma unroll
    for (int off = 4; off; off >>= 1) s += __shfl_xor(s, off);
    float r = 1.f / s;
    if (lane < 8) {
        out[node * 16 + 2 * cpos]     = e0 * r;
        out[node * 16 + 2 * cpos + 1] = e1 * r;
    }
}

// ---------------------------------------------------------------------------
extern "C" void kernel_launch(void* const* d_in, const int* in_sizes, int n_in,
                              void* d_out, int out_size, void* d_ws, size_t ws_size,
                              hipStream_t stream) {
    const float* x   = (const float*)d_in[0];
    const int*   ei  = (const int*)d_in[1];
    const float* W1  = (const float*)d_in[2];
    const float* as1 = (const float*)d_in[3];
    const float* ad1 = (const float*)d_in[4];
    const float* b1  = (const float*)d_in[5];
    const float* W2  = (const float*)d_in[6];
    const float* as2 = (const float*)d_in[7];
    const float* ad2 = (const float*)d_in[8];
    const float* b2  = (const float*)d_in[9];
    const float* W3  = (const float*)d_in[10];
    const float* as3 = (const float*)d_in[11];
    const float* ad3 = (const float*)d_in[12];
    const float* b3  = (const float*)d_in[13];
    const float* W4  = (const float*)d_in[14];
    const float* as4 = (const float*)d_in[15];
    const float* ad4 = (const float*)d_in[16];
    const float* b4  = (const float*)d_in[17];

    char* ws = (char*)d_ws;
    size_t off = 0;
    auto alloc = [&](size_t bytes) -> void* {
        void* p = ws + off;
        off = (off + bytes + 255) & ~(size_t)255;
        return p;
    };
    unsigned short* hbuf = (unsigned short*)alloc((size_t)MPAD * 2560 * sizeof(short));
    unsigned short* abuf = (unsigned short*)alloc((size_t)MPAD * 2560 * sizeof(short));
    unsigned short* pbuf = (unsigned short*)alloc((size_t)4 * MPAD * 448 * sizeof(short));
    unsigned short* xagg = (unsigned short*)alloc((size_t)MPAD * 10 * 128 * sizeof(short));
    unsigned short* W1t  = (unsigned short*)alloc((size_t)2560 * 128 * sizeof(short));
    unsigned short* W2t  = (unsigned short*)alloc((size_t)448 * 2560 * sizeof(short));
    unsigned short* W3t  = (unsigned short*)alloc((size_t)128 * 448 * sizeof(short));
    float* wsrc   = (float*)alloc((size_t)10 * 128 * sizeof(float));
    float* wdst   = (float*)alloc((size_t)10 * 128 * sizeof(float));
    float* e_src  = (float*)alloc((size_t)NNODES * 10 * sizeof(float));
    float* e_dst  = (float*)alloc((size_t)NNODES * 10 * sizeof(float));
    int* indeg    = (int*)alloc(NNODES * sizeof(int));
    int* row_ptr  = (int*)alloc((NNODES + 1) * sizeof(int));
    int* cursor   = (int*)alloc(NNODES * sizeof(int));
    int* col      = (int*)alloc(ETOT * sizeof(int));
    (void)ws_size;

    hipMemsetAsync(indeg, 0, NNODES * sizeof(int), stream);

    // count_deg | convert | make_wsd | transposes, one dispatch
    prep_all<<<352 + 5000 + 5 + 1496, 256, 0, stream>>>(
        ei, indeg, x, abuf, W1, as1, ad1, wsrc, wdst, W2, W3, W1t, W2t, W3t);
    scan_rowptr<<<1, 1024, 0, stream>>>(indeg, row_ptr, cursor, NNODES);
    // scatter_edges | e1_dots, one dispatch
    scatter_e1<<<352 + 2500, 256, 0, stream>>>(
        ei, cursor, col, abuf, wsrc, wdst, e_src, e_dst);

    const int Mb = MPAD / GBM;   // 79

    // ---- Layer 1 (linearity-restructured): agg_x -> batched GEMM ----
    agg_x<<<NNODES, 64, 0, stream>>>(abuf, e_src, e_dst, row_ptr, col, xagg);
    gemm_l1<<<dim3(20, Mb), 256, 0, stream>>>(xagg, W1t, b1, abuf);   // abuf = x2

    // ---- Layer 2: 2560 -> 8x56 (GBK=64, XCD-swizzled, split-K=4) ----
    gemm_k64<64><<<dim3(8 * 7 * 10, 4), 256, 0, stream>>>(
        abuf, W2t, pbuf, 448, 7, 2560, 640);
    reduce_attn_l2<<<2500, 256, 0, stream>>>(
        (const unsigned int*)pbuf, (unsigned int*)hbuf, as2, ad2, e_src, e_dst, NNODES);
    agg_l2<<<NNODES, 64, 0, stream>>>(hbuf, e_src, e_dst, row_ptr, col, b2, abuf);

    // ---- Layer 3: 448 -> 4x32 (GBK=32, XCD-swizzled, split-K=2) ----
    gemm_k32<64><<<dim3(8 * 2 * 10, 2), 256, 0, stream>>>(
        abuf, W3t, pbuf, 128, 2, 448, 224);
    reduce_attn_l3<<<2500, 256, 0, stream>>>(
        (const unsigned int*)pbuf, (unsigned int*)hbuf, as3, ad3, e_src, e_dst, NNODES);
    agg_l3<<<NNODES, 64, 0, stream>>>(hbuf, e_src, e_dst, row_ptr, col, b3, abuf);

    // ---- Layer 4: 128 -> 1x16 (attn fused into GEMM) + softmax ----
    gemm4_attn<<<(NNODES + 15) / 16, 256, 0, stream>>>(
        abuf, W4, as4, ad4, hbuf, e_src, e_dst, NNODES);
    agg4_softmax<<<NNODES, 64, 0, stream>>>(
        (const unsigned int*)hbuf, e_src, e_dst, row_ptr, col, b4, (float*)d_out);
}

// Round 15
// 278.385 us; speedup vs baseline: 1.3162x; 1.0110x over previous
//
#include <hip/hip_runtime.h>
#include <math.h>

// Problem constants (match reference setup_inputs()).
#define NNODES 10000
#define MPAD   10112           // 79 * 128 (MFMA M-tile padding)
#define NEDGES 80000           // directed edges before self loops
#define ETOT   (NEDGES + NNODES)

typedef __attribute__((ext_vector_type(4))) float f32x4;
typedef __attribute__((ext_vector_type(8))) short bf16x8;
typedef __attribute__((ext_vector_type(4))) unsigned int u32x4;

__device__ inline unsigned short f2bf(float f) {
    unsigned int u = __float_as_uint(f);
    unsigned int r = (u + 0x7fffu + ((u >> 16) & 1u)) >> 16;
    return (unsigned short)r;
}
__device__ inline float bf2f(unsigned short h) {
    return __uint_as_float(((unsigned int)h) << 16);
}
__device__ inline float lrelu01(float v) { return (v > 0.f) ? v : 0.1f * v; }
__device__ inline float lrelu02(float v) { return (v > 0.f) ? v : 0.2f * v; }

// ---------------------------------------------------------------------------
// Mega prep kernel: count_deg | x->bf16 convert | make_wsd | 3 transposes.
// ---------------------------------------------------------------------------
__global__ __launch_bounds__(256) void prep_all(const int* __restrict__ ei,
                                                int* __restrict__ indeg,
                                                const float* __restrict__ x,
                                                unsigned short* __restrict__ xb,
                                                const float* __restrict__ W1,
                                                const float* __restrict__ as1,
                                                const float* __restrict__ ad1,
                                                float* __restrict__ wsrc,
                                                float* __restrict__ wdst,
                                                const float* __restrict__ W2,
                                                const float* __restrict__ W3,
                                                unsigned short* __restrict__ W1t,
                                                unsigned short* __restrict__ W2t,
                                                unsigned short* __restrict__ W3t) {
    __shared__ float t[32][33];
    int b = blockIdx.x, tid = threadIdx.x;
    if (b < 352) {                       // count_deg
        int i = b * 256 + tid;
        if (i < ETOT) {
            int dst = (i < NEDGES) ? ei[NEDGES + i] : (i - NEDGES);
            atomicAdd(&indeg[dst], 1);
        }
        return;
    }
    b -= 352;
    if (b < 5000) {                      // convert x -> bf16
        int i = b * 256 + tid;
        if (i < NNODES * 128) xb[i] = f2bf(x[i]);
        return;
    }
    b -= 5000;
    if (b < 5) {                         // make_wsd: wsrc/wdst [10][128]
        int idx = b * 256 + tid;
        if (idx < 1280) {
            int h = idx >> 7, k = idx & 127;
            const float* wrow = W1 + (size_t)k * 2560 + h * 256;
            const float* as = as1 + h * 256;
            const float* ad = ad1 + h * 256;
            float s = 0.f, d = 0.f;
            for (int c = 0; c < 256; c += 4) {
                f32x4 w = *(const f32x4*)&wrow[c];
                f32x4 a = *(const f32x4*)&as[c];
                f32x4 bb = *(const f32x4*)&ad[c];
                #pragma unroll
                for (int j = 0; j < 4; ++j) { s += w[j] * a[j]; d += w[j] * bb[j]; }
            }
            wsrc[h * 128 + k] = s;
            wdst[h * 128 + k] = d;
        }
        return;
    }
    b -= 5;                              // transposes (1496 32x32 tiles)
    const float* W; unsigned short* Wt; int K, N, nb, kb;
    if (b < 320)       { W = W1; Wt = W1t; K = 128;  N = 2560; nb = b % 80; kb = b / 80; }
    else if (b < 1440) { W = W2; Wt = W2t; K = 2560; N = 448;  int i = b - 320;  nb = i % 14; kb = i / 14; }
    else               { W = W3; Wt = W3t; K = 448;  N = 128;  int i = b - 1440; nb = i % 4;  kb = i / 4;  }
    int kb32 = kb * 32, nb32 = nb * 32;
    int tx = tid & 31, ty = tid >> 5;    // 32 x 8
    #pragma unroll
    for (int i = 0; i < 32; i += 8)
        t[ty + i][tx] = W[(size_t)(kb32 + ty + i) * N + nb32 + tx];
    __syncthreads();
    #pragma unroll
    for (int i = 0; i < 32; i += 8)
        Wt[(size_t)(nb32 + ty + i) * K + kb32 + tx] = f2bf(t[tx][ty + i]);
}

// ---------------------------------------------------------------------------
// Single-block exclusive scan over indeg -> row_ptr (and cursor copy).
// ---------------------------------------------------------------------------
__global__ void scan_rowptr(const int* __restrict__ indeg, int* __restrict__ row_ptr,
                            int* __restrict__ cursor, int n) {
    __shared__ int sums[1024];
    int tid = threadIdx.x;
    int per = (n + 1023) / 1024;
    int start = tid * per;
    int end = start + per; if (end > n) end = n;
    int s = 0;
    for (int i = start; i < end; ++i) s += indeg[i];
    sums[tid] = s;
    __syncthreads();
    for (int off = 1; off < 1024; off <<= 1) {
        int v = (tid >= off) ? sums[tid - off] : 0;
        __syncthreads();
        sums[tid] += v;
        __syncthreads();
    }
    int excl = (tid == 0) ? 0 : sums[tid - 1];
    for (int i = start; i < end; ++i) {
        row_ptr[i] = excl;
        cursor[i]  = excl;
        excl += indeg[i];
    }
    if (tid == 1023) row_ptr[n] = sums[1023];
}

// ---------------------------------------------------------------------------
// scatter_edges | e1_dots merged. Blocks [0,352) scatter, [352,2852) e1.
// ---------------------------------------------------------------------------
__global__ __launch_bounds__(256) void scatter_e1(const int* __restrict__ ei,
                                                  int* __restrict__ cursor,
                                                  int* __restrict__ col,
                                                  const unsigned short* __restrict__ xb,
                                                  const float* __restrict__ wsrc,
                                                  const float* __restrict__ wdst,
                                                  float* __restrict__ e_src,
                                                  float* __restrict__ e_dst) {
    __shared__ float ws[1280], wd[1280];
    int b = blockIdx.x, tid = threadIdx.x;
    if (b < 352) {
        int i = b * 256 + tid;
        if (i < ETOT) {
            int src, dst;
            if (i < NEDGES) { src = ei[i]; dst = ei[NEDGES + i]; }
            else            { src = i - NEDGES; dst = i - NEDGES; }
            int pos = atomicAdd(&cursor[dst], 1);
            col[pos] = src;
        }
        return;
    }
    b -= 352;
    for (int i = tid; i < 1280; i += 256) { ws[i] = wsrc[i]; wd[i] = wdst[i]; }
    __syncthreads();
    int node = b * 4 + (tid >> 6);
    int lane = tid & 63;
    if (node >= NNODES) return;
    unsigned int xv = ((const unsigned int*)xb)[node * 64 + lane];
    float v0 = bf2f((unsigned short)(xv & 0xffffu));
    float v1 = bf2f((unsigned short)(xv >> 16));
    #pragma unroll
    for (int h = 0; h < 10; ++h) {
        float ps = v0 * ws[h * 128 + 2 * lane] + v1 * ws[h * 128 + 2 * lane + 1];
        float pd = v0 * wd[h * 128 + 2 * lane] + v1 * wd[h * 128 + 2 * lane + 1];
        #pragma unroll
        for (int off = 32; off; off >>= 1) {
            ps += __shfl_down(ps, off);
            pd += __shfl_down(pd, off);
        }
        if (lane == 0) { e_src[node * 10 + h] = ps; e_dst[node * 10 + h] = pd; }
    }
}

// ---------------------------------------------------------------------------
// Layer-1 x-aggregation: xagg[d,h,:] = sum_s alpha[d,s,h] * x[s,:].
// ---------------------------------------------------------------------------
__global__ __launch_bounds__(64) void agg_x(const unsigned short* __restrict__ xb,
                                            const float* __restrict__ e_src,
                                            const float* __restrict__ e_dst,
                                            const int* __restrict__ row_ptr,
                                            const int* __restrict__ col,
                                            unsigned short* __restrict__ xagg) {
    int node = blockIdx.x;
    int lane = threadIdx.x;
    int rs = row_ptr[node], re = row_ptr[node + 1];
    float edv = (lane < 10) ? e_dst[node * 10 + lane] : 0.f;

    float dn = 0.f;
    float a0[10], a1[10];
    #pragma unroll
    for (int h = 0; h < 10; ++h) { a0[h] = 0.f; a1[h] = 0.f; }
    for (int i = rs; i < re; ++i) {
        int s = col[i];
        float w = 0.f;
        if (lane < 10) w = __expf(lrelu02(e_src[s * 10 + lane] + edv));
        dn += w;
        unsigned int xv = ((const unsigned int*)xb)[s * 64 + lane];
        float v0 = bf2f((unsigned short)(xv & 0xffffu));
        float v1 = bf2f((unsigned short)(xv >> 16));
        #pragma unroll
        for (int h = 0; h < 10; ++h) {
            float wh = __shfl(w, h);
            a0[h] += wh * v0;
            a1[h] += wh * v1;
        }
    }
    #pragma unroll
    for (int h = 0; h < 10; ++h) {
        float rdn = 1.f / (__shfl(dn, h) + 1e-16f);
        unsigned int o = (unsigned int)f2bf(a0[h] * rdn) |
                         ((unsigned int)f2bf(a1[h] * rdn) << 16);
        ((unsigned int*)xagg)[((size_t)node * 10 + h) * 64 + lane] = o;
    }
}

// ---------------------------------------------------------------------------
// GBK=64 LDS XOR-8 swizzle: LDS chunk position p of row R holds global
// 16B-chunk p^(R&7); staging lane fetches (l&7)^(l>>3); reads un-permute
// with q^(row16&7) -> 2-way aliasing = free.
// ---------------------------------------------------------------------------

// Layer-1 batched per-head GEMM (K=128, GBK=64): x2 = lrelu01(xagg@W1t + b1).
#define GBM 128
__global__ __launch_bounds__(256) void gemm_l1(const unsigned short* __restrict__ A,
                                               const unsigned short* __restrict__ Bt,
                                               const float* __restrict__ bias,
                                               unsigned short* __restrict__ C) {
    constexpr int NT = 128, NI = 4, K = 128;
    __shared__ short As[GBM * 64];
    __shared__ short Bs[NT * 64];
    int h  = blockIdx.x >> 1;
    int nt = blockIdx.x & 1;
    int bn = h * 256 + nt * 128;
    int bm = blockIdx.y * GBM;
    int tid  = threadIdx.x;
    int wave = tid >> 6, lane = tid & 63;
    int wr = wave >> 1, wc = wave & 1;
    int lr8    = lane >> 3;
    int gchunk = (lane & 7) ^ lr8;
    int row16  = lane & 15;
    int quad   = lane >> 4;

    f32x4 acc[4][NI];
    #pragma unroll
    for (int mi = 0; mi < 4; ++mi)
        #pragma unroll
        for (int ni = 0; ni < NI; ++ni) acc[mi][ni] = (f32x4){0.f, 0.f, 0.f, 0.f};

    for (int k0 = 0; k0 < K; k0 += 64) {
        #pragma unroll
        for (int r = 0; r < 4; ++r) {
            int cs = r * 4 + wave;
            int row = cs * 8 + lr8;
            const unsigned short* gp = A + ((size_t)(bm + row) * 10 + h) * K + k0 + gchunk * 8;
            __builtin_amdgcn_global_load_lds(
                (const __attribute__((address_space(1))) void*)gp,
                (__attribute__((address_space(3))) void*)&As[cs * 512], 16, 0, 0);
        }
        #pragma unroll
        for (int r = 0; r < 4; ++r) {
            int cs = r * 4 + wave;
            int row = cs * 8 + lr8;
            const unsigned short* gp = Bt + (size_t)(bn + row) * K + k0 + gchunk * 8;
            __builtin_amdgcn_global_load_lds(
                (const __attribute__((address_space(1))) void*)gp,
                (__attribute__((address_space(3))) void*)&Bs[cs * 512], 16, 0, 0);
        }
        __syncthreads();
        #pragma unroll
        for (int kh = 0; kh < 2; ++kh) {
            int q = kh * 4 + quad;
            int pos = (q ^ (row16 & 7)) * 8;
            bf16x8 af[4], bfr[NI];
            #pragma unroll
            for (int mi = 0; mi < 4; ++mi)
                af[mi] = *(const bf16x8*)&As[(wr * 64 + mi * 16 + row16) * 64 + pos];
            #pragma unroll
            for (int ni = 0; ni < NI; ++ni)
                bfr[ni] = *(const bf16x8*)&Bs[(wc * 64 + ni * 16 + row16) * 64 + pos];
            #pragma unroll
            for (int mi = 0; mi < 4; ++mi)
                #pragma unroll
                for (int ni = 0; ni < NI; ++ni)
                    acc[mi][ni] = __builtin_amdgcn_mfma_f32_16x16x32_bf16(
                        af[mi], bfr[ni], acc[mi][ni], 0, 0, 0);
        }
        __syncthreads();
    }

    int rbase = bm + wr * 64 + (lane >> 4) * 4;
    #pragma unroll
    for (int mi = 0; mi < 4; ++mi)
        #pragma unroll
        for (int ni = 0; ni < NI; ++ni) {
            int cc = bn + wc * 64 + ni * 16 + (lane & 15);
            float b = bias[cc];
            #pragma unroll
            for (int r = 0; r < 4; ++r) {
                float v = lrelu01(acc[mi][ni][r] + b);
                C[(size_t)(rbase + mi * 16 + r) * 2560 + cc] = f2bf(v);
            }
        }
}

// ---------------------------------------------------------------------------
// GBK=64 GEMM, XCD-swizzled grid.x + split-K grid.y (bf16 partials).
// kend clamped to K so uneven splits work (e.g. K=448 -> 256+192).
// ---------------------------------------------------------------------------
template <int NT>
__global__ __launch_bounds__(256) void gemm_k64(const unsigned short* __restrict__ A,
                                                const unsigned short* __restrict__ Bt,
                                                unsigned short* __restrict__ C,
                                                int N, int nbn, int K, int klen) {
    constexpr int NI = NT / 32;
    __shared__ short As[GBM * 64];
    __shared__ short Bs[NT * 64];
    int b = blockIdx.x;
    int x = b & 7, t = b >> 3;
    int j = x + 8 * (t / nbn);
    if (j >= MPAD / GBM) return;
    int bn = (t % nbn) * NT;
    int bm = j * GBM;
    int kbeg = blockIdx.y * klen;
    int kend = kbeg + klen; if (kend > K) kend = K;
    size_t zoff = (size_t)blockIdx.y * MPAD * N;
    int tid  = threadIdx.x;
    int wave = tid >> 6, lane = tid & 63;
    int wr = wave >> 1, wc = wave & 1;
    int lr8    = lane >> 3;
    int gchunk = (lane & 7) ^ lr8;
    int row16  = lane & 15;
    int quad   = lane >> 4;

    f32x4 acc[4][NI];
    #pragma unroll
    for (int mi = 0; mi < 4; ++mi)
        #pragma unroll
        for (int ni = 0; ni < NI; ++ni) acc[mi][ni] = (f32x4){0.f, 0.f, 0.f, 0.f};

    for (int k0 = kbeg; k0 < kend; k0 += 64) {
        #pragma unroll
        for (int r = 0; r < 4; ++r) {
            int cs = r * 4 + wave;
            int row = cs * 8 + lr8;
            const unsigned short* gp = A + (size_t)(bm + row) * K + k0 + gchunk * 8;
            __builtin_amdgcn_global_load_lds(
                (const __attribute__((address_space(1))) void*)gp,
                (__attribute__((address_space(3))) void*)&As[cs * 512], 16, 0, 0);
        }
        #pragma unroll
        for (int r = 0; r < NT / 32; ++r) {
            int cs = r * 4 + wave;
            int row = cs * 8 + lr8;
            const unsigned short* gp = Bt + (size_t)(bn + row) * K + k0 + gchunk * 8;
            __builtin_amdgcn_global_load_lds(
                (const __attribute__((address_space(1))) void*)gp,
                (__attribute__((address_space(3))) void*)&Bs[cs * 512], 16, 0, 0);
        }
        __syncthreads();
        #pragma unroll
        for (int kh = 0; kh < 2; ++kh) {
            int q = kh * 4 + quad;
            int pos = (q ^ (row16 & 7)) * 8;
            bf16x8 af[4], bfr[NI];
            #pragma unroll
            for (int mi = 0; mi < 4; ++mi)
                af[mi] = *(const bf16x8*)&As[(wr * 64 + mi * 16 + row16) * 64 + pos];
            #pragma unroll
            for (int ni = 0; ni < NI; ++ni)
                bfr[ni] = *(const bf16x8*)&Bs[(wc * (NT / 2) + ni * 16 + row16) * 64 + pos];
            #pragma unroll
            for (int mi = 0; mi < 4; ++mi)
                #pragma unroll
                for (int ni = 0; ni < NI; ++ni)
                    acc[mi][ni] = __builtin_amdgcn_mfma_f32_16x16x32_bf16(
                        af[mi], bfr[ni], acc[mi][ni], 0, 0, 0);
        }
        __syncthreads();
    }

    int rbase = bm + wr * 64 + (lane >> 4) * 4;
    int cbase = bn + wc * (NT / 2) + (lane & 15);
    #pragma unroll
    for (int mi = 0; mi < 4; ++mi)
        #pragma unroll
        for (int ni = 0; ni < NI; ++ni)
            #pragma unroll
            for (int r = 0; r < 4; ++r)
                C[zoff + (size_t)(rbase + mi * 16 + r) * N + cbase + ni * 16] =
                    f2bf(acc[mi][ni][r]);
}

// ---------------------------------------------------------------------------
// Fused split-K reduce + attention halves, layer 2 (4 slices, N=448, H=8).
// ---------------------------------------------------------------------------
__global__ __launch_bounds__(256) void reduce_attn_l2(const unsigned int* __restrict__ P,
                                                      unsigned int* __restrict__ h2out,
                                                      const float* __restrict__ as2,
                                                      const float* __restrict__ ad2,
                                                      float* __restrict__ e_src,
                                                      float* __restrict__ e_dst, int M) {
    const size_t stride = (size_t)MPAD * 224;
    int wave = threadIdx.x >> 6, lane = threadIdx.x & 63;
    int node = blockIdx.x * 4 + wave;
    if (node >= M) return;
    bool act = lane < 56;
    int head = lane / 7;
    int m = lane - head * 7;
    size_t base = (size_t)node * 224 + lane * 4;
    float lo[4], hi[4];
    #pragma unroll
    for (int d = 0; d < 4; ++d) {
        float l = 0.f, hh = 0.f;
        #pragma unroll
        for (int s = 0; s < 4; ++s) {
            unsigned int v = P[s * stride + base + d];
            l  += bf2f((unsigned short)(v & 0xffffu));
            hh += bf2f((unsigned short)(v >> 16));
        }
        lo[d] = l; hi[d] = hh;
    }
    if (act) {
        #pragma unroll
        for (int d = 0; d < 4; ++d)
            h2out[base + d] = (unsigned int)f2bf(lo[d]) |
                              ((unsigned int)f2bf(hi[d]) << 16);
    }
    float ps = 0.f, pd = 0.f;
    if (act) {
        const float* as = as2 + head * 56 + m * 8;
        const float* ad = ad2 + head * 56 + m * 8;
        #pragma unroll
        for (int d = 0; d < 4; ++d) {
            ps += lo[d] * as[2 * d] + hi[d] * as[2 * d + 1];
            pd += lo[d] * ad[2 * d] + hi[d] * ad[2 * d + 1];
        }
    }
    int lead = (lane / 7) * 7;
    float ts = 0.f, td = 0.f;
    #pragma unroll
    for (int jj = 0; jj < 7; ++jj) {
        int src = lead + jj; if (src > 63) src = 63;
        ts += __shfl(ps, src);
        td += __shfl(pd, src);
    }
    if (act && m == 0) {
        e_src[node * 8 + head] = ts;
        e_dst[node * 8 + head] = td;
    }
}

// Fused reduce+attn, layer 3 (2 slices, N=128, H=4). One wave per node.
__global__ __launch_bounds__(256) void reduce_attn_l3(const unsigned int* __restrict__ P,
                                                      unsigned int* __restrict__ h2out,
                                                      const float* __restrict__ as3,
                                                      const float* __restrict__ ad3,
                                                      float* __restrict__ e_src,
                                                      float* __restrict__ e_dst, int M) {
    const size_t stride = (size_t)MPAD * 64;
    int wave = threadIdx.x >> 6, lane = threadIdx.x & 63;
    int node = blockIdx.x * 4 + wave;
    if (node >= M) return;
    int head = lane >> 4;
    int cl = (lane & 15) * 2;
    size_t idx = (size_t)node * 64 + lane;
    unsigned int v0 = P[idx], v1 = P[stride + idx];
    float lo = bf2f((unsigned short)(v0 & 0xffffu)) + bf2f((unsigned short)(v1 & 0xffffu));
    float hi = bf2f((unsigned short)(v0 >> 16)) + bf2f((unsigned short)(v1 >> 16));
    h2out[idx] = (unsigned int)f2bf(lo) | ((unsigned int)f2bf(hi) << 16);
    float ps = lo * as3[head * 32 + cl] + hi * as3[head * 32 + cl + 1];
    float pd = lo * ad3[head * 32 + cl] + hi * ad3[head * 32 + cl + 1];
    #pragma unroll
    for (int off = 8; off; off >>= 1) {
        ps += __shfl_xor(ps, off);
        pd += __shfl_xor(pd, off);
    }
    if ((lane & 15) == 0) {
        e_src[node * 4 + head] = ps;
        e_dst[node * 4 + head] = pd;
    }
}

// ---------------------------------------------------------------------------
// Layer-2 (H=8, C=56) aggregation: one wave per node, 56 active lanes.
// ---------------------------------------------------------------------------
__global__ __launch_bounds__(64) void agg_l2(const unsigned short* __restrict__ h,
                                             const float* __restrict__ e_src,
                                             const float* __restrict__ e_dst,
                                             const int* __restrict__ row_ptr,
                                             const int* __restrict__ col,
                                             const float* __restrict__ bias,
                                             unsigned short* __restrict__ out) {
    const int H = 8;
    int node = blockIdx.x;
    int lane = threadIdx.x;
    bool act = lane < 56;
    int head = act ? (lane / 7) : 0;
    int cpos = act ? (lane - head * 7) : 0;
    int rs = row_ptr[node], re = row_ptr[node + 1];
    float edv = e_dst[node * H + head];

    float dn = 0.f;
    float acc0[8], acc1[8];
    #pragma unroll
    for (int k = 0; k < 8; ++k) { acc0[k] = 0.f; acc1[k] = 0.f; }
    int i = rs;
    for (; i + 1 < re; i += 2) {
        int s0 = col[i], s1 = col[i + 1];
        float es0 = e_src[s0 * H + head];
        float es1 = e_src[s1 * H + head];
        u32x4 hv0 = *(const u32x4*)(h + (size_t)s0 * 448 + head * 56 + cpos * 8);
        u32x4 hv1 = *(const u32x4*)(h + (size_t)s1 * 448 + head * 56 + cpos * 8);
        float w0 = __expf(lrelu02(es0 + edv));
        float w1 = __expf(lrelu02(es1 + edv));
        dn += w0 + w1;
        #pragma unroll
        for (int d = 0; d < 4; ++d) {
            acc0[2 * d]     += w0 * bf2f((unsigned short)(hv0[d] & 0xffffu));
            acc0[2 * d + 1] += w0 * bf2f((unsigned short)(hv0[d] >> 16));
            acc1[2 * d]     += w1 * bf2f((unsigned short)(hv1[d] & 0xffffu));
            acc1[2 * d + 1] += w1 * bf2f((unsigned short)(hv1[d] >> 16));
        }
    }
    if (i < re) {
        int s = col[i];
        float w = __expf(lrelu02(e_src[s * H + head] + edv));
        dn += w;
        u32x4 hv = *(const u32x4*)(h + (size_t)s * 448 + head * 56 + cpos * 8);
        #pragma unroll
        for (int d = 0; d < 4; ++d) {
            acc0[2 * d]     += w * bf2f((unsigned short)(hv[d] & 0xffffu));
            acc0[2 * d + 1] += w * bf2f((unsigned short)(hv[d] >> 16));
        }
    }
    float rdn = 1.f / (dn + 1e-16f);

    if (act) {
        const float* bp = bias + head * 56 + cpos * 8;
        u32x4 o;
        #pragma unroll
        for (int d = 0; d < 4; ++d) {
            float v0 = lrelu01((acc0[2 * d] + acc1[2 * d]) * rdn + bp[2 * d]);
            float v1 = lrelu01((acc0[2 * d + 1] + acc1[2 * d + 1]) * rdn + bp[2 * d + 1]);
            o[d] = (unsigned int)f2bf(v0) | ((unsigned int)f2bf(v1) << 16);
        }
        *(u32x4*)(out + (size_t)node * 448 + head * 56 + cpos * 8) = o;
    }
}

// Layer-3 (H=4, C=32): one wave per node, 16 active lanes.
__global__ __launch_bounds__(64) void agg_l3(const unsigned short* __restrict__ h,
                                             const float* __restrict__ e_src,
                                             const float* __restrict__ e_dst,
                                             const int* __restrict__ row_ptr,
                                             const int* __restrict__ col,
                                             const float* __restrict__ bias,
                                             unsigned short* __restrict__ out) {
    const int H = 4;
    int node = blockIdx.x;
    int lane = threadIdx.x;
    bool act = lane < 16;
    int head = (lane >> 2) & 3;
    int cpos = lane & 3;
    int rs = row_ptr[node], re = row_ptr[node + 1];
    float edv = e_dst[node * H + head];

    float dn = 0.f;
    float acc0[8], acc1[8];
    #pragma unroll
    for (int k = 0; k < 8; ++k) { acc0[k] = 0.f; acc1[k] = 0.f; }
    int i = rs;
    for (; i + 1 < re; i += 2) {
        int s0 = col[i], s1 = col[i + 1];
        float es0 = e_src[s0 * H + head];
        float es1 = e_src[s1 * H + head];
        u32x4 hv0 = *(const u32x4*)(h + (size_t)s0 * 128 + head * 32 + cpos * 8);
        u32x4 hv1 = *(const u32x4*)(h + (size_t)s1 * 128 + head * 32 + cpos * 8);
        float w0 = __expf(lrelu02(es0 + edv));
        float w1 = __expf(lrelu02(es1 + edv));
        dn += w0 + w1;
        #pragma unroll
        for (int d = 0; d < 4; ++d) {
            acc0[2 * d]     += w0 * bf2f((unsigned short)(hv0[d] & 0xffffu));
            acc0[2 * d + 1] += w0 * bf2f((unsigned short)(hv0[d] >> 16));
            acc1[2 * d]     += w1 * bf2f((unsigned short)(hv1[d] & 0xffffu));
            acc1[2 * d + 1] += w1 * bf2f((unsigned short)(hv1[d] >> 16));
        }
    }
    if (i < re) {
        int s = col[i];
        float w = __expf(lrelu02(e_src[s * H + head] + edv));
        dn += w;
        u32x4 hv = *(const u32x4*)(h + (size_t)s * 128 + head * 32 + cpos * 8);
        #pragma unroll
        for (int d = 0; d < 4; ++d) {
            acc0[2 * d]     += w * bf2f((unsigned short)(hv[d] & 0xffffu));
            acc0[2 * d + 1] += w * bf2f((unsigned short)(hv[d] >> 16));
        }
    }
    float rdn = 1.f / (dn + 1e-16f);

    if (act) {
        const float* bp = bias + head * 32 + cpos * 8;
        u32x4 o;
        #pragma unroll
        for (int d = 0; d < 4; ++d) {
            float v0 = lrelu01((acc0[2 * d] + acc1[2 * d]) * rdn + bp[2 * d]);
            float v1 = lrelu01((acc0[2 * d + 1] + acc1[2 * d + 1]) * rdn + bp[2 * d + 1]);
            o[d] = (unsigned int)f2bf(v0) | ((unsigned int)f2bf(v1) << 16);
        }
        *(u32x4*)(out + (size_t)node * 128 + head * 32 + cpos * 8) = o;
    }
}

// ---------------------------------------------------------------------------
// Layer-4 GEMM fused with attention halves.
// ---------------------------------------------------------------------------
__global__ __launch_bounds__(256) void gemm4_attn(const unsigned short* __restrict__ A,
                                                  const float* __restrict__ W,
                                                  const float* __restrict__ as4,
                                                  const float* __restrict__ ad4,
                                                  unsigned short* __restrict__ C,
                                                  float* __restrict__ e_src,
                                                  float* __restrict__ e_dst, int M) {
    __shared__ float Ws[128 * 16];
    int tid = threadIdx.x;
    for (int i = tid; i < 2048; i += 256) Ws[i] = W[i];
    __syncthreads();
    int node = blockIdx.x * 16 + (tid >> 4);
    int n = tid & 15;
    if (node >= M) return;
    const unsigned short* ap = A + (size_t)node * 128;
    float acc = 0.f;
    #pragma unroll 8
    for (int k = 0; k < 128; ++k)
        acc += bf2f(ap[k]) * Ws[k * 16 + n];
    C[(size_t)node * 16 + n] = f2bf(acc);
    float vs = acc * as4[n];
    float vd = acc * ad4[n];
    #pragma unroll
    for (int off = 1; off < 16; off <<= 1) {
        vs += __shfl_xor(vs, off);
        vd += __shfl_xor(vd, off);
    }
    if (n == 0) { e_src[node] = vs; e_dst[node] = vd; }
}

// Layer-4 fused: aggregate (H=1, C=16) + bias + LeakyReLU(0.1) + row softmax.
__global__ __launch_bounds__(64) void agg4_softmax(const unsigned int* __restrict__ h2,
                                                   const float* __restrict__ e_src,
                                                   const float* __restrict__ e_dst,
                                                   const int* __restrict__ row_ptr,
                                                   const int* __restrict__ col,
                                                   const float* __restrict__ bias,
                                                   float* __restrict__ out) {
    int node = blockIdx.x;
    int lane = threadIdx.x;
    int cpos = lane & 7;
    int rs = row_ptr[node], re = row_ptr[node + 1];
    float edv = e_dst[node];

    float dn = 0.f, a0 = 0.f, a1 = 0.f;
    for (int i = rs; i < re; ++i) {
        int s = col[i];
        float w = __expf(lrelu02(e_src[s] + edv));
        dn += w;
        unsigned int hv = h2[(size_t)s * 8 + cpos];
        a0 += w * bf2f((unsigned short)(hv & 0xffffu));
        a1 += w * bf2f((unsigned short)(hv >> 16));
    }
    float rdn = 1.f / (dn + 1e-16f);
    float v0 = lrelu01(a0 * rdn + bias[2 * cpos]);
    float v1 = lrelu01(a1 * rdn + bias[2 * cpos + 1]);

    float m = fmaxf(v0, v1);
    #pragma unroll
    for (int off = 4; off; off >>= 1) m = fmaxf(m, __shfl_xor(m, off));
    float e0 = __expf(v0 - m), e1 = __expf(v1 - m);
    float s = e0 + e1;
    #pragma unroll
    for (int off = 4; off; off >>= 1) s += __shfl_xor(s, off);
    float r = 1.f / s;
    if (lane < 8) {
        out[node * 16 + 2 * cpos]     = e0 * r;
        out[node * 16 + 2 * cpos + 1] = e1 * r;
    }
}

// ---------------------------------------------------------------------------
extern "C" void kernel_launch(void* const* d_in, const int* in_sizes, int n_in,
                              void* d_out, int out_size, void* d_ws, size_t ws_size,
                              hipStream_t stream) {
    const float* x   = (const float*)d_in[0];
    const int*   ei  = (const int*)d_in[1];
    const float* W1  = (const float*)d_in[2];
    const float* as1 = (const float*)d_in[3];
    const float* ad1 = (const float*)d_in[4];
    const float* b1  = (const float*)d_in[5];
    const float* W2  = (const float*)d_in[6];
    const float* as2 = (const float*)d_in[7];
    const float* ad2 = (const float*)d_in[8];
    const float* b2  = (const float*)d_in[9];
    const float* W3  = (const float*)d_in[10];
    const float* as3 = (const float*)d_in[11];
    const float* ad3 = (const float*)d_in[12];
    const float* b3  = (const float*)d_in[13];
    const float* W4  = (const float*)d_in[14];
    const float* as4 = (const float*)d_in[15];
    const float* ad4 = (const float*)d_in[16];
    const float* b4  = (const float*)d_in[17];

    char* ws = (char*)d_ws;
    size_t off = 0;
    auto alloc = [&](size_t bytes) -> void* {
        void* p = ws + off;
        off = (off + bytes + 255) & ~(size_t)255;
        return p;
    };
    unsigned short* hbuf = (unsigned short*)alloc((size_t)MPAD * 2560 * sizeof(short));
    unsigned short* abuf = (unsigned short*)alloc((size_t)MPAD * 2560 * sizeof(short));
    unsigned short* pbuf = (unsigned short*)alloc((size_t)4 * MPAD * 448 * sizeof(short));
    unsigned short* xagg = (unsigned short*)alloc((size_t)MPAD * 10 * 128 * sizeof(short));
    unsigned short* W1t  = (unsigned short*)alloc((size_t)2560 * 128 * sizeof(short));
    unsigned short* W2t  = (unsigned short*)alloc((size_t)448 * 2560 * sizeof(short));
    unsigned short* W3t  = (unsigned short*)alloc((size_t)128 * 448 * sizeof(short));
    float* wsrc   = (float*)alloc((size_t)10 * 128 * sizeof(float));
    float* wdst   = (float*)alloc((size_t)10 * 128 * sizeof(float));
    float* e_src  = (float*)alloc((size_t)NNODES * 10 * sizeof(float));
    float* e_dst  = (float*)alloc((size_t)NNODES * 10 * sizeof(float));
    int* indeg    = (int*)alloc(NNODES * sizeof(int));
    int* row_ptr  = (int*)alloc((NNODES + 1) * sizeof(int));
    int* cursor   = (int*)alloc(NNODES * sizeof(int));
    int* col      = (int*)alloc(ETOT * sizeof(int));
    (void)ws_size;

    hipMemsetAsync(indeg, 0, NNODES * sizeof(int), stream);

    prep_all<<<352 + 5000 + 5 + 1496, 256, 0, stream>>>(
        ei, indeg, x, abuf, W1, as1, ad1, wsrc, wdst, W2, W3, W1t, W2t, W3t);
    scan_rowptr<<<1, 1024, 0, stream>>>(indeg, row_ptr, cursor, NNODES);
    scatter_e1<<<352 + 2500, 256, 0, stream>>>(
        ei, cursor, col, abuf, wsrc, wdst, e_src, e_dst);

    const int Mb = MPAD / GBM;   // 79

    // ---- Layer 1 (linearity-restructured): agg_x -> batched GEMM ----
    agg_x<<<NNODES, 64, 0, stream>>>(abuf, e_src, e_dst, row_ptr, col, xagg);
    gemm_l1<<<dim3(20, Mb), 256, 0, stream>>>(xagg, W1t, b1, abuf);   // abuf = x2

    // ---- Layer 2: 2560 -> 8x56 (GBK=64, XCD-swizzled, split-K=4) ----
    gemm_k64<64><<<dim3(8 * 7 * 10, 4), 256, 0, stream>>>(
        abuf, W2t, pbuf, 448, 7, 2560, 640);
    reduce_attn_l2<<<2500, 256, 0, stream>>>(
        (const unsigned int*)pbuf, (unsigned int*)hbuf, as2, ad2, e_src, e_dst, NNODES);
    agg_l2<<<NNODES, 64, 0, stream>>>(hbuf, e_src, e_dst, row_ptr, col, b2, abuf);

    // ---- Layer 3: 448 -> 4x32 (GBK=64, XCD-swizzled, split-K=2: 256+192) ----
    gemm_k64<64><<<dim3(8 * 2 * 10, 2), 256, 0, stream>>>(
        abuf, W3t, pbuf, 128, 2, 448, 256);
    reduce_attn_l3<<<2500, 256, 0, stream>>>(
        (const unsigned int*)pbuf, (unsigned int*)hbuf, as3, ad3, e_src, e_dst, NNODES);
    agg_l3<<<NNODES, 64, 0, stream>>>(hbuf, e_src, e_dst, row_ptr, col, b3, abuf);

    // ---- Layer 4: 128 -> 1x16 (attn fused into GEMM) + softmax ----
    gemm4_attn<<<(NNODES + 15) / 16, 256, 0, stream>>>(
        abuf, W4, as4, ad4, hbuf, e_src, e_dst, NNODES);
    agg4_softmax<<<NNODES, 64, 0, stream>>>(
        (const unsigned int*)hbuf, e_src, e_dst, row_ptr, col, b4, (float*)d_out);
}